// Round 3
// baseline (9007.347 us; speedup 1.0000x reference)
//
#include <hip/hip_runtime.h>
#include <hip/hip_bf16.h>

#define EPSC 1e-5f
#define Bn 2
#define CIN 512
#define Cc 256
#define Hh 48
#define Ww 48
#define Ll 2304
#define DI 512
#define DS 16
#define DTR 16
#define MROWS (Bn * Ll)   // 4608

using bf16 = __hip_bfloat16;

// dual-dtype input load: flag=1 -> bf16, flag=0 -> f32
__device__ __forceinline__ float ldIn(const void* p, size_t i, bool bf) {
    return bf ? __bfloat162float(((const bf16*)p)[i]) : ((const float*)p)[i];
}
__device__ __forceinline__ float toF(float v) { return v; }
__device__ __forceinline__ float toF(bf16 v) { return __bfloat162float(v); }
__device__ __forceinline__ void stO(float* p, float v) { *p = v; }
__device__ __forceinline__ void stO(bf16* p, float v) { *p = __float2bfloat16(v); }

__device__ __forceinline__ int perm_l(int dir, int t) {
    if (dir == 0) return t;
    if (dir == 1) return Ll - 1 - t;
    int tt = (dir == 2) ? t : (Ll - 1 - t);
    int h = tt % Hh, w = tt / Hh;     // transpose-scan mapping
    return h * Ww + w;
}

// ---------------- dtype detector: packed-bf16 exponent heuristic ----------------
__global__ void k_detect(const unsigned int* __restrict__ xb, int* __restrict__ flag) {
    if (threadIdx.x == 0 && blockIdx.x == 0) {
        int cnt = 0;
        for (int i = 0; i < 64; i++) {
            unsigned int u = xb[i];
            unsigned int lo = u & 0xFFFFu;
            int e = (int)((lo >> 7) & 0xFF);
            if (lo == 0u || (e >= 90 && e <= 160)) cnt++;
        }
        *flag = (cnt >= 60) ? 1 : 0;
    }
}

// ---------------- ws-size probe ----------------
__global__ __launch_bounds__(256) void k_probe(bf16* __restrict__ out, int n, float val) {
    int i = blockIdx.x * 256 + threadIdx.x;
    if (i < n) out[i] = __float2bfloat16(val);
}

// ---------------- transpose: x (B, CIN, L) -> xTb (B*L, CIN) bf16 ----------------
__global__ __launch_bounds__(256) void k_transpose_in(const void* __restrict__ x, bf16* __restrict__ xT,
                                                      const int* __restrict__ dflag) {
    bool bf = (*dflag != 0);
    __shared__ float tile[32][33];
    int b = blockIdx.z;
    int l0 = blockIdx.x * 32, c0 = blockIdx.y * 32;
    int tx = threadIdx.x, ty = threadIdx.y;
    #pragma unroll
    for (int i = 0; i < 4; i++) {
        int c = c0 + ty + i * 8;
        tile[ty + i * 8][tx] = ldIn(x, ((size_t)(b * CIN + c)) * Ll + l0 + tx, bf);
    }
    __syncthreads();
    #pragma unroll
    for (int i = 0; i < 4; i++) {
        int l = l0 + ty + i * 8;
        xT[((size_t)(b * Ll + l)) * CIN + c0 + tx] = __float2bfloat16(tile[tx][ty + i * 8]);
    }
}

// ---------------- generic GEMM: Out(M,N) = A(M,K) x W(N,K)^T, epilogues ----------------
// EP: 0 none, 1 bn+relu, 2 bias, 3 softplus(acc+bias), 4 accumulate 0.25x into fg at permuted row
template <int EP, typename TA, typename TO>
__global__ __launch_bounds__(256) void k_gemm(const TA* __restrict__ A, const void* __restrict__ W,
                                              TO* __restrict__ Out, int M, int N, int K, int lda,
                                              const void* __restrict__ g, const void* __restrict__ bias,
                                              float* __restrict__ fgOut, int dir, const int* __restrict__ dflag) {
    bool bf = (*dflag != 0);
    __shared__ float As[16][64];
    __shared__ float Ws[16][64];
    int tid = threadIdx.x;
    int tx = tid & 15, ty = tid >> 4;
    int row0 = blockIdx.y * 64, col0 = blockIdx.x * 64;
    float acc[4][4] = {};
    for (int k0 = 0; k0 < K; k0 += 16) {
        #pragma unroll
        for (int i = 0; i < 4; i++) {
            int idx = tid + i * 256;
            int kk = idx & 15, mm = idx >> 4;
            As[kk][mm] = toF(A[(size_t)(row0 + mm) * lda + k0 + kk]);
        }
        #pragma unroll
        for (int i = 0; i < 4; i++) {
            int idx = tid + i * 256;
            int kk = idx & 15, nn = idx >> 4;
            int col = col0 + nn;
            Ws[kk][nn] = (col < N) ? ldIn(W, (size_t)col * K + k0 + kk, bf) : 0.f;
        }
        __syncthreads();
        #pragma unroll
        for (int k = 0; k < 16; k++) {
            float a[4], bb[4];
            #pragma unroll
            for (int i = 0; i < 4; i++) a[i] = As[k][ty * 4 + i];
            #pragma unroll
            for (int j = 0; j < 4; j++) bb[j] = Ws[k][tx * 4 + j];
            #pragma unroll
            for (int i = 0; i < 4; i++)
                #pragma unroll
                for (int j = 0; j < 4; j++) acc[i][j] += a[i] * bb[j];
        }
        __syncthreads();
    }
    float rs = rsqrtf(1.f + EPSC);
    #pragma unroll
    for (int i = 0; i < 4; i++) {
        int m = row0 + ty * 4 + i;
        #pragma unroll
        for (int j = 0; j < 4; j++) {
            int n = col0 + tx * 4 + j;
            if (n >= N) continue;
            float v = acc[i][j];
            if (EP == 1) {
                v = v * ldIn(g, n, bf) * rs + ldIn(bias, n, bf);
                v = fmaxf(v, 0.f);
            } else if (EP == 2) {
                v += ldIn(bias, n, bf);
            } else if (EP == 3) {
                v += ldIn(bias, n, bf);
                v = (v > 20.f) ? v : log1pf(expf(v));
            }
            if (EP == 4) {
                int b = m / Ll, t = m % Ll;
                int l = perm_l(dir, t);
                fgOut[(size_t)(b * Ll + l) * Cc + n] += 0.25f * v;
            } else {
                stO(&Out[(size_t)m * N + n], v);
            }
        }
    }
}

// ---------------- LayerNorm over C=256 per row ----------------
__global__ __launch_bounds__(256) void k_ln(const float* __restrict__ xr, const void* __restrict__ g,
                                            const void* __restrict__ bvec, float* __restrict__ xn,
                                            const int* __restrict__ dflag) {
    bool bf = (*dflag != 0);
    int m = blockIdx.x;
    int c = threadIdx.x;
    float v = xr[(size_t)m * Cc + c];
    float s1 = v, s2 = v * v;
    #pragma unroll
    for (int off = 32; off; off >>= 1) {
        s1 += __shfl_down(s1, off);
        s2 += __shfl_down(s2, off);
    }
    __shared__ float a1[4], a2[4];
    int w = c >> 6;
    if ((c & 63) == 0) { a1[w] = s1; a2[w] = s2; }
    __syncthreads();
    float t1 = a1[0] + a1[1] + a1[2] + a1[3];
    float t2 = a2[0] + a2[1] + a2[2] + a2[3];
    float mu = t1 * (1.f / 256.f);
    float var = t2 * (1.f / 256.f) - mu * mu;
    float r = rsqrtf(var + EPSC);
    xn[(size_t)m * Cc + c] = (v - mu) * r * ldIn(g, c, bf) + ldIn(bvec, c, bf);
}

// ---------------- fused depthwise 1x7 + 7x1 convs with bn+relu, summed ----------------
__global__ __launch_bounds__(256) void k_dwconv_hv(const float* __restrict__ p, const void* __restrict__ dwh,
                                                   const void* __restrict__ bnhg, const void* __restrict__ bnhb,
                                                   const void* __restrict__ dwv, const void* __restrict__ bnvg,
                                                   const void* __restrict__ bnvb, float* __restrict__ hv,
                                                   const int* __restrict__ dflag) {
    bool bf = (*dflag != 0);
    int m = blockIdx.x;
    int c = threadIdx.x;
    int b = m / Ll, l = m % Ll;
    int yy = l / Ww, xx = l % Ww;
    const float* base = p + (size_t)b * Ll * Cc;
    float ah = 0.f, av = 0.f;
    #pragma unroll
    for (int j = 0; j < 7; j++) {
        int x2 = xx + j - 3;
        if (0 <= x2 && x2 < Ww) ah += ldIn(dwh, c * 7 + j, bf) * base[(size_t)(yy * Ww + x2) * Cc + c];
        int y2 = yy + j - 3;
        if (0 <= y2 && y2 < Hh) av += ldIn(dwv, c * 7 + j, bf) * base[(size_t)(y2 * Ww + xx) * Cc + c];
    }
    float rs = rsqrtf(1.f + EPSC);
    float out = fmaxf(ah * ldIn(bnhg, c, bf) * rs + ldIn(bnhb, c, bf), 0.f) +
                fmaxf(av * ldIn(bnvg, c, bf) * rs + ldIn(bnvb, c, bf), 0.f);
    hv[(size_t)m * Cc + c] = out;
}

// ---------------- per-direction causal depthwise conv(k=4) + silu ----------------
__global__ __launch_bounds__(512) void k_conv1d(const bf16* __restrict__ xz, const void* __restrict__ cw,
                                                const void* __restrict__ cb, bf16* __restrict__ xm2, int dir,
                                                const int* __restrict__ dflag) {
    bool bf = (*dflag != 0);
    int m = blockIdx.x;
    int ch = threadIdx.x;
    int b = m / Ll, t = m % Ll;
    float acc = ldIn(cb, ch, bf);
    #pragma unroll
    for (int j = 0; j < 4; j++) {
        int tt = t + j - 3;
        if (tt >= 0) {
            int l = perm_l(dir, tt);
            acc += ldIn(cw, ch * 4 + j, bf) * __bfloat162float(xz[((size_t)(b * Ll + l)) * 1024 + ch]);
        }
    }
    xm2[(size_t)m * DI + ch] = __float2bfloat16(acc / (1.f + expf(-acc)));
}

// ---------------- selective scan ----------------
__global__ __launch_bounds__(256) void k_scan(const bf16* __restrict__ dtb, const bf16* __restrict__ xm2,
                                              const float* __restrict__ proj, const bf16* __restrict__ xz,
                                              const void* __restrict__ A_log, const void* __restrict__ Dp,
                                              bf16* __restrict__ y, int dir, const int* __restrict__ dflag) {
    bool bf = (*dflag != 0);
    int tid = threadIdx.x;
    int s = tid & 15;
    int gid = blockIdx.x * 16 + (tid >> 4);
    int b = gid >> 9;
    int ch = gid & 511;
    float Acoef = -expf(ldIn(A_log, ch * 16 + s, bf));
    float dp = ldIn(Dp, ch, bf);
    float h = 0.f;
    const bf16* dtp = dtb + (size_t)b * Ll * DI + ch;
    const bf16* xp = xm2 + (size_t)b * Ll * DI + ch;
    const float* pp = proj + (size_t)b * Ll * 48;
    #pragma unroll 4
    for (int t = 0; t < Ll; t++) {
        float dtv = __bfloat162float(dtp[(size_t)t * DI]);
        float xv = __bfloat162float(xp[(size_t)t * DI]);
        float Bv = pp[t * 48 + 16 + s];
        float Cv = pp[t * 48 + 32 + s];
        h = expf(dtv * Acoef) * h + dtv * xv * Bv;
        float prod = h * Cv;
        prod += __shfl_xor(prod, 8);
        prod += __shfl_xor(prod, 4);
        prod += __shfl_xor(prod, 2);
        prod += __shfl_xor(prod, 1);
        if (s == 0) {
            int l = perm_l(dir, t);
            float zv = __bfloat162float(xz[((size_t)(b * Ll + l)) * 1024 + 512 + ch]);
            float sig = 1.f / (1.f + expf(-zv));
            y[(size_t)(b * Ll + t) * DI + ch] = __float2bfloat16((prod + dp * xv) * zv * sig);
        }
    }
}

// ---------------- mean over spatial of (fl+fg) -> ssum (pre-zeroed), atomics ----------------
__global__ __launch_bounds__(256) void k_meanU(const float* __restrict__ fl, const float* __restrict__ fg,
                                               float* __restrict__ ssum) {
    int b = blockIdx.y;
    int chunk = blockIdx.x;   // 32 chunks x 72 rows
    int c = threadIdx.x;
    float acc = 0.f;
    for (int i = 0; i < 72; i++) {
        int l = chunk * 72 + i;
        size_t off = ((size_t)(b * Ll + l)) * Cc + c;
        acc += fl[off] + fg[off];
    }
    atomicAdd(&ssum[b * Cc + c], acc);
}

// ---------------- SE head ----------------
__global__ __launch_bounds__(256) void k_se(const float* __restrict__ ssum, const void* __restrict__ fc1,
                                            const void* __restrict__ fc2, float* __restrict__ w01,
                                            const int* __restrict__ dflag) {
    bool bf = (*dflag != 0);
    int b = blockIdx.x;
    int c = threadIdx.x;
    __shared__ float sh[256];
    __shared__ float mid[16];
    sh[c] = ssum[b * 256 + c] * (1.f / (float)Ll);
    __syncthreads();
    if (c < 16) {
        float a = 0.f;
        for (int k = 0; k < 256; k++) a += sh[k] * ldIn(fc1, c * 256 + k, bf);
        mid[c] = fmaxf(a, 0.f);
    }
    __syncthreads();
    float a0 = 0.f, a1 = 0.f;
    #pragma unroll
    for (int j = 0; j < 16; j++) {
        float mj = mid[j];
        a0 += mj * ldIn(fc2, c * 16 + j, bf);
        a1 += mj * ldIn(fc2, (256 + c) * 16 + j, bf);
    }
    float mx = fmaxf(a0, a1);
    float e0 = expf(a0 - mx), e1 = expf(a1 - mx);
    float inv = 1.f / (e0 + e1);
    w01[b * 256 + c] = e0 * inv;
    w01[512 + b * 256 + c] = e1 * inv;
}

// ---------------- final combine + transpose to (B,C,H,W), dtype-flag output ----------------
__global__ __launch_bounds__(256) void k_final(const float* __restrict__ fl, const float* __restrict__ fg,
                                               const float* __restrict__ w01, void* __restrict__ out,
                                               const int* __restrict__ dflag) {
    bool bf = (*dflag != 0);
    __shared__ float tile[32][33];
    int b = blockIdx.z;
    int l0 = blockIdx.x * 32, c0 = blockIdx.y * 32;
    int tx = threadIdx.x, ty = threadIdx.y;
    #pragma unroll
    for (int i = 0; i < 4; i++) {
        int l = l0 + ty + i * 8;
        int c = c0 + tx;
        size_t off = ((size_t)(b * Ll + l)) * Cc + c;
        tile[ty + i * 8][tx] = w01[b * 256 + c] * fl[off] + w01[512 + b * 256 + c] * fg[off];
    }
    __syncthreads();
    #pragma unroll
    for (int i = 0; i < 4; i++) {
        int c = c0 + ty + i * 8;
        size_t off = ((size_t)(b * Cc + c)) * Ll + l0 + tx;
        float v = tile[tx][ty + i * 8];
        if (bf) ((bf16*)out)[off] = __float2bfloat16(v);
        else    ((float*)out)[off] = v;
    }
}

extern "C" void kernel_launch(void* const* d_in, const int* in_sizes, int n_in,
                              void* d_out, int out_size, void* d_ws, size_t ws_size,
                              hipStream_t stream) {
    const void* x        = d_in[0];
    const void* reduce_w = d_in[1];
    const void* bn0_g    = d_in[2];
    const void* bn0_b    = d_in[3];
    const void* proj_w   = d_in[4];
    const void* bn1_g    = d_in[5];
    const void* bn1_b    = d_in[6];
    const void* dwh_w    = d_in[7];
    const void* bnh_g    = d_in[8];
    const void* bnh_b    = d_in[9];
    const void* dwv_w    = d_in[10];
    const void* bnv_g    = d_in[11];
    const void* bnv_b    = d_in[12];
    const void* fus_w    = d_in[13];
    const void* fus_b    = d_in[14];
    const void* ln_g     = d_in[15];
    const void* ln_b     = d_in[16];
    const void* in_w     = d_in[17];
    const void* conv_w   = d_in[18];
    const void* conv_b   = d_in[19];
    const void* xproj_w  = d_in[20];
    const void* dt_w     = d_in[21];
    const void* dt_b     = d_in[22];
    const void* A_log    = d_in[23];
    const void* Dp       = d_in[24];
    const void* out_w    = d_in[25];
    const void* fc1_w    = d_in[26];
    const void* fc2_w    = d_in[27];

    // ---- workspace layout (units: f32 slots) ----
    float* ws = (float*)d_ws;
    float* xr     = ws;                        // 1179648 f32
    float* fl     = ws + 1179648;              // 1179648 f32
    float* fg     = ws + 2359296;              // 1179648 f32
    float* scrD   = ws + 3538944;              // 1179648 f32  (p, then xn)
    float* scrE   = ws + 4718592;              // 1179648 f32  (xTb bf16, then hv f32)
    bf16*  xz     = (bf16*)(ws + 5898240);     // 4718592 bf16
    bf16*  xm2    = (bf16*)(ws + 8257536);     // 2359296 bf16
    bf16*  dtb    = (bf16*)(ws + 9437184);     // 2359296 bf16
    bf16*  yb     = (bf16*)(ws + 10616832);    // 2359296 bf16
    float* proj   = ws + 11796480;             // 221184 f32
    float* ssum   = ws + 12017664;             // 512
    float* w01    = ws + 12018176;             // 1024
    int*   dflag  = (int*)(ws + 12019200);     // 1
    const size_t needed = 12019201ULL * 4ULL;  // ~45.9 MB

    if (ws_size < needed) {
        float val = 1000.0f + (float)(ws_size >> 20);
        k_probe<<<(out_size + 255) / 256, 256, 0, stream>>>((bf16*)d_out, out_size, val);
        return;
    }

    bf16* xTb = (bf16*)scrE;
    float* p  = scrD;
    float* hv = scrE;
    float* xn = scrD;

    // 0. detect input dtype (bf16 vs f32) from x's bit patterns
    k_detect<<<1, 64, 0, stream>>>((const unsigned int*)x, dflag);
    // 1. transpose x -> xTb (bf16)
    k_transpose_in<<<dim3(Ll / 32, CIN / 32, Bn), dim3(32, 8), 0, stream>>>(x, xTb, dflag);
    // 2. xr = relu(bn0(xTb @ reduce_w^T))
    k_gemm<1, bf16, float><<<dim3(4, MROWS / 64), 256, 0, stream>>>(xTb, reduce_w, xr, MROWS, Cc, CIN, CIN, bn0_g, bn0_b, nullptr, 0, dflag);
    // 3. p = relu(bn1(xr @ proj_w^T))
    k_gemm<1, float, float><<<dim3(4, MROWS / 64), 256, 0, stream>>>(xr, proj_w, p, MROWS, Cc, Cc, Cc, bn1_g, bn1_b, nullptr, 0, dflag);
    // 4. hv = relu(bnh(dwconv_h)) + relu(bnv(dwconv_v))
    k_dwconv_hv<<<MROWS, 256, 0, stream>>>(p, dwh_w, bnh_g, bnh_b, dwv_w, bnv_g, bnv_b, hv, dflag);
    // 5. fl = hv @ fus_w^T + fus_b
    k_gemm<2, float, float><<<dim3(4, MROWS / 64), 256, 0, stream>>>(hv, fus_w, fl, MROWS, Cc, Cc, Cc, nullptr, fus_b, nullptr, 0, dflag);
    // 6. xn = LN(xr)
    k_ln<<<MROWS, 256, 0, stream>>>(xr, ln_g, ln_b, xn, dflag);
    // 7. xz = xn @ in_w^T (bf16 out; shared across all 4 directions)
    k_gemm<0, float, bf16><<<dim3(16, MROWS / 64), 256, 0, stream>>>(xn, in_w, xz, MROWS, 2 * DI, Cc, Cc, nullptr, nullptr, nullptr, 0, dflag);
    // 8. fg = xr  (the "+ x" residual)
    hipMemcpyAsync(fg, xr, (size_t)1179648 * 4, hipMemcpyDeviceToDevice, stream);
    // 9. per-direction mamba
    for (int dir = 0; dir < 4; dir++) {
        k_conv1d<<<MROWS, 512, 0, stream>>>(xz, conv_w, conv_b, xm2, dir, dflag);
        k_gemm<0, bf16, float><<<dim3(1, MROWS / 64), 256, 0, stream>>>(xm2, xproj_w, proj, MROWS, DTR + 2 * DS, DI, DI, nullptr, nullptr, nullptr, 0, dflag);
        k_gemm<3, float, bf16><<<dim3(8, MROWS / 64), 256, 0, stream>>>(proj, dt_w, dtb, MROWS, DI, DTR, 48, nullptr, dt_b, nullptr, 0, dflag);
        k_scan<<<64, 256, 0, stream>>>(dtb, xm2, proj, xz, A_log, Dp, yb, dir, dflag);
        k_gemm<4, bf16, float><<<dim3(4, MROWS / 64), 256, 0, stream>>>(yb, out_w, (float*)nullptr, MROWS, Cc, DI, DI, nullptr, nullptr, fg, dir, dflag);
    }
    // 10. s = mean over spatial of (fl+fg)
    hipMemsetAsync(ssum, 0, 512 * 4, stream);
    k_meanU<<<dim3(32, Bn), 256, 0, stream>>>(fl, fg, ssum);
    // 11. SE head -> softmax weights
    k_se<<<Bn, 256, 0, stream>>>(ssum, fc1_w, fc2_w, w01, dflag);
    // 12. final combine + transpose to (B,C,H,W)
    k_final<<<dim3(Ll / 32, Cc / 32, Bn), dim3(32, 8), 0, stream>>>(fl, fg, w01, d_out, dflag);
}

// Round 4
// 3063.471 us; speedup vs baseline: 2.9402x; 2.9402x over previous
//
#include <hip/hip_runtime.h>
#include <hip/hip_bf16.h>

#define EPSC 1e-5f
#define Bn 2
#define CIN 512
#define Cc 256
#define Hh 48
#define Ww 48
#define Ll 2304
#define DI 512
#define DS 16
#define DTR 16
#define MROWS (Bn * Ll)   // 4608

using bf16 = __hip_bfloat16;

// dual-dtype input load: flag=1 -> bf16, flag=0 -> f32
__device__ __forceinline__ float ldIn(const void* p, size_t i, bool bf) {
    return bf ? __bfloat162float(((const bf16*)p)[i]) : ((const float*)p)[i];
}
__device__ __forceinline__ float toF(float v) { return v; }
__device__ __forceinline__ float toF(bf16 v) { return __bfloat162float(v); }
__device__ __forceinline__ void stO(float* p, float v) { *p = v; }
__device__ __forceinline__ void stO(bf16* p, float v) { *p = __float2bfloat16(v); }
__device__ __forceinline__ float bfu2f(unsigned short u) {
    return __uint_as_float(((unsigned int)u) << 16);
}

template <int DIR>
__device__ __forceinline__ int perm_t(int t) {
    if constexpr (DIR == 0) { return t; }
    else if constexpr (DIR == 1) { return Ll - 1 - t; }
    else {
        int tt = (DIR == 2) ? t : (Ll - 1 - t);
        int h = tt % Hh, w = tt / Hh;     // transpose-scan mapping (compile-time div)
        return h * Ww + w;
    }
}

// ---------------- dtype detector: packed-bf16 exponent heuristic ----------------
__global__ void k_detect(const unsigned int* __restrict__ xb, int* __restrict__ flag) {
    if (threadIdx.x == 0 && blockIdx.x == 0) {
        int cnt = 0;
        for (int i = 0; i < 64; i++) {
            unsigned int u = xb[i];
            unsigned int lo = u & 0xFFFFu;
            int e = (int)((lo >> 7) & 0xFF);
            if (lo == 0u || (e >= 90 && e <= 160)) cnt++;
        }
        *flag = (cnt >= 60) ? 1 : 0;
    }
}

// ---------------- ws-size probe ----------------
__global__ __launch_bounds__(256) void k_probe(bf16* __restrict__ out, int n, float val) {
    int i = blockIdx.x * 256 + threadIdx.x;
    if (i < n) out[i] = __float2bfloat16(val);
}

// ---------------- transpose: x (B, CIN, L) -> xTb (B*L, CIN) bf16 ----------------
__global__ __launch_bounds__(256) void k_transpose_in(const void* __restrict__ x, bf16* __restrict__ xT,
                                                      const int* __restrict__ dflag) {
    bool bf = (*dflag != 0);
    __shared__ float tile[32][33];
    int b = blockIdx.z;
    int l0 = blockIdx.x * 32, c0 = blockIdx.y * 32;
    int tx = threadIdx.x, ty = threadIdx.y;
    #pragma unroll
    for (int i = 0; i < 4; i++) {
        int c = c0 + ty + i * 8;
        tile[ty + i * 8][tx] = ldIn(x, ((size_t)(b * CIN + c)) * Ll + l0 + tx, bf);
    }
    __syncthreads();
    #pragma unroll
    for (int i = 0; i < 4; i++) {
        int l = l0 + ty + i * 8;
        xT[((size_t)(b * Ll + l)) * CIN + c0 + tx] = __float2bfloat16(tile[tx][ty + i * 8]);
    }
}

// ---------------- generic GEMM: Out(M,N) = A(M,K) x W(N,K)^T, epilogues ----------------
// EP: 0 none, 1 bn+relu, 2 bias, 3 softplus(acc+bias), 4 accumulate 0.25x into fg at permuted row
template <int EP, int DIR, typename TA, typename TO>
__global__ __launch_bounds__(256) void k_gemm(const TA* __restrict__ A, const void* __restrict__ W,
                                              TO* __restrict__ Out, int M, int N, int K, int lda,
                                              const void* __restrict__ g, const void* __restrict__ bias,
                                              float* __restrict__ fgOut, const int* __restrict__ dflag) {
    bool bf = (*dflag != 0);
    __shared__ float As[16][64];
    __shared__ float Ws[16][64];
    int tid = threadIdx.x;
    int tx = tid & 15, ty = tid >> 4;
    int row0 = blockIdx.y * 64, col0 = blockIdx.x * 64;
    float acc[4][4] = {};
    for (int k0 = 0; k0 < K; k0 += 16) {
        #pragma unroll
        for (int i = 0; i < 4; i++) {
            int idx = tid + i * 256;
            int kk = idx & 15, mm = idx >> 4;
            As[kk][mm] = toF(A[(size_t)(row0 + mm) * lda + k0 + kk]);
        }
        #pragma unroll
        for (int i = 0; i < 4; i++) {
            int idx = tid + i * 256;
            int kk = idx & 15, nn = idx >> 4;
            int col = col0 + nn;
            Ws[kk][nn] = (col < N) ? ldIn(W, (size_t)col * K + k0 + kk, bf) : 0.f;
        }
        __syncthreads();
        #pragma unroll
        for (int k = 0; k < 16; k++) {
            float a[4], bb[4];
            #pragma unroll
            for (int i = 0; i < 4; i++) a[i] = As[k][ty * 4 + i];
            #pragma unroll
            for (int j = 0; j < 4; j++) bb[j] = Ws[k][tx * 4 + j];
            #pragma unroll
            for (int i = 0; i < 4; i++)
                #pragma unroll
                for (int j = 0; j < 4; j++) acc[i][j] += a[i] * bb[j];
        }
        __syncthreads();
    }
    float rs = rsqrtf(1.f + EPSC);
    #pragma unroll
    for (int i = 0; i < 4; i++) {
        int m = row0 + ty * 4 + i;
        #pragma unroll
        for (int j = 0; j < 4; j++) {
            int n = col0 + tx * 4 + j;
            if (n >= N) continue;
            float v = acc[i][j];
            if (EP == 1) {
                v = v * ldIn(g, n, bf) * rs + ldIn(bias, n, bf);
                v = fmaxf(v, 0.f);
            } else if (EP == 2) {
                v += ldIn(bias, n, bf);
            } else if (EP == 3) {
                v += ldIn(bias, n, bf);
                v = (v > 20.f) ? v : log1pf(expf(v));
            }
            if (EP == 4) {
                int b = m / Ll, t = m % Ll;
                int l = perm_t<DIR>(t);
                fgOut[(size_t)(b * Ll + l) * Cc + n] += 0.25f * v;
            } else {
                stO(&Out[(size_t)m * N + n], v);
            }
        }
    }
}

// ---------------- LayerNorm over C=256 per row ----------------
__global__ __launch_bounds__(256) void k_ln(const float* __restrict__ xr, const void* __restrict__ g,
                                            const void* __restrict__ bvec, float* __restrict__ xn,
                                            const int* __restrict__ dflag) {
    bool bf = (*dflag != 0);
    int m = blockIdx.x;
    int c = threadIdx.x;
    float v = xr[(size_t)m * Cc + c];
    float s1 = v, s2 = v * v;
    #pragma unroll
    for (int off = 32; off; off >>= 1) {
        s1 += __shfl_down(s1, off);
        s2 += __shfl_down(s2, off);
    }
    __shared__ float a1[4], a2[4];
    int w = c >> 6;
    if ((c & 63) == 0) { a1[w] = s1; a2[w] = s2; }
    __syncthreads();
    float t1 = a1[0] + a1[1] + a1[2] + a1[3];
    float t2 = a2[0] + a2[1] + a2[2] + a2[3];
    float mu = t1 * (1.f / 256.f);
    float var = t2 * (1.f / 256.f) - mu * mu;
    float r = rsqrtf(var + EPSC);
    xn[(size_t)m * Cc + c] = (v - mu) * r * ldIn(g, c, bf) + ldIn(bvec, c, bf);
}

// ---------------- fused depthwise 1x7 + 7x1 convs with bn+relu, summed ----------------
__global__ __launch_bounds__(256) void k_dwconv_hv(const float* __restrict__ p, const void* __restrict__ dwh,
                                                   const void* __restrict__ bnhg, const void* __restrict__ bnhb,
                                                   const void* __restrict__ dwv, const void* __restrict__ bnvg,
                                                   const void* __restrict__ bnvb, float* __restrict__ hv,
                                                   const int* __restrict__ dflag) {
    bool bf = (*dflag != 0);
    int m = blockIdx.x;
    int c = threadIdx.x;
    int b = m / Ll, l = m % Ll;
    int yy = l / Ww, xx = l % Ww;
    const float* base = p + (size_t)b * Ll * Cc;
    float ah = 0.f, av = 0.f;
    #pragma unroll
    for (int j = 0; j < 7; j++) {
        int x2 = xx + j - 3;
        if (0 <= x2 && x2 < Ww) ah += ldIn(dwh, c * 7 + j, bf) * base[(size_t)(yy * Ww + x2) * Cc + c];
        int y2 = yy + j - 3;
        if (0 <= y2 && y2 < Hh) av += ldIn(dwv, c * 7 + j, bf) * base[(size_t)(y2 * Ww + xx) * Cc + c];
    }
    float rs = rsqrtf(1.f + EPSC);
    float out = fmaxf(ah * ldIn(bnhg, c, bf) * rs + ldIn(bnhb, c, bf), 0.f) +
                fmaxf(av * ldIn(bnvg, c, bf) * rs + ldIn(bnvb, c, bf), 0.f);
    hv[(size_t)m * Cc + c] = out;
}

// ---------------- per-direction causal depthwise conv(k=4) + silu (DIR templated) ----------------
template <int DIR>
__global__ __launch_bounds__(512) void k_conv1d(const bf16* __restrict__ xz, const void* __restrict__ cw,
                                                const void* __restrict__ cb, bf16* __restrict__ xm2,
                                                const int* __restrict__ dflag) {
    bool bf = (*dflag != 0);
    int m = blockIdx.x;
    int ch = threadIdx.x;
    int b = m / Ll, t = m % Ll;
    float acc = ldIn(cb, ch, bf);
    #pragma unroll
    for (int j = 0; j < 4; j++) {
        int tt = t + j - 3;
        if (tt >= 0) {
            int l = perm_t<DIR>(tt);
            acc += ldIn(cw, ch * 4 + j, bf) * __bfloat162float(xz[((size_t)(b * Ll + l)) * 1024 + ch]);
        }
    }
    xm2[(size_t)m * DI + ch] = __float2bfloat16(acc / (1.f + __expf(-acc)));
}

// ---------------- selective scan v2: LDS tile double-buffered, 1 wave/block ----------------
// block = 64 threads = 1 wave = 4 (b,ch) groups x 16 states. grid = 256 blocks.
template <int DIR>
__global__ __launch_bounds__(64) void k_scan2(const bf16* __restrict__ dtb, const bf16* __restrict__ xm2,
                                              const float* __restrict__ proj, const bf16* __restrict__ xz,
                                              const void* __restrict__ A_log, const void* __restrict__ Dp,
                                              bf16* __restrict__ y, const int* __restrict__ dflag) {
    bool bf = (*dflag != 0);
    int lane = threadIdx.x;          // 0..63
    int g = lane >> 4, s = lane & 15;
    int blk = blockIdx.x;            // 0..255
    int b = blk >> 7;
    int ch0 = (blk & 127) * 4;
    int ch = ch0 + g;

    float Acoef = -__expf(ldIn(A_log, ch * 16 + s, bf));
    float dp = ldIn(Dp, ch, bf);
    float h = 0.f;

    // LDS tiles: [buf][tt][...]
    __shared__ uint2  sdtU[2][32];    // 4 ch bf16 per tt
    __shared__ uint2  sxmU[2][32];
    __shared__ uint2  szU[2][32];
    __shared__ float4 sBU[2][128];    // [tt*4 + s4] -> floats [tt][s]
    __shared__ float4 sCU[2][128];

    const bf16*  dtp = dtb + (size_t)b * Ll * DI;
    const bf16*  xp  = xm2 + (size_t)b * Ll * DI;
    const float* pp  = proj + (size_t)b * Ll * 48;
    const bf16*  zp  = xz + (size_t)b * Ll * 1024 + 512;

    int ttl = lane & 31;
    bool isA = lane < 32;

    // ---- prologue: stage tile 0 into buf 0 ----
    {
        size_t rowOff = (size_t)ttl * DI + ch0;
        const bf16* p1 = isA ? (dtp + rowOff) : (xp + rowOff);
        ushort4 r1 = *(const ushort4*)p1;
        ushort4 rz;
        if (isA) {
            int lpz = perm_t<DIR>(ttl);
            rz = *(const ushort4*)(zp + (size_t)lpz * 1024 + ch0);
        }
        int q0 = lane, q1 = 64 + lane;
        const float* pr0 = pp + (size_t)(q0 >> 2) * 48 + (q0 & 3) * 4;
        const float* pr1 = pp + (size_t)(q1 >> 2) * 48 + (q1 & 3) * 4;
        float4 b0 = *(const float4*)(pr0 + 16);
        float4 c0 = *(const float4*)(pr0 + 32);
        float4 b1 = *(const float4*)(pr1 + 16);
        float4 c1 = *(const float4*)(pr1 + 32);
        ushort4* w1 = (ushort4*)(isA ? &sdtU[0][ttl] : &sxmU[0][ttl]);
        *w1 = r1;
        if (isA) *(ushort4*)&szU[0][ttl] = rz;
        sBU[0][q0] = b0; sBU[0][q1] = b1;
        sCU[0][q0] = c0; sCU[0][q1] = c1;
    }
    __syncthreads();

    int buf = 0;
    for (int tile = 0; tile < Ll / 32; tile++) {
        // ---- prefetch next tile into registers (clamped on last tile) ----
        int t0n = (tile < Ll / 32 - 1) ? (tile + 1) * 32 : tile * 32;
        size_t rowOff = (size_t)(t0n + ttl) * DI + ch0;
        const bf16* p1 = isA ? (dtp + rowOff) : (xp + rowOff);
        ushort4 r1 = *(const ushort4*)p1;
        ushort4 rz;
        if (isA) {
            int lpz = perm_t<DIR>(t0n + ttl);
            rz = *(const ushort4*)(zp + (size_t)lpz * 1024 + ch0);
        }
        int q0 = lane, q1 = 64 + lane;
        const float* pr0 = pp + (size_t)(t0n + (q0 >> 2)) * 48 + (q0 & 3) * 4;
        const float* pr1 = pp + (size_t)(t0n + (q1 >> 2)) * 48 + (q1 & 3) * 4;
        float4 rb0 = *(const float4*)(pr0 + 16);
        float4 rc0 = *(const float4*)(pr0 + 32);
        float4 rb1 = *(const float4*)(pr1 + 16);
        float4 rc1 = *(const float4*)(pr1 + 32);

        // ---- compute current tile from LDS ----
        const unsigned short* dtl = (const unsigned short*)sdtU[buf];
        const unsigned short* xml = (const unsigned short*)sxmU[buf];
        const unsigned short* zl  = (const unsigned short*)szU[buf];
        const float* Bl = (const float*)sBU[buf];
        const float* Cl = (const float*)sCU[buf];
        int tbase = tile * 32;
        #pragma unroll 8
        for (int tt = 0; tt < 32; tt++) {
            float dtv = bfu2f(dtl[tt * 4 + g]);
            float xv  = bfu2f(xml[tt * 4 + g]);
            float Bv  = Bl[tt * 16 + s];
            float Cv  = Cl[tt * 16 + s];
            float da = __expf(dtv * Acoef);
            h = fmaf(da, h, dtv * xv * Bv);
            float prod = h * Cv;
            prod += __shfl_xor(prod, 8);
            prod += __shfl_xor(prod, 4);
            prod += __shfl_xor(prod, 2);
            prod += __shfl_xor(prod, 1);
            if (s == 0) {
                float zv = bfu2f(zl[tt * 4 + g]);
                float sig = 1.f / (1.f + __expf(-zv));
                y[(size_t)(b * Ll + tbase + tt) * DI + ch] = __float2bfloat16((prod + dp * xv) * zv * sig);
            }
        }

        // ---- write prefetched regs into other buffer ----
        int nb = buf ^ 1;
        ushort4* w1 = (ushort4*)(isA ? &sdtU[nb][ttl] : &sxmU[nb][ttl]);
        *w1 = r1;
        if (isA) *(ushort4*)&szU[nb][ttl] = rz;
        sBU[nb][q0] = rb0; sBU[nb][q1] = rb1;
        sCU[nb][q0] = rc0; sCU[nb][q1] = rc1;
        __syncthreads();
        buf = nb;
    }
}

// ---------------- mean over spatial of (fl+fg) -> ssum (pre-zeroed), atomics ----------------
__global__ __launch_bounds__(256) void k_meanU(const float* __restrict__ fl, const float* __restrict__ fg,
                                               float* __restrict__ ssum) {
    int b = blockIdx.y;
    int chunk = blockIdx.x;   // 32 chunks x 72 rows
    int c = threadIdx.x;
    float acc = 0.f;
    for (int i = 0; i < 72; i++) {
        int l = chunk * 72 + i;
        size_t off = ((size_t)(b * Ll + l)) * Cc + c;
        acc += fl[off] + fg[off];
    }
    atomicAdd(&ssum[b * Cc + c], acc);
}

// ---------------- SE head ----------------
__global__ __launch_bounds__(256) void k_se(const float* __restrict__ ssum, const void* __restrict__ fc1,
                                            const void* __restrict__ fc2, float* __restrict__ w01,
                                            const int* __restrict__ dflag) {
    bool bf = (*dflag != 0);
    int b = blockIdx.x;
    int c = threadIdx.x;
    __shared__ float sh[256];
    __shared__ float mid[16];
    sh[c] = ssum[b * 256 + c] * (1.f / (float)Ll);
    __syncthreads();
    if (c < 16) {
        float a = 0.f;
        for (int k = 0; k < 256; k++) a += sh[k] * ldIn(fc1, c * 256 + k, bf);
        mid[c] = fmaxf(a, 0.f);
    }
    __syncthreads();
    float a0 = 0.f, a1 = 0.f;
    #pragma unroll
    for (int j = 0; j < 16; j++) {
        float mj = mid[j];
        a0 += mj * ldIn(fc2, c * 16 + j, bf);
        a1 += mj * ldIn(fc2, (256 + c) * 16 + j, bf);
    }
    float mx = fmaxf(a0, a1);
    float e0 = expf(a0 - mx), e1 = expf(a1 - mx);
    float inv = 1.f / (e0 + e1);
    w01[b * 256 + c] = e0 * inv;
    w01[512 + b * 256 + c] = e1 * inv;
}

// ---------------- final combine + transpose to (B,C,H,W), dtype-flag output ----------------
__global__ __launch_bounds__(256) void k_final(const float* __restrict__ fl, const float* __restrict__ fg,
                                               const float* __restrict__ w01, void* __restrict__ out,
                                               const int* __restrict__ dflag) {
    bool bf = (*dflag != 0);
    __shared__ float tile[32][33];
    int b = blockIdx.z;
    int l0 = blockIdx.x * 32, c0 = blockIdx.y * 32;
    int tx = threadIdx.x, ty = threadIdx.y;
    #pragma unroll
    for (int i = 0; i < 4; i++) {
        int l = l0 + ty + i * 8;
        int c = c0 + tx;
        size_t off = ((size_t)(b * Ll + l)) * Cc + c;
        tile[ty + i * 8][tx] = w01[b * 256 + c] * fl[off] + w01[512 + b * 256 + c] * fg[off];
    }
    __syncthreads();
    #pragma unroll
    for (int i = 0; i < 4; i++) {
        int c = c0 + ty + i * 8;
        size_t off = ((size_t)(b * Cc + c)) * Ll + l0 + tx;
        float v = tile[tx][ty + i * 8];
        if (bf) ((bf16*)out)[off] = __float2bfloat16(v);
        else    ((float*)out)[off] = v;
    }
}

extern "C" void kernel_launch(void* const* d_in, const int* in_sizes, int n_in,
                              void* d_out, int out_size, void* d_ws, size_t ws_size,
                              hipStream_t stream) {
    const void* x        = d_in[0];
    const void* reduce_w = d_in[1];
    const void* bn0_g    = d_in[2];
    const void* bn0_b    = d_in[3];
    const void* proj_w   = d_in[4];
    const void* bn1_g    = d_in[5];
    const void* bn1_b    = d_in[6];
    const void* dwh_w    = d_in[7];
    const void* bnh_g    = d_in[8];
    const void* bnh_b    = d_in[9];
    const void* dwv_w    = d_in[10];
    const void* bnv_g    = d_in[11];
    const void* bnv_b    = d_in[12];
    const void* fus_w    = d_in[13];
    const void* fus_b    = d_in[14];
    const void* ln_g     = d_in[15];
    const void* ln_b     = d_in[16];
    const void* in_w     = d_in[17];
    const void* conv_w   = d_in[18];
    const void* conv_b   = d_in[19];
    const void* xproj_w  = d_in[20];
    const void* dt_w     = d_in[21];
    const void* dt_b     = d_in[22];
    const void* A_log    = d_in[23];
    const void* Dp       = d_in[24];
    const void* out_w    = d_in[25];
    const void* fc1_w    = d_in[26];
    const void* fc2_w    = d_in[27];

    // ---- workspace layout (units: f32 slots) ----
    float* ws = (float*)d_ws;
    float* xr     = ws;                        // 1179648 f32
    float* fl     = ws + 1179648;              // 1179648 f32
    float* fg     = ws + 2359296;              // 1179648 f32
    float* scrD   = ws + 3538944;              // 1179648 f32  (p, then xn)
    float* scrE   = ws + 4718592;              // 1179648 f32  (xTb bf16, then hv f32)
    bf16*  xz     = (bf16*)(ws + 5898240);     // 4718592 bf16
    bf16*  xm2    = (bf16*)(ws + 8257536);     // 2359296 bf16
    bf16*  dtb    = (bf16*)(ws + 9437184);     // 2359296 bf16
    bf16*  yb     = (bf16*)(ws + 10616832);    // 2359296 bf16
    float* proj   = ws + 11796480;             // 221184 f32
    float* ssum   = ws + 12017664;             // 512
    float* w01    = ws + 12018176;             // 1024
    int*   dflag  = (int*)(ws + 12019200);     // 1
    const size_t needed = 12019201ULL * 4ULL;  // ~45.9 MB

    if (ws_size < needed) {
        float val = 1000.0f + (float)(ws_size >> 20);
        k_probe<<<(out_size + 255) / 256, 256, 0, stream>>>((bf16*)d_out, out_size, val);
        return;
    }

    bf16* xTb = (bf16*)scrE;
    float* p  = scrD;
    float* hv = scrE;
    float* xn = scrD;

    // 0. detect input dtype (bf16 vs f32)
    k_detect<<<1, 64, 0, stream>>>((const unsigned int*)x, dflag);
    // 1. transpose x -> xTb (bf16)
    k_transpose_in<<<dim3(Ll / 32, CIN / 32, Bn), dim3(32, 8), 0, stream>>>(x, xTb, dflag);
    // 2. xr = relu(bn0(xTb @ reduce_w^T))
    k_gemm<1, 0, bf16, float><<<dim3(4, MROWS / 64), 256, 0, stream>>>(xTb, reduce_w, xr, MROWS, Cc, CIN, CIN, bn0_g, bn0_b, nullptr, dflag);
    // 3. p = relu(bn1(xr @ proj_w^T))
    k_gemm<1, 0, float, float><<<dim3(4, MROWS / 64), 256, 0, stream>>>(xr, proj_w, p, MROWS, Cc, Cc, Cc, bn1_g, bn1_b, nullptr, dflag);
    // 4. hv = relu(bnh(dwconv_h)) + relu(bnv(dwconv_v))
    k_dwconv_hv<<<MROWS, 256, 0, stream>>>(p, dwh_w, bnh_g, bnh_b, dwv_w, bnv_g, bnv_b, hv, dflag);
    // 5. fl = hv @ fus_w^T + fus_b
    k_gemm<2, 0, float, float><<<dim3(4, MROWS / 64), 256, 0, stream>>>(hv, fus_w, fl, MROWS, Cc, Cc, Cc, nullptr, fus_b, nullptr, dflag);
    // 6. xn = LN(xr)
    k_ln<<<MROWS, 256, 0, stream>>>(xr, ln_g, ln_b, xn, dflag);
    // 7. xz = xn @ in_w^T (bf16 out; shared across all 4 directions)
    k_gemm<0, 0, float, bf16><<<dim3(16, MROWS / 64), 256, 0, stream>>>(xn, in_w, xz, MROWS, 2 * DI, Cc, Cc, nullptr, nullptr, nullptr, dflag);
    // 8. fg = xr  (the "+ x" residual)
    hipMemcpyAsync(fg, xr, (size_t)1179648 * 4, hipMemcpyDeviceToDevice, stream);
    // 9. per-direction mamba
    for (int dir = 0; dir < 4; dir++) {
        switch (dir) {
            case 0: k_conv1d<0><<<MROWS, 512, 0, stream>>>(xz, conv_w, conv_b, xm2, dflag); break;
            case 1: k_conv1d<1><<<MROWS, 512, 0, stream>>>(xz, conv_w, conv_b, xm2, dflag); break;
            case 2: k_conv1d<2><<<MROWS, 512, 0, stream>>>(xz, conv_w, conv_b, xm2, dflag); break;
            case 3: k_conv1d<3><<<MROWS, 512, 0, stream>>>(xz, conv_w, conv_b, xm2, dflag); break;
        }
        k_gemm<0, 0, bf16, float><<<dim3(1, MROWS / 64), 256, 0, stream>>>(xm2, xproj_w, proj, MROWS, DTR + 2 * DS, DI, DI, nullptr, nullptr, nullptr, dflag);
        k_gemm<3, 0, float, bf16><<<dim3(8, MROWS / 64), 256, 0, stream>>>(proj, dt_w, dtb, MROWS, DI, DTR, 48, nullptr, dt_b, nullptr, dflag);
        switch (dir) {
            case 0: k_scan2<0><<<256, 64, 0, stream>>>(dtb, xm2, proj, xz, A_log, Dp, yb, dflag); break;
            case 1: k_scan2<1><<<256, 64, 0, stream>>>(dtb, xm2, proj, xz, A_log, Dp, yb, dflag); break;
            case 2: k_scan2<2><<<256, 64, 0, stream>>>(dtb, xm2, proj, xz, A_log, Dp, yb, dflag); break;
            case 3: k_scan2<3><<<256, 64, 0, stream>>>(dtb, xm2, proj, xz, A_log, Dp, yb, dflag); break;
        }
        switch (dir) {
            case 0: k_gemm<4, 0, bf16, float><<<dim3(4, MROWS / 64), 256, 0, stream>>>(yb, out_w, (float*)nullptr, MROWS, Cc, DI, DI, nullptr, nullptr, fg, dflag); break;
            case 1: k_gemm<4, 1, bf16, float><<<dim3(4, MROWS / 64), 256, 0, stream>>>(yb, out_w, (float*)nullptr, MROWS, Cc, DI, DI, nullptr, nullptr, fg, dflag); break;
            case 2: k_gemm<4, 2, bf16, float><<<dim3(4, MROWS / 64), 256, 0, stream>>>(yb, out_w, (float*)nullptr, MROWS, Cc, DI, DI, nullptr, nullptr, fg, dflag); break;
            case 3: k_gemm<4, 3, bf16, float><<<dim3(4, MROWS / 64), 256, 0, stream>>>(yb, out_w, (float*)nullptr, MROWS, Cc, DI, DI, nullptr, nullptr, fg, dflag); break;
        }
    }
    // 10. s = mean over spatial of (fl+fg)
    hipMemsetAsync(ssum, 0, 512 * 4, stream);
    k_meanU<<<dim3(32, Bn), 256, 0, stream>>>(fl, fg, ssum);
    // 11. SE head -> softmax weights
    k_se<<<Bn, 256, 0, stream>>>(ssum, fc1_w, fc2_w, w01, dflag);
    // 12. final combine + transpose to (B,C,H,W)
    k_final<<<dim3(Ll / 32, Cc / 32, Bn), dim3(32, 8), 0, stream>>>(fl, fg, w01, d_out, dflag);
}

// Round 5
// 1697.673 us; speedup vs baseline: 5.3057x; 1.8045x over previous
//
#include <hip/hip_runtime.h>
#include <hip/hip_bf16.h>

#define EPSC 1e-5f
#define Bn 2
#define CIN 512
#define Cc 256
#define Hh 48
#define Ww 48
#define Ll 2304
#define DI 512
#define DS 16
#define DTR 16
#define MROWS (Bn * Ll)   // 4608

using bf16 = __hip_bfloat16;

// dual-dtype input load: flag=1 -> bf16, flag=0 -> f32
__device__ __forceinline__ float ldIn(const void* p, size_t i, bool bf) {
    return bf ? __bfloat162float(((const bf16*)p)[i]) : ((const float*)p)[i];
}
__device__ __forceinline__ float toF(float v) { return v; }
__device__ __forceinline__ float toF(bf16 v) { return __bfloat162float(v); }
__device__ __forceinline__ void stO(float* p, float v) { *p = v; }
__device__ __forceinline__ void stO(bf16* p, float v) { *p = __float2bfloat16(v); }
__device__ __forceinline__ float bfu2f(unsigned short u) {
    return __uint_as_float(((unsigned int)u) << 16);
}

template <int DIR>
__device__ __forceinline__ int perm_t(int t) {
    if constexpr (DIR == 0) { return t; }
    else if constexpr (DIR == 1) { return Ll - 1 - t; }
    else {
        int tt = (DIR == 2) ? t : (Ll - 1 - t);
        int h = tt % Hh, w = tt / Hh;     // transpose-scan mapping (compile-time div)
        return h * Ww + w;
    }
}

// ---------------- dtype detector: packed-bf16 exponent heuristic ----------------
__global__ void k_detect(const unsigned int* __restrict__ xb, int* __restrict__ flag) {
    if (threadIdx.x == 0 && blockIdx.x == 0) {
        int cnt = 0;
        for (int i = 0; i < 64; i++) {
            unsigned int u = xb[i];
            unsigned int lo = u & 0xFFFFu;
            int e = (int)((lo >> 7) & 0xFF);
            if (lo == 0u || (e >= 90 && e <= 160)) cnt++;
        }
        *flag = (cnt >= 60) ? 1 : 0;
    }
}

// ---------------- ws-size probe ----------------
__global__ __launch_bounds__(256) void k_probe(bf16* __restrict__ out, int n, float val) {
    int i = blockIdx.x * 256 + threadIdx.x;
    if (i < n) out[i] = __float2bfloat16(val);
}

// ---------------- transpose: x (B, CIN, L) -> xTb (B*L, CIN) bf16 ----------------
__global__ __launch_bounds__(256) void k_transpose_in(const void* __restrict__ x, bf16* __restrict__ xT,
                                                      const int* __restrict__ dflag) {
    bool bf = (*dflag != 0);
    __shared__ float tile[32][33];
    int b = blockIdx.z;
    int l0 = blockIdx.x * 32, c0 = blockIdx.y * 32;
    int tx = threadIdx.x, ty = threadIdx.y;
    #pragma unroll
    for (int i = 0; i < 4; i++) {
        int c = c0 + ty + i * 8;
        tile[ty + i * 8][tx] = ldIn(x, ((size_t)(b * CIN + c)) * Ll + l0 + tx, bf);
    }
    __syncthreads();
    #pragma unroll
    for (int i = 0; i < 4; i++) {
        int l = l0 + ty + i * 8;
        xT[((size_t)(b * Ll + l)) * CIN + c0 + tx] = __float2bfloat16(tile[tx][ty + i * 8]);
    }
}

// ---------------- generic GEMM: Out(M,N) = A(M,K) x W(N,K)^T, epilogues ----------------
// EP: 0 none, 1 bn+relu, 2 bias, 3 softplus(acc+bias), 4 accumulate 0.25x into fg at permuted row
template <int EP, int DIR, typename TA, typename TO>
__global__ __launch_bounds__(256) void k_gemm(const TA* __restrict__ A, const void* __restrict__ W,
                                              TO* __restrict__ Out, int M, int N, int K, int lda,
                                              const void* __restrict__ g, const void* __restrict__ bias,
                                              float* __restrict__ fgOut, const int* __restrict__ dflag) {
    bool bf = (*dflag != 0);
    __shared__ float As[16][64];
    __shared__ float Ws[16][64];
    int tid = threadIdx.x;
    int tx = tid & 15, ty = tid >> 4;
    int row0 = blockIdx.y * 64, col0 = blockIdx.x * 64;
    float acc[4][4] = {};
    for (int k0 = 0; k0 < K; k0 += 16) {
        #pragma unroll
        for (int i = 0; i < 4; i++) {
            int idx = tid + i * 256;
            int kk = idx & 15, mm = idx >> 4;
            As[kk][mm] = toF(A[(size_t)(row0 + mm) * lda + k0 + kk]);
        }
        #pragma unroll
        for (int i = 0; i < 4; i++) {
            int idx = tid + i * 256;
            int kk = idx & 15, nn = idx >> 4;
            int col = col0 + nn;
            Ws[kk][nn] = (col < N) ? ldIn(W, (size_t)col * K + k0 + kk, bf) : 0.f;
        }
        __syncthreads();
        #pragma unroll
        for (int k = 0; k < 16; k++) {
            float a[4], bb[4];
            #pragma unroll
            for (int i = 0; i < 4; i++) a[i] = As[k][ty * 4 + i];
            #pragma unroll
            for (int j = 0; j < 4; j++) bb[j] = Ws[k][tx * 4 + j];
            #pragma unroll
            for (int i = 0; i < 4; i++)
                #pragma unroll
                for (int j = 0; j < 4; j++) acc[i][j] += a[i] * bb[j];
        }
        __syncthreads();
    }
    float rs = rsqrtf(1.f + EPSC);
    #pragma unroll
    for (int i = 0; i < 4; i++) {
        int m = row0 + ty * 4 + i;
        #pragma unroll
        for (int j = 0; j < 4; j++) {
            int n = col0 + tx * 4 + j;
            if (n >= N) continue;
            float v = acc[i][j];
            if (EP == 1) {
                v = v * ldIn(g, n, bf) * rs + ldIn(bias, n, bf);
                v = fmaxf(v, 0.f);
            } else if (EP == 2) {
                v += ldIn(bias, n, bf);
            } else if (EP == 3) {
                v += ldIn(bias, n, bf);
                v = (v > 20.f) ? v : log1pf(expf(v));
            }
            if (EP == 4) {
                int b = m / Ll, t = m % Ll;
                int l = perm_t<DIR>(t);
                fgOut[(size_t)(b * Ll + l) * Cc + n] += 0.25f * v;
            } else {
                stO(&Out[(size_t)m * N + n], v);
            }
        }
    }
}

// ---------------- LayerNorm over C=256 per row ----------------
__global__ __launch_bounds__(256) void k_ln(const float* __restrict__ xr, const void* __restrict__ g,
                                            const void* __restrict__ bvec, float* __restrict__ xn,
                                            const int* __restrict__ dflag) {
    bool bf = (*dflag != 0);
    int m = blockIdx.x;
    int c = threadIdx.x;
    float v = xr[(size_t)m * Cc + c];
    float s1 = v, s2 = v * v;
    #pragma unroll
    for (int off = 32; off; off >>= 1) {
        s1 += __shfl_down(s1, off);
        s2 += __shfl_down(s2, off);
    }
    __shared__ float a1[4], a2[4];
    int w = c >> 6;
    if ((c & 63) == 0) { a1[w] = s1; a2[w] = s2; }
    __syncthreads();
    float t1 = a1[0] + a1[1] + a1[2] + a1[3];
    float t2 = a2[0] + a2[1] + a2[2] + a2[3];
    float mu = t1 * (1.f / 256.f);
    float var = t2 * (1.f / 256.f) - mu * mu;
    float r = rsqrtf(var + EPSC);
    xn[(size_t)m * Cc + c] = (v - mu) * r * ldIn(g, c, bf) + ldIn(bvec, c, bf);
}

// ---------------- fused depthwise 1x7 + 7x1 convs with bn+relu, summed ----------------
__global__ __launch_bounds__(256) void k_dwconv_hv(const float* __restrict__ p, const void* __restrict__ dwh,
                                                   const void* __restrict__ bnhg, const void* __restrict__ bnhb,
                                                   const void* __restrict__ dwv, const void* __restrict__ bnvg,
                                                   const void* __restrict__ bnvb, float* __restrict__ hv,
                                                   const int* __restrict__ dflag) {
    bool bf = (*dflag != 0);
    int m = blockIdx.x;
    int c = threadIdx.x;
    int b = m / Ll, l = m % Ll;
    int yy = l / Ww, xx = l % Ww;
    const float* base = p + (size_t)b * Ll * Cc;
    float ah = 0.f, av = 0.f;
    #pragma unroll
    for (int j = 0; j < 7; j++) {
        int x2 = xx + j - 3;
        if (0 <= x2 && x2 < Ww) ah += ldIn(dwh, c * 7 + j, bf) * base[(size_t)(yy * Ww + x2) * Cc + c];
        int y2 = yy + j - 3;
        if (0 <= y2 && y2 < Hh) av += ldIn(dwv, c * 7 + j, bf) * base[(size_t)(y2 * Ww + xx) * Cc + c];
    }
    float rs = rsqrtf(1.f + EPSC);
    float out = fmaxf(ah * ldIn(bnhg, c, bf) * rs + ldIn(bnhb, c, bf), 0.f) +
                fmaxf(av * ldIn(bnvg, c, bf) * rs + ldIn(bnvb, c, bf), 0.f);
    hv[(size_t)m * Cc + c] = out;
}

// ---------------- per-direction causal depthwise conv(k=4) + silu (DIR templated) ----------------
template <int DIR>
__global__ __launch_bounds__(512) void k_conv1d(const bf16* __restrict__ xz, const void* __restrict__ cw,
                                                const void* __restrict__ cb, bf16* __restrict__ xm2,
                                                const int* __restrict__ dflag) {
    bool bf = (*dflag != 0);
    int m = blockIdx.x;
    int ch = threadIdx.x;
    int b = m / Ll, t = m % Ll;
    float acc = ldIn(cb, ch, bf);
    #pragma unroll
    for (int j = 0; j < 4; j++) {
        int tt = t + j - 3;
        if (tt >= 0) {
            int l = perm_t<DIR>(tt);
            acc += ldIn(cw, ch * 4 + j, bf) * __bfloat162float(xz[((size_t)(b * Ll + l)) * 1024 + ch]);
        }
    }
    xm2[(size_t)m * DI + ch] = __float2bfloat16(acc / (1.f + __expf(-acc)));
}

// ---------------- selective scan v3: phase-split reduction, XCD-swizzled channels ----------------
// block = 64 threads = 1 wave = 4 (b,ch) groups x 16 states. grid = 256 blocks.
template <int DIR>
__global__ __launch_bounds__(64) void k_scan3(const bf16* __restrict__ dtb, const bf16* __restrict__ xm2,
                                              const float* __restrict__ proj, const bf16* __restrict__ xz,
                                              const void* __restrict__ A_log, const void* __restrict__ Dp,
                                              bf16* __restrict__ y, const int* __restrict__ dflag) {
    bool bf = (*dflag != 0);
    int lane = threadIdx.x;          // 0..63
    int g = lane >> 4, s = lane & 15;
    int blk = blockIdx.x;            // 0..255
    int b = blk >> 7;
    int j = blk & 127;
    // XCD-aware swizzle: the 8 blocks sharing a 64B channel-line have equal blk%8
    int ch0 = (j & 15) * 32 + (j >> 4) * 4;
    int ch = ch0 + g;

    float Acoef = -__expf(ldIn(A_log, ch * 16 + s, bf));
    float dp = ldIn(Dp, ch, bf);
    float h = 0.f;

    // LDS tiles: [buf][tt][...]
    __shared__ uint2  sdtU[2][32];    // 4 ch bf16 per tt
    __shared__ uint2  sxmU[2][32];
    __shared__ uint2  szU[2][32];
    __shared__ float4 sBU[2][128];    // [tt*4 + quarter] -> floats [tt][s]
    __shared__ float4 sCU[2][128];

    const bf16*  dtp = dtb + (size_t)b * Ll * DI;
    const bf16*  xp  = xm2 + (size_t)b * Ll * DI;
    const float* pp  = proj + (size_t)b * Ll * 48;
    const bf16*  zp  = xz + (size_t)b * Ll * 1024 + 512;

    int ttl = lane & 31;
    bool isA = lane < 32;

    // ---- prologue: stage tile 0 into buf 0 ----
    {
        size_t rowOff = (size_t)ttl * DI + ch0;
        const bf16* p1 = isA ? (dtp + rowOff) : (xp + rowOff);
        ushort4 r1 = *(const ushort4*)p1;
        ushort4 rz;
        if (isA) {
            int lpz = perm_t<DIR>(ttl);
            rz = *(const ushort4*)(zp + (size_t)lpz * 1024 + ch0);
        }
        int q0 = lane, q1 = 64 + lane;
        const float* pr0 = pp + (size_t)(q0 >> 2) * 48 + (q0 & 3) * 4;
        const float* pr1 = pp + (size_t)(q1 >> 2) * 48 + (q1 & 3) * 4;
        float4 b0 = *(const float4*)(pr0 + 16);
        float4 c0 = *(const float4*)(pr0 + 32);
        float4 b1 = *(const float4*)(pr1 + 16);
        float4 c1 = *(const float4*)(pr1 + 32);
        ushort4* w1 = (ushort4*)(isA ? &sdtU[0][ttl] : &sxmU[0][ttl]);
        *w1 = r1;
        if (isA) *(ushort4*)&szU[0][ttl] = rz;
        sBU[0][q0] = b0; sBU[0][q1] = b1;
        sCU[0][q0] = c0; sCU[0][q1] = c1;
    }
    __syncthreads();

    int buf = 0;
    for (int tile = 0; tile < Ll / 32; tile++) {
        // ---- prefetch next tile into registers (clamped on last tile) ----
        int t0n = (tile < Ll / 32 - 1) ? (tile + 1) * 32 : tile * 32;
        size_t rowOff = (size_t)(t0n + ttl) * DI + ch0;
        const bf16* p1 = isA ? (dtp + rowOff) : (xp + rowOff);
        ushort4 r1 = *(const ushort4*)p1;
        ushort4 rz;
        if (isA) {
            int lpz = perm_t<DIR>(t0n + ttl);
            rz = *(const ushort4*)(zp + (size_t)lpz * 1024 + ch0);
        }
        int q0 = lane, q1 = 64 + lane;
        const float* pr0 = pp + (size_t)(t0n + (q0 >> 2)) * 48 + (q0 & 3) * 4;
        const float* pr1 = pp + (size_t)(t0n + (q1 >> 2)) * 48 + (q1 & 3) * 4;
        float4 rb0 = *(const float4*)(pr0 + 16);
        float4 rc0 = *(const float4*)(pr0 + 32);
        float4 rb1 = *(const float4*)(pr1 + 16);
        float4 rc1 = *(const float4*)(pr1 + 32);

        // ---- phase 1: h-recurrence for 32 steps; bank h*C into regs ----
        const unsigned short* dtl = (const unsigned short*)sdtU[buf];
        const unsigned short* xml = (const unsigned short*)sxmU[buf];
        const unsigned short* zl  = (const unsigned short*)szU[buf];
        const float* Bl = (const float*)sBU[buf];
        const float* Cl = (const float*)sCU[buf];
        int tbase = tile * 32;
        float pc[32];
        #pragma unroll
        for (int tt = 0; tt < 32; tt++) {
            float dtv = bfu2f(dtl[tt * 4 + g]);
            float xv  = bfu2f(xml[tt * 4 + g]);
            float Bv  = Bl[tt * 16 + s];
            float da  = __expf(dtv * Acoef);
            h = fmaf(da, h, dtv * xv * Bv);
            pc[tt] = h * Cl[tt * 16 + s];
        }
        // ---- phase 2: batched 16-lane xor reduction (pipelined shfls) ----
        #pragma unroll
        for (int r = 8; r; r >>= 1) {
            #pragma unroll
            for (int tt = 0; tt < 32; tt++) pc[tt] += __shfl_xor(pc[tt], r);
        }
        // ---- phase 3: each lane writes 2 outputs ----
        #pragma unroll
        for (int k = 0; k < 2; k++) {
            int tt = s + 16 * k;
            float xv = bfu2f(xml[tt * 4 + g]);
            float zv = bfu2f(zl[tt * 4 + g]);
            float sig = 1.f / (1.f + __expf(-zv));
            y[(size_t)(b * Ll + tbase + tt) * DI + ch] = __float2bfloat16((pc[tt] + dp * xv) * zv * sig);
        }

        // ---- write prefetched regs into other buffer ----
        int nb = buf ^ 1;
        ushort4* w1 = (ushort4*)(isA ? &sdtU[nb][ttl] : &sxmU[nb][ttl]);
        *w1 = r1;
        if (isA) *(ushort4*)&szU[nb][ttl] = rz;
        sBU[nb][q0] = rb0; sBU[nb][q1] = rb1;
        sCU[nb][q0] = rc0; sCU[nb][q1] = rc1;
        __syncthreads();
        buf = nb;
    }
}

// ---------------- mean over spatial of (fl+fg) -> ssum (pre-zeroed), atomics ----------------
__global__ __launch_bounds__(256) void k_meanU(const float* __restrict__ fl, const float* __restrict__ fg,
                                               float* __restrict__ ssum) {
    int b = blockIdx.y;
    int chunk = blockIdx.x;   // 32 chunks x 72 rows
    int c = threadIdx.x;
    float acc = 0.f;
    for (int i = 0; i < 72; i++) {
        int l = chunk * 72 + i;
        size_t off = ((size_t)(b * Ll + l)) * Cc + c;
        acc += fl[off] + fg[off];
    }
    atomicAdd(&ssum[b * Cc + c], acc);
}

// ---------------- SE head ----------------
__global__ __launch_bounds__(256) void k_se(const float* __restrict__ ssum, const void* __restrict__ fc1,
                                            const void* __restrict__ fc2, float* __restrict__ w01,
                                            const int* __restrict__ dflag) {
    bool bf = (*dflag != 0);
    int b = blockIdx.x;
    int c = threadIdx.x;
    __shared__ float sh[256];
    __shared__ float mid[16];
    sh[c] = ssum[b * 256 + c] * (1.f / (float)Ll);
    __syncthreads();
    if (c < 16) {
        float a = 0.f;
        for (int k = 0; k < 256; k++) a += sh[k] * ldIn(fc1, c * 256 + k, bf);
        mid[c] = fmaxf(a, 0.f);
    }
    __syncthreads();
    float a0 = 0.f, a1 = 0.f;
    #pragma unroll
    for (int j = 0; j < 16; j++) {
        float mj = mid[j];
        a0 += mj * ldIn(fc2, c * 16 + j, bf);
        a1 += mj * ldIn(fc2, (256 + c) * 16 + j, bf);
    }
    float mx = fmaxf(a0, a1);
    float e0 = expf(a0 - mx), e1 = expf(a1 - mx);
    float inv = 1.f / (e0 + e1);
    w01[b * 256 + c] = e0 * inv;
    w01[512 + b * 256 + c] = e1 * inv;
}

// ---------------- final combine + transpose to (B,C,H,W), dtype-flag output ----------------
__global__ __launch_bounds__(256) void k_final(const float* __restrict__ fl, const float* __restrict__ fg,
                                               const float* __restrict__ w01, void* __restrict__ out,
                                               const int* __restrict__ dflag) {
    bool bf = (*dflag != 0);
    __shared__ float tile[32][33];
    int b = blockIdx.z;
    int l0 = blockIdx.x * 32, c0 = blockIdx.y * 32;
    int tx = threadIdx.x, ty = threadIdx.y;
    #pragma unroll
    for (int i = 0; i < 4; i++) {
        int l = l0 + ty + i * 8;
        int c = c0 + tx;
        size_t off = ((size_t)(b * Ll + l)) * Cc + c;
        tile[ty + i * 8][tx] = w01[b * 256 + c] * fl[off] + w01[512 + b * 256 + c] * fg[off];
    }
    __syncthreads();
    #pragma unroll
    for (int i = 0; i < 4; i++) {
        int c = c0 + ty + i * 8;
        size_t off = ((size_t)(b * Cc + c)) * Ll + l0 + tx;
        float v = tile[tx][ty + i * 8];
        if (bf) ((bf16*)out)[off] = __float2bfloat16(v);
        else    ((float*)out)[off] = v;
    }
}

extern "C" void kernel_launch(void* const* d_in, const int* in_sizes, int n_in,
                              void* d_out, int out_size, void* d_ws, size_t ws_size,
                              hipStream_t stream) {
    const void* x        = d_in[0];
    const void* reduce_w = d_in[1];
    const void* bn0_g    = d_in[2];
    const void* bn0_b    = d_in[3];
    const void* proj_w   = d_in[4];
    const void* bn1_g    = d_in[5];
    const void* bn1_b    = d_in[6];
    const void* dwh_w    = d_in[7];
    const void* bnh_g    = d_in[8];
    const void* bnh_b    = d_in[9];
    const void* dwv_w    = d_in[10];
    const void* bnv_g    = d_in[11];
    const void* bnv_b    = d_in[12];
    const void* fus_w    = d_in[13];
    const void* fus_b    = d_in[14];
    const void* ln_g     = d_in[15];
    const void* ln_b     = d_in[16];
    const void* in_w     = d_in[17];
    const void* conv_w   = d_in[18];
    const void* conv_b   = d_in[19];
    const void* xproj_w  = d_in[20];
    const void* dt_w     = d_in[21];
    const void* dt_b     = d_in[22];
    const void* A_log    = d_in[23];
    const void* Dp       = d_in[24];
    const void* out_w    = d_in[25];
    const void* fc1_w    = d_in[26];
    const void* fc2_w    = d_in[27];

    // ---- workspace layout (units: f32 slots) ----
    float* ws = (float*)d_ws;
    float* xr     = ws;                        // 1179648 f32
    float* fl     = ws + 1179648;              // 1179648 f32
    float* fg     = ws + 2359296;              // 1179648 f32
    float* scrD   = ws + 3538944;              // 1179648 f32  (p, then xn)
    float* scrE   = ws + 4718592;              // 1179648 f32  (xTb bf16, then hv f32)
    bf16*  xz     = (bf16*)(ws + 5898240);     // 4718592 bf16
    bf16*  xm2    = (bf16*)(ws + 8257536);     // 2359296 bf16
    bf16*  dtb    = (bf16*)(ws + 9437184);     // 2359296 bf16
    bf16*  yb     = (bf16*)(ws + 10616832);    // 2359296 bf16
    float* proj   = ws + 11796480;             // 221184 f32
    float* ssum   = ws + 12017664;             // 512
    float* w01    = ws + 12018176;             // 1024
    int*   dflag  = (int*)(ws + 12019200);     // 1
    const size_t needed = 12019201ULL * 4ULL;  // ~45.9 MB

    if (ws_size < needed) {
        float val = 1000.0f + (float)(ws_size >> 20);
        k_probe<<<(out_size + 255) / 256, 256, 0, stream>>>((bf16*)d_out, out_size, val);
        return;
    }

    bf16* xTb = (bf16*)scrE;
    float* p  = scrD;
    float* hv = scrE;
    float* xn = scrD;

    // 0. detect input dtype (bf16 vs f32)
    k_detect<<<1, 64, 0, stream>>>((const unsigned int*)x, dflag);
    // 1. transpose x -> xTb (bf16)
    k_transpose_in<<<dim3(Ll / 32, CIN / 32, Bn), dim3(32, 8), 0, stream>>>(x, xTb, dflag);
    // 2. xr = relu(bn0(xTb @ reduce_w^T))
    k_gemm<1, 0, bf16, float><<<dim3(4, MROWS / 64), 256, 0, stream>>>(xTb, reduce_w, xr, MROWS, Cc, CIN, CIN, bn0_g, bn0_b, nullptr, dflag);
    // 3. p = relu(bn1(xr @ proj_w^T))
    k_gemm<1, 0, float, float><<<dim3(4, MROWS / 64), 256, 0, stream>>>(xr, proj_w, p, MROWS, Cc, Cc, Cc, bn1_g, bn1_b, nullptr, dflag);
    // 4. hv = relu(bnh(dwconv_h)) + relu(bnv(dwconv_v))
    k_dwconv_hv<<<MROWS, 256, 0, stream>>>(p, dwh_w, bnh_g, bnh_b, dwv_w, bnv_g, bnv_b, hv, dflag);
    // 5. fl = hv @ fus_w^T + fus_b
    k_gemm<2, 0, float, float><<<dim3(4, MROWS / 64), 256, 0, stream>>>(hv, fus_w, fl, MROWS, Cc, Cc, Cc, nullptr, fus_b, nullptr, dflag);
    // 6. xn = LN(xr)
    k_ln<<<MROWS, 256, 0, stream>>>(xr, ln_g, ln_b, xn, dflag);
    // 7. xz = xn @ in_w^T (bf16 out; shared across all 4 directions)
    k_gemm<0, 0, float, bf16><<<dim3(16, MROWS / 64), 256, 0, stream>>>(xn, in_w, xz, MROWS, 2 * DI, Cc, Cc, nullptr, nullptr, nullptr, dflag);
    // 8. fg = xr  (the "+ x" residual)
    hipMemcpyAsync(fg, xr, (size_t)1179648 * 4, hipMemcpyDeviceToDevice, stream);
    // 9. per-direction mamba
    for (int dir = 0; dir < 4; dir++) {
        switch (dir) {
            case 0: k_conv1d<0><<<MROWS, 512, 0, stream>>>(xz, conv_w, conv_b, xm2, dflag); break;
            case 1: k_conv1d<1><<<MROWS, 512, 0, stream>>>(xz, conv_w, conv_b, xm2, dflag); break;
            case 2: k_conv1d<2><<<MROWS, 512, 0, stream>>>(xz, conv_w, conv_b, xm2, dflag); break;
            case 3: k_conv1d<3><<<MROWS, 512, 0, stream>>>(xz, conv_w, conv_b, xm2, dflag); break;
        }
        k_gemm<0, 0, bf16, float><<<dim3(1, MROWS / 64), 256, 0, stream>>>(xm2, xproj_w, proj, MROWS, DTR + 2 * DS, DI, DI, nullptr, nullptr, nullptr, dflag);
        k_gemm<3, 0, float, bf16><<<dim3(8, MROWS / 64), 256, 0, stream>>>(proj, dt_w, dtb, MROWS, DI, DTR, 48, nullptr, dt_b, nullptr, dflag);
        switch (dir) {
            case 0: k_scan3<0><<<256, 64, 0, stream>>>(dtb, xm2, proj, xz, A_log, Dp, yb, dflag); break;
            case 1: k_scan3<1><<<256, 64, 0, stream>>>(dtb, xm2, proj, xz, A_log, Dp, yb, dflag); break;
            case 2: k_scan3<2><<<256, 64, 0, stream>>>(dtb, xm2, proj, xz, A_log, Dp, yb, dflag); break;
            case 3: k_scan3<3><<<256, 64, 0, stream>>>(dtb, xm2, proj, xz, A_log, Dp, yb, dflag); break;
        }
        switch (dir) {
            case 0: k_gemm<4, 0, bf16, float><<<dim3(4, MROWS / 64), 256, 0, stream>>>(yb, out_w, (float*)nullptr, MROWS, Cc, DI, DI, nullptr, nullptr, fg, dflag); break;
            case 1: k_gemm<4, 1, bf16, float><<<dim3(4, MROWS / 64), 256, 0, stream>>>(yb, out_w, (float*)nullptr, MROWS, Cc, DI, DI, nullptr, nullptr, fg, dflag); break;
            case 2: k_gemm<4, 2, bf16, float><<<dim3(4, MROWS / 64), 256, 0, stream>>>(yb, out_w, (float*)nullptr, MROWS, Cc, DI, DI, nullptr, nullptr, fg, dflag); break;
            case 3: k_gemm<4, 3, bf16, float><<<dim3(4, MROWS / 64), 256, 0, stream>>>(yb, out_w, (float*)nullptr, MROWS, Cc, DI, DI, nullptr, nullptr, fg, dflag); break;
        }
    }
    // 10. s = mean over spatial of (fl+fg)
    hipMemsetAsync(ssum, 0, 512 * 4, stream);
    k_meanU<<<dim3(32, Bn), 256, 0, stream>>>(fl, fg, ssum);
    // 11. SE head -> softmax weights
    k_se<<<Bn, 256, 0, stream>>>(ssum, fc1_w, fc2_w, w01, dflag);
    // 12. final combine + transpose to (B,C,H,W)
    k_final<<<dim3(Ll / 32, Cc / 32, Bn), dim3(32, 8), 0, stream>>>(fl, fg, w01, d_out, dflag);
}

// Round 6
// 1126.693 us; speedup vs baseline: 7.9945x; 1.5068x over previous
//
#include <hip/hip_runtime.h>
#include <hip/hip_bf16.h>

#define EPSC 1e-5f
#define Bn 2
#define CIN 512
#define Cc 256
#define Hh 48
#define Ww 48
#define Ll 2304
#define DI 512
#define DS 16
#define DTR 16
#define MROWS (Bn * Ll)   // 4608

using bf16 = __hip_bfloat16;

// dual-dtype input load: flag=1 -> bf16, flag=0 -> f32
__device__ __forceinline__ float ldIn(const void* p, size_t i, bool bf) {
    return bf ? __bfloat162float(((const bf16*)p)[i]) : ((const float*)p)[i];
}
__device__ __forceinline__ float toF(float v) { return v; }
__device__ __forceinline__ float toF(bf16 v) { return __bfloat162float(v); }
__device__ __forceinline__ void stO(float* p, float v) { *p = v; }
__device__ __forceinline__ void stO(bf16* p, float v) { *p = __float2bfloat16(v); }
__device__ __forceinline__ float bfu2f(unsigned short u) {
    return __uint_as_float(((unsigned int)u) << 16);
}

template <int DIR>
__device__ __forceinline__ int perm_t(int t) {
    if constexpr (DIR == 0) { return t; }
    else if constexpr (DIR == 1) { return Ll - 1 - t; }
    else {
        int tt = (DIR == 2) ? t : (Ll - 1 - t);
        int h = tt % Hh, w = tt / Hh;
        return h * Ww + w;
    }
}
__device__ __forceinline__ int perm_rt(int dir, int t) {
    if (dir == 0) return t;
    if (dir == 1) return Ll - 1 - t;
    int tt = (dir == 2) ? t : (Ll - 1 - t);
    int h = tt % Hh, w = tt / Hh;   // const divisors -> magic mul
    return h * Ww + w;
}

// ---------------- dtype detector ----------------
__global__ void k_detect(const unsigned int* __restrict__ xb, int* __restrict__ flag) {
    if (threadIdx.x == 0 && blockIdx.x == 0) {
        int cnt = 0;
        for (int i = 0; i < 64; i++) {
            unsigned int u = xb[i];
            unsigned int lo = u & 0xFFFFu;
            int e = (int)((lo >> 7) & 0xFF);
            if (lo == 0u || (e >= 90 && e <= 160)) cnt++;
        }
        *flag = (cnt >= 60) ? 1 : 0;
    }
}

// ---------------- ws-size probe ----------------
__global__ __launch_bounds__(256) void k_probe(bf16* __restrict__ out, int n, float val) {
    int i = blockIdx.x * 256 + threadIdx.x;
    if (i < n) out[i] = __float2bfloat16(val);
}

// ---------------- transpose: x (B, CIN, L) -> xTb (B*L, CIN) bf16 ----------------
__global__ __launch_bounds__(256) void k_transpose_in(const void* __restrict__ x, bf16* __restrict__ xT,
                                                      const int* __restrict__ dflag) {
    bool bf = (*dflag != 0);
    __shared__ float tile[32][33];
    int b = blockIdx.z;
    int l0 = blockIdx.x * 32, c0 = blockIdx.y * 32;
    int tx = threadIdx.x, ty = threadIdx.y;
    #pragma unroll
    for (int i = 0; i < 4; i++) {
        int c = c0 + ty + i * 8;
        tile[ty + i * 8][tx] = ldIn(x, ((size_t)(b * CIN + c)) * Ll + l0 + tx, bf);
    }
    __syncthreads();
    #pragma unroll
    for (int i = 0; i < 4; i++) {
        int l = l0 + ty + i * 8;
        xT[((size_t)(b * Ll + l)) * CIN + c0 + tx] = __float2bfloat16(tile[tx][ty + i * 8]);
    }
}

// ---------------- generic GEMM: Out(M,N) = A(M,K) x W(N,K)^T, epilogues ----------------
// EP: 0 none, 1 bn+relu, 2 bias, 5 batched-dir atomic accumulate 0.25x into fg
template <int EP, typename TA, typename TO>
__global__ __launch_bounds__(256) void k_gemm(const TA* __restrict__ A, const void* __restrict__ W,
                                              TO* __restrict__ Out, int M, int N, int K, int lda,
                                              const void* __restrict__ g, const void* __restrict__ bias,
                                              float* __restrict__ fgOut, const int* __restrict__ dflag) {
    bool bf = (*dflag != 0);
    __shared__ float As[16][64];
    __shared__ float Ws[16][64];
    int tid = threadIdx.x;
    int tx = tid & 15, ty = tid >> 4;
    int row0 = blockIdx.y * 64, col0 = blockIdx.x * 64;
    float acc[4][4] = {};
    for (int k0 = 0; k0 < K; k0 += 16) {
        #pragma unroll
        for (int i = 0; i < 4; i++) {
            int idx = tid + i * 256;
            int kk = idx & 15, mm = idx >> 4;
            As[kk][mm] = toF(A[(size_t)(row0 + mm) * lda + k0 + kk]);
        }
        #pragma unroll
        for (int i = 0; i < 4; i++) {
            int idx = tid + i * 256;
            int kk = idx & 15, nn = idx >> 4;
            int col = col0 + nn;
            Ws[kk][nn] = (col < N) ? ldIn(W, (size_t)col * K + k0 + kk, bf) : 0.f;
        }
        __syncthreads();
        #pragma unroll
        for (int k = 0; k < 16; k++) {
            float a[4], bb[4];
            #pragma unroll
            for (int i = 0; i < 4; i++) a[i] = As[k][ty * 4 + i];
            #pragma unroll
            for (int j = 0; j < 4; j++) bb[j] = Ws[k][tx * 4 + j];
            #pragma unroll
            for (int i = 0; i < 4; i++)
                #pragma unroll
                for (int j = 0; j < 4; j++) acc[i][j] += a[i] * bb[j];
        }
        __syncthreads();
    }
    float rs = rsqrtf(1.f + EPSC);
    #pragma unroll
    for (int i = 0; i < 4; i++) {
        int m = row0 + ty * 4 + i;
        #pragma unroll
        for (int j = 0; j < 4; j++) {
            int n = col0 + tx * 4 + j;
            if (n >= N) continue;
            float v = acc[i][j];
            if (EP == 1) {
                v = v * ldIn(g, n, bf) * rs + ldIn(bias, n, bf);
                v = fmaxf(v, 0.f);
            } else if (EP == 2) {
                v += ldIn(bias, n, bf);
            }
            if (EP == 5) {
                int dir = m / MROWS;
                int rem = m - dir * MROWS;
                int b = rem / Ll;
                int t = rem - b * Ll;
                int l = perm_rt(dir, t);
                atomicAdd(&fgOut[(size_t)(b * Ll + l) * Cc + n], 0.25f * v);
            } else {
                stO(&Out[(size_t)m * N + n], v);
            }
        }
    }
}

// ---------------- LayerNorm over C=256 per row ----------------
__global__ __launch_bounds__(256) void k_ln(const float* __restrict__ xr, const void* __restrict__ g,
                                            const void* __restrict__ bvec, float* __restrict__ xn,
                                            const int* __restrict__ dflag) {
    bool bf = (*dflag != 0);
    int m = blockIdx.x;
    int c = threadIdx.x;
    float v = xr[(size_t)m * Cc + c];
    float s1 = v, s2 = v * v;
    #pragma unroll
    for (int off = 32; off; off >>= 1) {
        s1 += __shfl_down(s1, off);
        s2 += __shfl_down(s2, off);
    }
    __shared__ float a1[4], a2[4];
    int w = c >> 6;
    if ((c & 63) == 0) { a1[w] = s1; a2[w] = s2; }
    __syncthreads();
    float t1 = a1[0] + a1[1] + a1[2] + a1[3];
    float t2 = a2[0] + a2[1] + a2[2] + a2[3];
    float mu = t1 * (1.f / 256.f);
    float var = t2 * (1.f / 256.f) - mu * mu;
    float r = rsqrtf(var + EPSC);
    xn[(size_t)m * Cc + c] = (v - mu) * r * ldIn(g, c, bf) + ldIn(bvec, c, bf);
}

// ---------------- fused depthwise 1x7 + 7x1 convs with bn+relu, summed ----------------
__global__ __launch_bounds__(256) void k_dwconv_hv(const float* __restrict__ p, const void* __restrict__ dwh,
                                                   const void* __restrict__ bnhg, const void* __restrict__ bnhb,
                                                   const void* __restrict__ dwv, const void* __restrict__ bnvg,
                                                   const void* __restrict__ bnvb, float* __restrict__ hv,
                                                   const int* __restrict__ dflag) {
    bool bf = (*dflag != 0);
    int m = blockIdx.x;
    int c = threadIdx.x;
    int b = m / Ll, l = m % Ll;
    int yy = l / Ww, xx = l % Ww;
    const float* base = p + (size_t)b * Ll * Cc;
    float ah = 0.f, av = 0.f;
    #pragma unroll
    for (int j = 0; j < 7; j++) {
        int x2 = xx + j - 3;
        if (0 <= x2 && x2 < Ww) ah += ldIn(dwh, c * 7 + j, bf) * base[(size_t)(yy * Ww + x2) * Cc + c];
        int y2 = yy + j - 3;
        if (0 <= y2 && y2 < Hh) av += ldIn(dwv, c * 7 + j, bf) * base[(size_t)(y2 * Ww + xx) * Cc + c];
    }
    float rs = rsqrtf(1.f + EPSC);
    float out = fmaxf(ah * ldIn(bnhg, c, bf) * rs + ldIn(bnhb, c, bf), 0.f) +
                fmaxf(av * ldIn(bnvg, c, bf) * rs + ldIn(bnvb, c, bf), 0.f);
    hv[(size_t)m * Cc + c] = out;
}

// ---------------- per-direction causal depthwise conv(k=4) + silu ----------------
template <int DIR>
__global__ __launch_bounds__(512) void k_conv1d(const bf16* __restrict__ xz, const void* __restrict__ cw,
                                                const void* __restrict__ cb, bf16* __restrict__ xm2,
                                                const int* __restrict__ dflag) {
    bool bf = (*dflag != 0);
    int m = blockIdx.x;
    int ch = threadIdx.x;
    int b = m / Ll, t = m % Ll;
    float acc = ldIn(cb, ch, bf);
    #pragma unroll
    for (int j = 0; j < 4; j++) {
        int tt = t + j - 3;
        if (tt >= 0) {
            int l = perm_t<DIR>(tt);
            acc += ldIn(cw, ch * 4 + j, bf) * __bfloat162float(xz[((size_t)(b * Ll + l)) * 1024 + ch]);
        }
    }
    xm2[(size_t)m * DI + ch] = __float2bfloat16(acc / (1.f + __expf(-acc)));
}

// ---------------- selective scan v4: all 4 dirs in one launch, dt fused, y in-place ----------------
// grid = 1024 blocks x 64 threads; block: dir(2b) x b(1b) x 128 ch-groups; wave = 4ch x 16 states
__global__ __launch_bounds__(64) void k_scan4(bf16* __restrict__ xm2y, const float* __restrict__ proj4,
                                              const bf16* __restrict__ xz,
                                              const void* __restrict__ A_log, const void* __restrict__ Dp,
                                              const void* __restrict__ dt_w, const void* __restrict__ dt_b,
                                              const int* __restrict__ dflag) {
    bool bf = (*dflag != 0);
    int lane = threadIdx.x;
    int g = lane >> 4, s = lane & 15;
    int blk = blockIdx.x;           // 0..1023
    int dir = blk >> 8;
    int rest = blk & 255;
    int b = rest >> 7;
    int j = rest & 127;
    int ch0 = (j & 15) * 32 + (j >> 4) * 4;   // XCD-line swizzle
    int ch = ch0 + g;

    float Acoef = -__expf(ldIn(A_log, ch * 16 + s, bf));
    float dp   = ldIn(Dp, ch, bf);
    float dtw  = ldIn(dt_w, ch * DTR + s, bf);
    float dtbias = ldIn(dt_b, ch, bf);
    float h = 0.f;

    __shared__ float sproj[2][32 * 48];
    __shared__ uint2 sxm[2][32];
    __shared__ uint2 szz[2][32];

    bf16* xmS = xm2y + ((size_t)dir * MROWS + (size_t)b * Ll) * DI;
    const float* ppS = proj4 + ((size_t)dir * MROWS + (size_t)b * Ll) * 48;
    const bf16* zp = xz + (size_t)b * Ll * 1024 + 512;

    int ttl = lane & 31;
    bool isA = lane < 32;

    // ---- prologue: stage tile 0 ----
    {
        ushort4 rxz;
        if (isA) rxz = *(const ushort4*)(xmS + (size_t)ttl * DI + ch0);
        else {
            int l = perm_rt(dir, ttl);
            rxz = *(const ushort4*)(zp + (size_t)l * 1024 + ch0);
        }
        float4 rp[6];
        #pragma unroll
        for (int k = 0; k < 6; k++) {
            int idx = k * 64 + lane;
            int c = idx >> 5, tt = idx & 31;
            rp[k] = *(const float4*)(ppS + (size_t)tt * 48 + c * 4);
        }
        if (isA) sxm[0][ttl] = *(uint2*)&rxz; else szz[0][ttl] = *(uint2*)&rxz;
        #pragma unroll
        for (int k = 0; k < 6; k++) {
            int idx = k * 64 + lane;
            int c = idx >> 5, tt = idx & 31;
            *(float4*)&sproj[0][tt * 48 + c * 4] = rp[k];
        }
    }
    __syncthreads();

    int buf = 0;
    const int NT = Ll / 32;
    for (int tile = 0; tile < NT; tile++) {
        // ---- prefetch next tile (clamped; last-tile values discarded) ----
        int t0n = (tile < NT - 1) ? (tile + 1) * 32 : tile * 32;
        ushort4 rxz;
        if (isA) rxz = *(const ushort4*)(xmS + (size_t)(t0n + ttl) * DI + ch0);
        else {
            int l = perm_rt(dir, t0n + ttl);
            rxz = *(const ushort4*)(zp + (size_t)l * 1024 + ch0);
        }
        float4 rp[6];
        #pragma unroll
        for (int k = 0; k < 6; k++) {
            int idx = k * 64 + lane;
            int c = idx >> 5, tt = idx & 31;
            rp[k] = *(const float4*)(ppS + (size_t)(t0n + tt) * 48 + c * 4);
        }

        const float* P = sproj[buf];
        const unsigned short* xml = (const unsigned short*)sxm[buf];
        const unsigned short* zl  = (const unsigned short*)szz[buf];
        int tbase = tile * 32;

        // ---- phase 0: dt = softplus(proj_dt @ dt_w^T + dt_b), batched reduce ----
        float dtv[32];
        #pragma unroll
        for (int tt = 0; tt < 32; tt++) dtv[tt] = P[tt * 48 + s] * dtw;
        #pragma unroll
        for (int r = 8; r; r >>= 1) {
            #pragma unroll
            for (int tt = 0; tt < 32; tt++) dtv[tt] += __shfl_xor(dtv[tt], r);
        }
        #pragma unroll
        for (int tt = 0; tt < 32; tt++) {
            float v = dtv[tt] + dtbias;
            dtv[tt] = (v > 20.f) ? v : __logf(1.f + __expf(v));
        }
        // ---- phase 1: h-recurrence; bank h*C ----
        float pc[32];
        #pragma unroll
        for (int tt = 0; tt < 32; tt++) {
            float xv = bfu2f(xml[tt * 4 + g]);
            float Bv = P[tt * 48 + 16 + s];
            float da = __expf(dtv[tt] * Acoef);
            h = fmaf(da, h, dtv[tt] * xv * Bv);
            pc[tt] = h * P[tt * 48 + 32 + s];
        }
        // ---- phase 2: batched 16-lane xor reduction ----
        #pragma unroll
        for (int r = 8; r; r >>= 1) {
            #pragma unroll
            for (int tt = 0; tt < 32; tt++) pc[tt] += __shfl_xor(pc[tt], r);
        }
        // ---- phase 3: write y in-place (2 outputs/lane) ----
        #pragma unroll
        for (int k = 0; k < 2; k++) {
            int tt = s + 16 * k;
            float xv = bfu2f(xml[tt * 4 + g]);
            float zv = bfu2f(zl[tt * 4 + g]);
            float sig = 1.f / (1.f + __expf(-zv));
            xmS[(size_t)(tbase + tt) * DI + ch] = __float2bfloat16((pc[tt] + dp * xv) * zv * sig);
        }

        // ---- commit prefetch into other buffer ----
        int nb = buf ^ 1;
        if (isA) sxm[nb][ttl] = *(uint2*)&rxz; else szz[nb][ttl] = *(uint2*)&rxz;
        #pragma unroll
        for (int k = 0; k < 6; k++) {
            int idx = k * 64 + lane;
            int c = idx >> 5, tt = idx & 31;
            *(float4*)&sproj[nb][tt * 48 + c * 4] = rp[k];
        }
        __syncthreads();
        buf = nb;
    }
}

// ---------------- mean over spatial of (fl+fg) -> ssum (pre-zeroed), atomics ----------------
__global__ __launch_bounds__(256) void k_meanU(const float* __restrict__ fl, const float* __restrict__ fg,
                                               float* __restrict__ ssum) {
    int b = blockIdx.y;
    int chunk = blockIdx.x;
    int c = threadIdx.x;
    float acc = 0.f;
    for (int i = 0; i < 72; i++) {
        int l = chunk * 72 + i;
        size_t off = ((size_t)(b * Ll + l)) * Cc + c;
        acc += fl[off] + fg[off];
    }
    atomicAdd(&ssum[b * Cc + c], acc);
}

// ---------------- SE head ----------------
__global__ __launch_bounds__(256) void k_se(const float* __restrict__ ssum, const void* __restrict__ fc1,
                                            const void* __restrict__ fc2, float* __restrict__ w01,
                                            const int* __restrict__ dflag) {
    bool bf = (*dflag != 0);
    int b = blockIdx.x;
    int c = threadIdx.x;
    __shared__ float sh[256];
    __shared__ float mid[16];
    sh[c] = ssum[b * 256 + c] * (1.f / (float)Ll);
    __syncthreads();
    if (c < 16) {
        float a = 0.f;
        for (int k = 0; k < 256; k++) a += sh[k] * ldIn(fc1, c * 256 + k, bf);
        mid[c] = fmaxf(a, 0.f);
    }
    __syncthreads();
    float a0 = 0.f, a1 = 0.f;
    #pragma unroll
    for (int j = 0; j < 16; j++) {
        float mj = mid[j];
        a0 += mj * ldIn(fc2, c * 16 + j, bf);
        a1 += mj * ldIn(fc2, (256 + c) * 16 + j, bf);
    }
    float mx = fmaxf(a0, a1);
    float e0 = expf(a0 - mx), e1 = expf(a1 - mx);
    float inv = 1.f / (e0 + e1);
    w01[b * 256 + c] = e0 * inv;
    w01[512 + b * 256 + c] = e1 * inv;
}

// ---------------- final combine + transpose to (B,C,H,W) ----------------
__global__ __launch_bounds__(256) void k_final(const float* __restrict__ fl, const float* __restrict__ fg,
                                               const float* __restrict__ w01, void* __restrict__ out,
                                               const int* __restrict__ dflag) {
    bool bf = (*dflag != 0);
    __shared__ float tile[32][33];
    int b = blockIdx.z;
    int l0 = blockIdx.x * 32, c0 = blockIdx.y * 32;
    int tx = threadIdx.x, ty = threadIdx.y;
    #pragma unroll
    for (int i = 0; i < 4; i++) {
        int l = l0 + ty + i * 8;
        int c = c0 + tx;
        size_t off = ((size_t)(b * Ll + l)) * Cc + c;
        tile[ty + i * 8][tx] = w01[b * 256 + c] * fl[off] + w01[512 + b * 256 + c] * fg[off];
    }
    __syncthreads();
    #pragma unroll
    for (int i = 0; i < 4; i++) {
        int c = c0 + ty + i * 8;
        size_t off = ((size_t)(b * Cc + c)) * Ll + l0 + tx;
        float v = tile[tx][ty + i * 8];
        if (bf) ((bf16*)out)[off] = __float2bfloat16(v);
        else    ((float*)out)[off] = v;
    }
}

extern "C" void kernel_launch(void* const* d_in, const int* in_sizes, int n_in,
                              void* d_out, int out_size, void* d_ws, size_t ws_size,
                              hipStream_t stream) {
    const void* x        = d_in[0];
    const void* reduce_w = d_in[1];
    const void* bn0_g    = d_in[2];
    const void* bn0_b    = d_in[3];
    const void* proj_w   = d_in[4];
    const void* bn1_g    = d_in[5];
    const void* bn1_b    = d_in[6];
    const void* dwh_w    = d_in[7];
    const void* bnh_g    = d_in[8];
    const void* bnh_b    = d_in[9];
    const void* dwv_w    = d_in[10];
    const void* bnv_g    = d_in[11];
    const void* bnv_b    = d_in[12];
    const void* fus_w    = d_in[13];
    const void* fus_b    = d_in[14];
    const void* ln_g     = d_in[15];
    const void* ln_b     = d_in[16];
    const void* in_w     = d_in[17];
    const void* conv_w   = d_in[18];
    const void* conv_b   = d_in[19];
    const void* xproj_w  = d_in[20];
    const void* dt_w     = d_in[21];
    const void* dt_b     = d_in[22];
    const void* A_log    = d_in[23];
    const void* Dp       = d_in[24];
    const void* out_w    = d_in[25];
    const void* fc1_w    = d_in[26];
    const void* fc2_w    = d_in[27];

    // ---- workspace layout (f32 slots), total 39.4 MB ----
    float* ws = (float*)d_ws;
    float* fl     = ws;                        // 1179648
    float* fg     = ws + 1179648;              // 1179648
    bf16*  xz     = (bf16*)(ws + 2359296);     // 4718592 bf16
    float* proj4  = ws + 4718592;              // 884736 f32  [dir][b*t][48]
    bf16*  xm2y   = (bf16*)(ws + 5603328);     // 9437184 bf16 [dir][b*t][512] (xm2 in, y in-place)
    float* xr     = ws + 5603328;              // transient (dead before conv1d)
    float* scrD   = ws + 6782976;              // transient: p, then xn
    float* scrE   = ws + 7962624;              // transient: xTb, then hv
    float* ssum   = ws + 10321920;             // 512
    float* w01    = ws + 10322432;             // 1024
    int*   dflag  = (int*)(ws + 10323456);     // 1
    const size_t needed = 10323457ULL * 4ULL;

    if (ws_size < needed) {
        float val = 1000.0f + (float)(ws_size >> 20);
        k_probe<<<(out_size + 255) / 256, 256, 0, stream>>>((bf16*)d_out, out_size, val);
        return;
    }

    bf16* xTb = (bf16*)scrE;
    float* p  = scrD;
    float* hv = scrE;
    float* xn = scrD;

    // 0. detect input dtype
    k_detect<<<1, 64, 0, stream>>>((const unsigned int*)x, dflag);
    // 1. transpose x -> xTb
    k_transpose_in<<<dim3(Ll / 32, CIN / 32, Bn), dim3(32, 8), 0, stream>>>(x, xTb, dflag);
    // 2. xr = relu(bn0(xTb @ reduce_w^T))
    k_gemm<1, bf16, float><<<dim3(4, MROWS / 64), 256, 0, stream>>>(xTb, reduce_w, xr, MROWS, Cc, CIN, CIN, bn0_g, bn0_b, nullptr, dflag);
    // 3. p = relu(bn1(xr @ proj_w^T))
    k_gemm<1, float, float><<<dim3(4, MROWS / 64), 256, 0, stream>>>(xr, proj_w, p, MROWS, Cc, Cc, Cc, bn1_g, bn1_b, nullptr, dflag);
    // 4. hv = relu(bnh(dwh)) + relu(bnv(dwv))
    k_dwconv_hv<<<MROWS, 256, 0, stream>>>(p, dwh_w, bnh_g, bnh_b, dwv_w, bnv_g, bnv_b, hv, dflag);
    // 5. fl = hv @ fus_w^T + fus_b
    k_gemm<2, float, float><<<dim3(4, MROWS / 64), 256, 0, stream>>>(hv, fus_w, fl, MROWS, Cc, Cc, Cc, nullptr, fus_b, nullptr, dflag);
    // 6. xn = LN(xr)
    k_ln<<<MROWS, 256, 0, stream>>>(xr, ln_g, ln_b, xn, dflag);
    // 7. xz = xn @ in_w^T
    k_gemm<0, float, bf16><<<dim3(16, MROWS / 64), 256, 0, stream>>>(xn, in_w, xz, MROWS, 2 * DI, Cc, Cc, nullptr, nullptr, nullptr, dflag);
    // 8. fg = xr (residual); xr/scrD/scrE dead after this
    hipMemcpyAsync(fg, xr, (size_t)1179648 * 4, hipMemcpyDeviceToDevice, stream);
    // 9. conv1d per dir -> xm2y slices
    k_conv1d<0><<<MROWS, 512, 0, stream>>>(xz, conv_w, conv_b, xm2y + 0ULL * MROWS * DI, dflag);
    k_conv1d<1><<<MROWS, 512, 0, stream>>>(xz, conv_w, conv_b, xm2y + 1ULL * MROWS * DI, dflag);
    k_conv1d<2><<<MROWS, 512, 0, stream>>>(xz, conv_w, conv_b, xm2y + 2ULL * MROWS * DI, dflag);
    k_conv1d<3><<<MROWS, 512, 0, stream>>>(xz, conv_w, conv_b, xm2y + 3ULL * MROWS * DI, dflag);
    // 10. batched xproj: proj4 = xm2y @ xproj_w^T  (M = 4*4608)
    k_gemm<0, bf16, float><<<dim3(1, 4 * MROWS / 64), 256, 0, stream>>>(xm2y, xproj_w, proj4, 4 * MROWS, DTR + 2 * DS, DI, DI, nullptr, nullptr, nullptr, dflag);
    // 11. scan all 4 dirs in one launch (dt fused, y in-place)
    k_scan4<<<1024, 64, 0, stream>>>(xm2y, proj4, xz, A_log, Dp, dt_w, dt_b, dflag);
    // 12. batched out-proj: fg += 0.25 * (y @ out_w^T) at permuted rows (atomic)
    k_gemm<5, bf16, float><<<dim3(4, 4 * MROWS / 64), 256, 0, stream>>>(xm2y, out_w, (float*)nullptr, 4 * MROWS, Cc, DI, DI, nullptr, nullptr, fg, dflag);
    // 13. SE head + final
    hipMemsetAsync(ssum, 0, 512 * 4, stream);
    k_meanU<<<dim3(32, Bn), 256, 0, stream>>>(fl, fg, ssum);
    k_se<<<Bn, 256, 0, stream>>>(ssum, fc1_w, fc2_w, w01, dflag);
    k_final<<<dim3(Ll / 32, Cc / 32, Bn), dim3(32, 8), 0, stream>>>(fl, fg, w01, d_out, dflag);
}

// Round 7
// 892.627 us; speedup vs baseline: 10.0908x; 1.2622x over previous
//
#include <hip/hip_runtime.h>
#include <hip/hip_bf16.h>

#define EPSC 1e-5f
#define Bn 2
#define CIN 512
#define Cc 256
#define Hh 48
#define Ww 48
#define Ll 2304
#define DI 512
#define DS 16
#define DTR 16
#define MROWS (Bn * Ll)   // 4608

using bf16 = __hip_bfloat16;
typedef short v8s __attribute__((ext_vector_type(8)));
typedef float v4f __attribute__((ext_vector_type(4)));

__device__ __forceinline__ float ldIn(const void* p, size_t i, bool bf) {
    return bf ? __bfloat162float(((const bf16*)p)[i]) : ((const float*)p)[i];
}
__device__ __forceinline__ float toF(float v) { return v; }
__device__ __forceinline__ float toF(bf16 v) { return __bfloat162float(v); }
__device__ __forceinline__ void stO(float* p, float v) { *p = v; }
__device__ __forceinline__ void stO(bf16* p, float v) { *p = __float2bfloat16(v); }
__device__ __forceinline__ float bfu2f(unsigned short u) {
    return __uint_as_float(((unsigned int)u) << 16);
}
__device__ __forceinline__ short f2bs(float f) {
    bf16 h = __float2bfloat16(f);
    short s;
    __builtin_memcpy(&s, &h, 2);
    return s;
}
union U16B { uint4 u; v8s v; };
__device__ __forceinline__ v8s ldA8(const bf16* p) { U16B t; t.u = *(const uint4*)p; return t.v; }
__device__ __forceinline__ v8s ldW8(const void* W, size_t idx, bool bf) {
    if (bf) return ldA8((const bf16*)W + idx);
    const float* f = (const float*)W + idx;
    float4 a = *(const float4*)f;
    float4 b = *(const float4*)(f + 4);
    v8s r;
    r[0] = f2bs(a.x); r[1] = f2bs(a.y); r[2] = f2bs(a.z); r[3] = f2bs(a.w);
    r[4] = f2bs(b.x); r[5] = f2bs(b.y); r[6] = f2bs(b.z); r[7] = f2bs(b.w);
    return r;
}

template <int DIR>
__device__ __forceinline__ int perm_t(int t) {
    if constexpr (DIR == 0) { return t; }
    else if constexpr (DIR == 1) { return Ll - 1 - t; }
    else {
        int tt = (DIR == 2) ? t : (Ll - 1 - t);
        int h = tt % Hh, w = tt / Hh;
        return h * Ww + w;
    }
}
__device__ __forceinline__ int perm_rt(int dir, int t) {
    if (dir == 0) return t;
    if (dir == 1) return Ll - 1 - t;
    int tt = (dir == 2) ? t : (Ll - 1 - t);
    int h = tt % Hh, w = tt / Hh;
    return h * Ww + w;
}

// ---------------- dtype detector ----------------
__global__ void k_detect(const unsigned int* __restrict__ xb, int* __restrict__ flag) {
    if (threadIdx.x == 0 && blockIdx.x == 0) {
        int cnt = 0;
        for (int i = 0; i < 64; i++) {
            unsigned int u = xb[i];
            unsigned int lo = u & 0xFFFFu;
            int e = (int)((lo >> 7) & 0xFF);
            if (lo == 0u || (e >= 90 && e <= 160)) cnt++;
        }
        *flag = (cnt >= 60) ? 1 : 0;
    }
}

// ---------------- ws-size probe ----------------
__global__ __launch_bounds__(256) void k_probe(bf16* __restrict__ out, int n, float val) {
    int i = blockIdx.x * 256 + threadIdx.x;
    if (i < n) out[i] = __float2bfloat16(val);
}

// ---------------- transpose: x (B, CIN, L) -> xTb (B*L, CIN) bf16 ----------------
__global__ __launch_bounds__(256) void k_transpose_in(const void* __restrict__ x, bf16* __restrict__ xT,
                                                      const int* __restrict__ dflag) {
    bool bf = (*dflag != 0);
    __shared__ float tile[32][33];
    int b = blockIdx.z;
    int l0 = blockIdx.x * 32, c0 = blockIdx.y * 32;
    int tx = threadIdx.x, ty = threadIdx.y;
    #pragma unroll
    for (int i = 0; i < 4; i++) {
        int c = c0 + ty + i * 8;
        tile[ty + i * 8][tx] = ldIn(x, ((size_t)(b * CIN + c)) * Ll + l0 + tx, bf);
    }
    __syncthreads();
    #pragma unroll
    for (int i = 0; i < 4; i++) {
        int l = l0 + ty + i * 8;
        xT[((size_t)(b * Ll + l)) * CIN + c0 + tx] = __float2bfloat16(tile[tx][ty + i * 8]);
    }
}

// ---------------- MFMA GEMM: Out(M,N) = A(M,K)bf16 x W(N,K)^T ----------------
// block = 256 thr = 4 waves stacked in M (tile 128xM, 64xN); wave tile 32x64 = 2x4 frags
// EP: 0 plain, 1 bn+relu, 2 bias
template <int EP, int KT, typename TO>
__global__ __launch_bounds__(256) void k_mgemm(const bf16* __restrict__ A, const void* __restrict__ W,
                                               TO* __restrict__ Out, int M, int N,
                                               const void* __restrict__ g, const void* __restrict__ bias,
                                               const int* __restrict__ dflag) {
    bool bf = (*dflag != 0);
    constexpr int K = KT * 32;
    int tid = threadIdx.x;
    int w = tid >> 6, lane = tid & 63, quad = lane >> 4, lm = lane & 15;
    int m_w = blockIdx.y * 128 + w * 32;
    int n_w = blockIdx.x * 64;
    v4f acc[2][4] = {};
    const bf16* aP0 = A + (size_t)(m_w + lm) * K + quad * 8;
    const bf16* aP1 = A + (size_t)(m_w + 16 + lm) * K + quad * 8;
    size_t wIdx[4];
    #pragma unroll
    for (int ni = 0; ni < 4; ni++) {
        int n = n_w + ni * 16 + lm;
        wIdx[ni] = (size_t)((n < N) ? n : 0) * K + quad * 8;
    }
    for (int kt = 0; kt < KT; kt++) {
        v8s a0 = ldA8(aP0 + kt * 32);
        v8s a1 = ldA8(aP1 + kt * 32);
        v8s bfr[4];
        #pragma unroll
        for (int ni = 0; ni < 4; ni++) bfr[ni] = ldW8(W, wIdx[ni] + kt * 32, bf);
        #pragma unroll
        for (int ni = 0; ni < 4; ni++) {
            acc[0][ni] = __builtin_amdgcn_mfma_f32_16x16x32_bf16(a0, bfr[ni], acc[0][ni], 0, 0, 0);
            acc[1][ni] = __builtin_amdgcn_mfma_f32_16x16x32_bf16(a1, bfr[ni], acc[1][ni], 0, 0, 0);
        }
    }
    float rs = rsqrtf(1.f + EPSC);
    #pragma unroll
    for (int mi = 0; mi < 2; mi++) {
        #pragma unroll
        for (int ni = 0; ni < 4; ni++) {
            int col = n_w + ni * 16 + lm;
            if (col >= N) continue;
            float gv = 0.f, bv = 0.f;
            if (EP == 1) { gv = ldIn(g, col, bf) * rs; bv = ldIn(bias, col, bf); }
            if (EP == 2) { bv = ldIn(bias, col, bf); }
            #pragma unroll
            for (int r = 0; r < 4; r++) {
                int row = m_w + mi * 16 + quad * 4 + r;
                float v = acc[mi][ni][r];
                if (EP == 1) v = fmaxf(v * gv + bv, 0.f);
                else if (EP == 2) v += bv;
                stO(&Out[(size_t)row * N + col], v);
            }
        }
    }
}

// ---------------- fused out-proj: fg = xrb + 0.25 * sum_dir y_dir(perm^-1) @ out_w^T ----------------
__global__ __launch_bounds__(256) void k_outgemm(const bf16* __restrict__ Y, const void* __restrict__ W,
                                                 const bf16* __restrict__ xrb, float* __restrict__ fg,
                                                 const int* __restrict__ dflag) {
    bool bf = (*dflag != 0);
    int tid = threadIdx.x;
    int w = tid >> 6, lane = tid & 63, quad = lane >> 4, lm = lane & 15;
    int row0 = blockIdx.y * 128 + w * 32;    // global (b*Ll + l), tiles never cross b
    int n_w = blockIdx.x * 64;
    int b = row0 / Ll;
    v4f acc[2][4] = {};
    const bf16* aP[4][2];
    #pragma unroll
    for (int mi = 0; mi < 2; mi++) {
        int l = (row0 + mi * 16 + lm) - b * Ll;
        int h = l / Ww, w2 = l % Ww;
        int t2 = w2 * Hh + h;
        int tArr[4] = { l, Ll - 1 - l, t2, Ll - 1 - t2 };
        #pragma unroll
        for (int dir = 0; dir < 4; dir++)
            aP[dir][mi] = Y + ((size_t)dir * MROWS + (size_t)b * Ll + tArr[dir]) * DI + quad * 8;
    }
    size_t wIdx[4];
    #pragma unroll
    for (int ni = 0; ni < 4; ni++) wIdx[ni] = (size_t)(n_w + ni * 16 + lm) * DI + quad * 8;
    for (int kt = 0; kt < 16; kt++) {
        v8s bfr[4];
        #pragma unroll
        for (int ni = 0; ni < 4; ni++) bfr[ni] = ldW8(W, wIdx[ni] + kt * 32, bf);
        #pragma unroll
        for (int dir = 0; dir < 4; dir++) {
            v8s a0 = ldA8(aP[dir][0] + kt * 32);
            v8s a1 = ldA8(aP[dir][1] + kt * 32);
            #pragma unroll
            for (int ni = 0; ni < 4; ni++) {
                acc[0][ni] = __builtin_amdgcn_mfma_f32_16x16x32_bf16(a0, bfr[ni], acc[0][ni], 0, 0, 0);
                acc[1][ni] = __builtin_amdgcn_mfma_f32_16x16x32_bf16(a1, bfr[ni], acc[1][ni], 0, 0, 0);
            }
        }
    }
    #pragma unroll
    for (int mi = 0; mi < 2; mi++) {
        #pragma unroll
        for (int ni = 0; ni < 4; ni++) {
            int col = n_w + ni * 16 + lm;
            #pragma unroll
            for (int r = 0; r < 4; r++) {
                int row = row0 + mi * 16 + quad * 4 + r;
                size_t off = (size_t)row * Cc + col;
                fg[off] = toF(xrb[off]) + 0.25f * acc[mi][ni][r];
            }
        }
    }
}

// ---------------- LayerNorm over C=256 per row (bf16 in/out) ----------------
__global__ __launch_bounds__(256) void k_ln(const bf16* __restrict__ xrb, const void* __restrict__ g,
                                            const void* __restrict__ bvec, bf16* __restrict__ xn,
                                            const int* __restrict__ dflag) {
    bool bf = (*dflag != 0);
    int m = blockIdx.x;
    int c = threadIdx.x;
    float v = toF(xrb[(size_t)m * Cc + c]);
    float s1 = v, s2 = v * v;
    #pragma unroll
    for (int off = 32; off; off >>= 1) {
        s1 += __shfl_down(s1, off);
        s2 += __shfl_down(s2, off);
    }
    __shared__ float a1[4], a2[4];
    int w = c >> 6;
    if ((c & 63) == 0) { a1[w] = s1; a2[w] = s2; }
    __syncthreads();
    float t1 = a1[0] + a1[1] + a1[2] + a1[3];
    float t2 = a2[0] + a2[1] + a2[2] + a2[3];
    float mu = t1 * (1.f / 256.f);
    float var = t2 * (1.f / 256.f) - mu * mu;
    float r = rsqrtf(var + EPSC);
    xn[(size_t)m * Cc + c] = __float2bfloat16((v - mu) * r * ldIn(g, c, bf) + ldIn(bvec, c, bf));
}

// ---------------- fused depthwise 1x7 + 7x1 convs with bn+relu (bf16 in/out) ----------------
__global__ __launch_bounds__(256) void k_dwconv_hv(const bf16* __restrict__ p, const void* __restrict__ dwh,
                                                   const void* __restrict__ bnhg, const void* __restrict__ bnhb,
                                                   const void* __restrict__ dwv, const void* __restrict__ bnvg,
                                                   const void* __restrict__ bnvb, bf16* __restrict__ hv,
                                                   const int* __restrict__ dflag) {
    bool bf = (*dflag != 0);
    int m = blockIdx.x;
    int c = threadIdx.x;
    int b = m / Ll, l = m % Ll;
    int yy = l / Ww, xx = l % Ww;
    const bf16* base = p + (size_t)b * Ll * Cc;
    float ah = 0.f, av = 0.f;
    #pragma unroll
    for (int j = 0; j < 7; j++) {
        int x2 = xx + j - 3;
        if (0 <= x2 && x2 < Ww) ah += ldIn(dwh, c * 7 + j, bf) * toF(base[(size_t)(yy * Ww + x2) * Cc + c]);
        int y2 = yy + j - 3;
        if (0 <= y2 && y2 < Hh) av += ldIn(dwv, c * 7 + j, bf) * toF(base[(size_t)(y2 * Ww + xx) * Cc + c]);
    }
    float rs = rsqrtf(1.f + EPSC);
    float out = fmaxf(ah * ldIn(bnhg, c, bf) * rs + ldIn(bnhb, c, bf), 0.f) +
                fmaxf(av * ldIn(bnvg, c, bf) * rs + ldIn(bnvb, c, bf), 0.f);
    hv[(size_t)m * Cc + c] = __float2bfloat16(out);
}

// ---------------- per-direction causal depthwise conv(k=4) + silu ----------------
template <int DIR>
__global__ __launch_bounds__(512) void k_conv1d(const bf16* __restrict__ xz, const void* __restrict__ cw,
                                                const void* __restrict__ cb, bf16* __restrict__ xm2,
                                                const int* __restrict__ dflag) {
    bool bf = (*dflag != 0);
    int m = blockIdx.x;
    int ch = threadIdx.x;
    int b = m / Ll, t = m % Ll;
    float acc = ldIn(cb, ch, bf);
    #pragma unroll
    for (int j = 0; j < 4; j++) {
        int tt = t + j - 3;
        if (tt >= 0) {
            int l = perm_t<DIR>(tt);
            acc += ldIn(cw, ch * 4 + j, bf) * __bfloat162float(xz[((size_t)(b * Ll + l)) * 1024 + ch]);
        }
    }
    xm2[(size_t)m * DI + ch] = __float2bfloat16(acc / (1.f + __expf(-acc)));
}

// ---------------- selective scan v4: all 4 dirs, dt fused, y in-place ----------------
__global__ __launch_bounds__(64) void k_scan4(bf16* __restrict__ xm2y, const float* __restrict__ proj4,
                                              const bf16* __restrict__ xz,
                                              const void* __restrict__ A_log, const void* __restrict__ Dp,
                                              const void* __restrict__ dt_w, const void* __restrict__ dt_b,
                                              const int* __restrict__ dflag) {
    bool bf = (*dflag != 0);
    int lane = threadIdx.x;
    int g = lane >> 4, s = lane & 15;
    int blk = blockIdx.x;
    int dir = blk >> 8;
    int rest = blk & 255;
    int b = rest >> 7;
    int j = rest & 127;
    int ch0 = (j & 15) * 32 + (j >> 4) * 4;
    int ch = ch0 + g;

    float Acoef = -__expf(ldIn(A_log, ch * 16 + s, bf));
    float dp   = ldIn(Dp, ch, bf);
    float dtw  = ldIn(dt_w, ch * DTR + s, bf);
    float dtbias = ldIn(dt_b, ch, bf);
    float h = 0.f;

    __shared__ float sproj[2][32 * 48];
    __shared__ uint2 sxm[2][32];
    __shared__ uint2 szz[2][32];

    bf16* xmS = xm2y + ((size_t)dir * MROWS + (size_t)b * Ll) * DI;
    const float* ppS = proj4 + ((size_t)dir * MROWS + (size_t)b * Ll) * 48;
    const bf16* zp = xz + (size_t)b * Ll * 1024 + 512;

    int ttl = lane & 31;
    bool isA = lane < 32;

    {
        ushort4 rxz;
        if (isA) rxz = *(const ushort4*)(xmS + (size_t)ttl * DI + ch0);
        else {
            int l = perm_rt(dir, ttl);
            rxz = *(const ushort4*)(zp + (size_t)l * 1024 + ch0);
        }
        float4 rp[6];
        #pragma unroll
        for (int k = 0; k < 6; k++) {
            int idx = k * 64 + lane;
            int c = idx >> 5, tt = idx & 31;
            rp[k] = *(const float4*)(ppS + (size_t)tt * 48 + c * 4);
        }
        if (isA) sxm[0][ttl] = *(uint2*)&rxz; else szz[0][ttl] = *(uint2*)&rxz;
        #pragma unroll
        for (int k = 0; k < 6; k++) {
            int idx = k * 64 + lane;
            int c = idx >> 5, tt = idx & 31;
            *(float4*)&sproj[0][tt * 48 + c * 4] = rp[k];
        }
    }
    __syncthreads();

    int buf = 0;
    const int NT = Ll / 32;
    for (int tile = 0; tile < NT; tile++) {
        int t0n = (tile < NT - 1) ? (tile + 1) * 32 : tile * 32;
        ushort4 rxz;
        if (isA) rxz = *(const ushort4*)(xmS + (size_t)(t0n + ttl) * DI + ch0);
        else {
            int l = perm_rt(dir, t0n + ttl);
            rxz = *(const ushort4*)(zp + (size_t)l * 1024 + ch0);
        }
        float4 rp[6];
        #pragma unroll
        for (int k = 0; k < 6; k++) {
            int idx = k * 64 + lane;
            int c = idx >> 5, tt = idx & 31;
            rp[k] = *(const float4*)(ppS + (size_t)(t0n + tt) * 48 + c * 4);
        }

        const float* P = sproj[buf];
        const unsigned short* xml = (const unsigned short*)sxm[buf];
        const unsigned short* zl  = (const unsigned short*)szz[buf];
        int tbase = tile * 32;

        float dtv[32];
        #pragma unroll
        for (int tt = 0; tt < 32; tt++) dtv[tt] = P[tt * 48 + s] * dtw;
        #pragma unroll
        for (int r = 8; r; r >>= 1) {
            #pragma unroll
            for (int tt = 0; tt < 32; tt++) dtv[tt] += __shfl_xor(dtv[tt], r);
        }
        #pragma unroll
        for (int tt = 0; tt < 32; tt++) {
            float v = dtv[tt] + dtbias;
            dtv[tt] = (v > 20.f) ? v : __logf(1.f + __expf(v));
        }
        float pc[32];
        #pragma unroll
        for (int tt = 0; tt < 32; tt++) {
            float xv = bfu2f(xml[tt * 4 + g]);
            float Bv = P[tt * 48 + 16 + s];
            float da = __expf(dtv[tt] * Acoef);
            h = fmaf(da, h, dtv[tt] * xv * Bv);
            pc[tt] = h * P[tt * 48 + 32 + s];
        }
        #pragma unroll
        for (int r = 8; r; r >>= 1) {
            #pragma unroll
            for (int tt = 0; tt < 32; tt++) pc[tt] += __shfl_xor(pc[tt], r);
        }
        #pragma unroll
        for (int k = 0; k < 2; k++) {
            int tt = s + 16 * k;
            float xv = bfu2f(xml[tt * 4 + g]);
            float zv = bfu2f(zl[tt * 4 + g]);
            float sig = 1.f / (1.f + __expf(-zv));
            xmS[(size_t)(tbase + tt) * DI + ch] = __float2bfloat16((pc[tt] + dp * xv) * zv * sig);
        }

        int nb = buf ^ 1;
        if (isA) sxm[nb][ttl] = *(uint2*)&rxz; else szz[nb][ttl] = *(uint2*)&rxz;
        #pragma unroll
        for (int k = 0; k < 6; k++) {
            int idx = k * 64 + lane;
            int c = idx >> 5, tt = idx & 31;
            *(float4*)&sproj[nb][tt * 48 + c * 4] = rp[k];
        }
        __syncthreads();
        buf = nb;
    }
}

// ---------------- mean over spatial of (fl+fg) -> ssum (pre-zeroed), atomics ----------------
__global__ __launch_bounds__(256) void k_meanU(const bf16* __restrict__ fl, const float* __restrict__ fg,
                                               float* __restrict__ ssum) {
    int b = blockIdx.y;
    int chunk = blockIdx.x;
    int c = threadIdx.x;
    float acc = 0.f;
    for (int i = 0; i < 72; i++) {
        int l = chunk * 72 + i;
        size_t off = ((size_t)(b * Ll + l)) * Cc + c;
        acc += toF(fl[off]) + fg[off];
    }
    atomicAdd(&ssum[b * Cc + c], acc);
}

// ---------------- SE head ----------------
__global__ __launch_bounds__(256) void k_se(const float* __restrict__ ssum, const void* __restrict__ fc1,
                                            const void* __restrict__ fc2, float* __restrict__ w01,
                                            const int* __restrict__ dflag) {
    bool bf = (*dflag != 0);
    int b = blockIdx.x;
    int c = threadIdx.x;
    __shared__ float sh[256];
    __shared__ float mid[16];
    sh[c] = ssum[b * 256 + c] * (1.f / (float)Ll);
    __syncthreads();
    if (c < 16) {
        float a = 0.f;
        for (int k = 0; k < 256; k++) a += sh[k] * ldIn(fc1, c * 256 + k, bf);
        mid[c] = fmaxf(a, 0.f);
    }
    __syncthreads();
    float a0 = 0.f, a1 = 0.f;
    #pragma unroll
    for (int j = 0; j < 16; j++) {
        float mj = mid[j];
        a0 += mj * ldIn(fc2, c * 16 + j, bf);
        a1 += mj * ldIn(fc2, (256 + c) * 16 + j, bf);
    }
    float mx = fmaxf(a0, a1);
    float e0 = expf(a0 - mx), e1 = expf(a1 - mx);
    float inv = 1.f / (e0 + e1);
    w01[b * 256 + c] = e0 * inv;
    w01[512 + b * 256 + c] = e1 * inv;
}

// ---------------- final combine + transpose to (B,C,H,W) ----------------
__global__ __launch_bounds__(256) void k_final(const bf16* __restrict__ fl, const float* __restrict__ fg,
                                               const float* __restrict__ w01, void* __restrict__ out,
                                               const int* __restrict__ dflag) {
    bool bf = (*dflag != 0);
    __shared__ float tile[32][33];
    int b = blockIdx.z;
    int l0 = blockIdx.x * 32, c0 = blockIdx.y * 32;
    int tx = threadIdx.x, ty = threadIdx.y;
    #pragma unroll
    for (int i = 0; i < 4; i++) {
        int l = l0 + ty + i * 8;
        int c = c0 + tx;
        size_t off = ((size_t)(b * Ll + l)) * Cc + c;
        tile[ty + i * 8][tx] = w01[b * 256 + c] * toF(fl[off]) + w01[512 + b * 256 + c] * fg[off];
    }
    __syncthreads();
    #pragma unroll
    for (int i = 0; i < 4; i++) {
        int c = c0 + ty + i * 8;
        size_t off = ((size_t)(b * Cc + c)) * Ll + l0 + tx;
        float v = tile[tx][ty + i * 8];
        if (bf) ((bf16*)out)[off] = __float2bfloat16(v);
        else    ((float*)out)[off] = v;
    }
}

extern "C" void kernel_launch(void* const* d_in, const int* in_sizes, int n_in,
                              void* d_out, int out_size, void* d_ws, size_t ws_size,
                              hipStream_t stream) {
    const void* x        = d_in[0];
    const void* reduce_w = d_in[1];
    const void* bn0_g    = d_in[2];
    const void* bn0_b    = d_in[3];
    const void* proj_w   = d_in[4];
    const void* bn1_g    = d_in[5];
    const void* bn1_b    = d_in[6];
    const void* dwh_w    = d_in[7];
    const void* bnh_g    = d_in[8];
    const void* bnh_b    = d_in[9];
    const void* dwv_w    = d_in[10];
    const void* bnv_g    = d_in[11];
    const void* bnv_b    = d_in[12];
    const void* fus_w    = d_in[13];
    const void* fus_b    = d_in[14];
    const void* ln_g     = d_in[15];
    const void* ln_b     = d_in[16];
    const void* in_w     = d_in[17];
    const void* conv_w   = d_in[18];
    const void* conv_b   = d_in[19];
    const void* xproj_w  = d_in[20];
    const void* dt_w     = d_in[21];
    const void* dt_b     = d_in[22];
    const void* A_log    = d_in[23];
    const void* Dp       = d_in[24];
    const void* out_w    = d_in[25];
    const void* fc1_w    = d_in[26];
    const void* fc2_w    = d_in[27];

    // ---- workspace layout (f32 slots), total 43.7 MB ----
    float* ws = (float*)d_ws;
    bf16*  fl     = (bf16*)ws;                   // 1179648 bf16 (589824 slots)
    float* fg     = ws + 589824;                 // 1179648 f32
    bf16*  xrb    = (bf16*)(ws + 1769472);       // 1179648 bf16 (589824 slots)
    bf16*  xz     = (bf16*)(ws + 2359296);       // 4718592 bf16 (2359296 slots)
    float* proj4  = ws + 4718592;                // 884736 f32
    bf16*  xm2y   = (bf16*)(ws + 5603328);       // 9437184 bf16 (4718592 slots); hosts xTb/hvb earlier
    bf16*  pbxnb  = (bf16*)(ws + 10321920);      // 1179648 bf16 (589824 slots); pb then xnb
    float* ssum   = ws + 10911744;               // 512
    float* w01    = ws + 10912256;               // 1024
    int*   dflag  = (int*)(ws + 10913280);       // 1
    const size_t needed = 10913281ULL * 4ULL;

    if (ws_size < needed) {
        float val = 1000.0f + (float)(ws_size >> 20);
        k_probe<<<(out_size + 255) / 256, 256, 0, stream>>>((bf16*)d_out, out_size, val);
        return;
    }

    bf16* xTb = (bf16*)xm2y;   // transient (steps 1-2), dead before hvb/xm2y
    bf16* hvb = (bf16*)xm2y;   // transient (steps 4-5), dead before conv1d writes xm2y
    bf16* pb  = pbxnb;         // steps 3-4
    bf16* xnb = pbxnb;         // steps 6-7 (pb dead)

    // 0. detect input dtype
    k_detect<<<1, 64, 0, stream>>>((const unsigned int*)x, dflag);
    // 1. transpose x -> xTb
    k_transpose_in<<<dim3(Ll / 32, CIN / 32, Bn), dim3(32, 8), 0, stream>>>(x, xTb, dflag);
    // 2. xrb = relu(bn0(xTb @ reduce_w^T))   [MFMA, K=512]
    k_mgemm<1, 16, bf16><<<dim3(4, MROWS / 128), 256, 0, stream>>>(xTb, reduce_w, xrb, MROWS, Cc, bn0_g, bn0_b, dflag);
    // 3. pb = relu(bn1(xrb @ proj_w^T))      [MFMA, K=256]
    k_mgemm<1, 8, bf16><<<dim3(4, MROWS / 128), 256, 0, stream>>>(xrb, proj_w, pb, MROWS, Cc, bn1_g, bn1_b, dflag);
    // 4. hvb = relu(bnh(dwh)) + relu(bnv(dwv))
    k_dwconv_hv<<<MROWS, 256, 0, stream>>>(pb, dwh_w, bnh_g, bnh_b, dwv_w, bnv_g, bnv_b, hvb, dflag);
    // 5. fl = hvb @ fus_w^T + fus_b          [MFMA, K=256]
    k_mgemm<2, 8, bf16><<<dim3(4, MROWS / 128), 256, 0, stream>>>(hvb, fus_w, fl, MROWS, Cc, nullptr, fus_b, dflag);
    // 6. xnb = LN(xrb)
    k_ln<<<MROWS, 256, 0, stream>>>(xrb, ln_g, ln_b, xnb, dflag);
    // 7. xz = xnb @ in_w^T                   [MFMA, K=256, N=1024]
    k_mgemm<0, 8, bf16><<<dim3(16, MROWS / 128), 256, 0, stream>>>(xnb, in_w, xz, MROWS, 2 * DI, nullptr, nullptr, dflag);
    // 8. conv1d per dir -> xm2y slices
    k_conv1d<0><<<MROWS, 512, 0, stream>>>(xz, conv_w, conv_b, xm2y + 0ULL * MROWS * DI, dflag);
    k_conv1d<1><<<MROWS, 512, 0, stream>>>(xz, conv_w, conv_b, xm2y + 1ULL * MROWS * DI, dflag);
    k_conv1d<2><<<MROWS, 512, 0, stream>>>(xz, conv_w, conv_b, xm2y + 2ULL * MROWS * DI, dflag);
    k_conv1d<3><<<MROWS, 512, 0, stream>>>(xz, conv_w, conv_b, xm2y + 3ULL * MROWS * DI, dflag);
    // 9. batched xproj: proj4 = xm2y @ xproj_w^T   [MFMA, M=4*4608, N=48, K=512]
    k_mgemm<0, 16, float><<<dim3(1, 4 * MROWS / 128), 256, 0, stream>>>(xm2y, xproj_w, proj4, 4 * MROWS, DTR + 2 * DS, nullptr, nullptr, dflag);
    // 10. scan all 4 dirs (dt fused, y in-place)
    k_scan4<<<1024, 64, 0, stream>>>(xm2y, proj4, xz, A_log, Dp, dt_w, dt_b, dflag);
    // 11. fused out-proj: fg = xrb + 0.25 * sum_dir (gathered y @ out_w^T)   [MFMA]
    k_outgemm<<<dim3(4, MROWS / 128), 256, 0, stream>>>(xm2y, out_w, xrb, fg, dflag);
    // 12. SE head + final
    hipMemsetAsync(ssum, 0, 512 * 4, stream);
    k_meanU<<<dim3(32, Bn), 256, 0, stream>>>(fl, fg, ssum);
    k_se<<<Bn, 256, 0, stream>>>(ssum, fc1_w, fc2_w, w01, dflag);
    k_final<<<dim3(Ll / 32, Cc / 32, Bn), dim3(32, 8), 0, stream>>>(fl, fg, w01, d_out, dflag);
}

// Round 8
// 815.621 us; speedup vs baseline: 11.0435x; 1.0944x over previous
//
#include <hip/hip_runtime.h>
#include <hip/hip_bf16.h>

#define EPSC 1e-5f
#define Bn 2
#define CIN 512
#define Cc 256
#define Hh 48
#define Ww 48
#define Ll 2304
#define DI 512
#define DS 16
#define DTR 16
#define MROWS (Bn * Ll)   // 4608
#define NCHUNK 8
#define CLEN (Ll / NCHUNK)        // 288
#define CTILES (CLEN / 32)        // 9

using bf16 = __hip_bfloat16;
typedef short v8s __attribute__((ext_vector_type(8)));
typedef float v4f __attribute__((ext_vector_type(4)));

__device__ __forceinline__ float ldIn(const void* p, size_t i, bool bf) {
    return bf ? __bfloat162float(((const bf16*)p)[i]) : ((const float*)p)[i];
}
__device__ __forceinline__ float toF(float v) { return v; }
__device__ __forceinline__ float toF(bf16 v) { return __bfloat162float(v); }
__device__ __forceinline__ void stO(float* p, float v) { *p = v; }
__device__ __forceinline__ void stO(bf16* p, float v) { *p = __float2bfloat16(v); }
__device__ __forceinline__ float bfu2f(unsigned short u) {
    return __uint_as_float(((unsigned int)u) << 16);
}
__device__ __forceinline__ short f2bs(float f) {
    bf16 h = __float2bfloat16(f);
    short s;
    __builtin_memcpy(&s, &h, 2);
    return s;
}
union U16B { uint4 u; v8s v; };
__device__ __forceinline__ v8s ldA8(const bf16* p) { U16B t; t.u = *(const uint4*)p; return t.v; }
__device__ __forceinline__ v8s ldW8(const void* W, size_t idx, bool bf) {
    if (bf) return ldA8((const bf16*)W + idx);
    const float* f = (const float*)W + idx;
    float4 a = *(const float4*)f;
    float4 b = *(const float4*)(f + 4);
    v8s r;
    r[0] = f2bs(a.x); r[1] = f2bs(a.y); r[2] = f2bs(a.z); r[3] = f2bs(a.w);
    r[4] = f2bs(b.x); r[5] = f2bs(b.y); r[6] = f2bs(b.z); r[7] = f2bs(b.w);
    return r;
}

template <int DIR>
__device__ __forceinline__ int perm_t(int t) {
    if constexpr (DIR == 0) { return t; }
    else if constexpr (DIR == 1) { return Ll - 1 - t; }
    else {
        int tt = (DIR == 2) ? t : (Ll - 1 - t);
        int h = tt % Hh, w = tt / Hh;
        return h * Ww + w;
    }
}
__device__ __forceinline__ int perm_rt(int dir, int t) {
    if (dir == 0) return t;
    if (dir == 1) return Ll - 1 - t;
    int tt = (dir == 2) ? t : (Ll - 1 - t);
    int h = tt % Hh, w = tt / Hh;
    return h * Ww + w;
}

// ---------------- dtype detector ----------------
__global__ void k_detect(const unsigned int* __restrict__ xb, int* __restrict__ flag) {
    if (threadIdx.x == 0 && blockIdx.x == 0) {
        int cnt = 0;
        for (int i = 0; i < 64; i++) {
            unsigned int u = xb[i];
            unsigned int lo = u & 0xFFFFu;
            int e = (int)((lo >> 7) & 0xFF);
            if (lo == 0u || (e >= 90 && e <= 160)) cnt++;
        }
        *flag = (cnt >= 60) ? 1 : 0;
    }
}

// ---------------- ws-size probe ----------------
__global__ __launch_bounds__(256) void k_probe(bf16* __restrict__ out, int n, float val) {
    int i = blockIdx.x * 256 + threadIdx.x;
    if (i < n) out[i] = __float2bfloat16(val);
}

// ---------------- transpose: x (B, CIN, L) -> xTb (B*L, CIN) bf16 ----------------
__global__ __launch_bounds__(256) void k_transpose_in(const void* __restrict__ x, bf16* __restrict__ xT,
                                                      const int* __restrict__ dflag) {
    bool bf = (*dflag != 0);
    __shared__ float tile[32][33];
    int b = blockIdx.z;
    int l0 = blockIdx.x * 32, c0 = blockIdx.y * 32;
    int tx = threadIdx.x, ty = threadIdx.y;
    #pragma unroll
    for (int i = 0; i < 4; i++) {
        int c = c0 + ty + i * 8;
        tile[ty + i * 8][tx] = ldIn(x, ((size_t)(b * CIN + c)) * Ll + l0 + tx, bf);
    }
    __syncthreads();
    #pragma unroll
    for (int i = 0; i < 4; i++) {
        int l = l0 + ty + i * 8;
        xT[((size_t)(b * Ll + l)) * CIN + c0 + tx] = __float2bfloat16(tile[tx][ty + i * 8]);
    }
}

// ---------------- MFMA GEMM ----------------
template <int EP, int KT, typename TO>
__global__ __launch_bounds__(256) void k_mgemm(const bf16* __restrict__ A, const void* __restrict__ W,
                                               TO* __restrict__ Out, int M, int N,
                                               const void* __restrict__ g, const void* __restrict__ bias,
                                               const int* __restrict__ dflag) {
    bool bf = (*dflag != 0);
    constexpr int K = KT * 32;
    int tid = threadIdx.x;
    int w = tid >> 6, lane = tid & 63, quad = lane >> 4, lm = lane & 15;
    int m_w = blockIdx.y * 128 + w * 32;
    int n_w = blockIdx.x * 64;
    v4f acc[2][4] = {};
    const bf16* aP0 = A + (size_t)(m_w + lm) * K + quad * 8;
    const bf16* aP1 = A + (size_t)(m_w + 16 + lm) * K + quad * 8;
    size_t wIdx[4];
    #pragma unroll
    for (int ni = 0; ni < 4; ni++) {
        int n = n_w + ni * 16 + lm;
        wIdx[ni] = (size_t)((n < N) ? n : 0) * K + quad * 8;
    }
    for (int kt = 0; kt < KT; kt++) {
        v8s a0 = ldA8(aP0 + kt * 32);
        v8s a1 = ldA8(aP1 + kt * 32);
        v8s bfr[4];
        #pragma unroll
        for (int ni = 0; ni < 4; ni++) bfr[ni] = ldW8(W, wIdx[ni] + kt * 32, bf);
        #pragma unroll
        for (int ni = 0; ni < 4; ni++) {
            acc[0][ni] = __builtin_amdgcn_mfma_f32_16x16x32_bf16(a0, bfr[ni], acc[0][ni], 0, 0, 0);
            acc[1][ni] = __builtin_amdgcn_mfma_f32_16x16x32_bf16(a1, bfr[ni], acc[1][ni], 0, 0, 0);
        }
    }
    float rs = rsqrtf(1.f + EPSC);
    #pragma unroll
    for (int mi = 0; mi < 2; mi++) {
        #pragma unroll
        for (int ni = 0; ni < 4; ni++) {
            int col = n_w + ni * 16 + lm;
            if (col >= N) continue;
            float gv = 0.f, bv = 0.f;
            if (EP == 1) { gv = ldIn(g, col, bf) * rs; bv = ldIn(bias, col, bf); }
            if (EP == 2) { bv = ldIn(bias, col, bf); }
            #pragma unroll
            for (int r = 0; r < 4; r++) {
                int row = m_w + mi * 16 + quad * 4 + r;
                float v = acc[mi][ni][r];
                if (EP == 1) v = fmaxf(v * gv + bv, 0.f);
                else if (EP == 2) v += bv;
                stO(&Out[(size_t)row * N + col], v);
            }
        }
    }
}

// ---------------- fused out-proj ----------------
__global__ __launch_bounds__(256) void k_outgemm(const bf16* __restrict__ Y, const void* __restrict__ W,
                                                 const bf16* __restrict__ xrb, float* __restrict__ fg,
                                                 const int* __restrict__ dflag) {
    bool bf = (*dflag != 0);
    int tid = threadIdx.x;
    int w = tid >> 6, lane = tid & 63, quad = lane >> 4, lm = lane & 15;
    int row0 = blockIdx.y * 128 + w * 32;
    int n_w = blockIdx.x * 64;
    int b = row0 / Ll;
    v4f acc[2][4] = {};
    const bf16* aP[4][2];
    #pragma unroll
    for (int mi = 0; mi < 2; mi++) {
        int l = (row0 + mi * 16 + lm) - b * Ll;
        int h = l / Ww, w2 = l % Ww;
        int t2 = w2 * Hh + h;
        int tArr[4] = { l, Ll - 1 - l, t2, Ll - 1 - t2 };
        #pragma unroll
        for (int dir = 0; dir < 4; dir++)
            aP[dir][mi] = Y + ((size_t)dir * MROWS + (size_t)b * Ll + tArr[dir]) * DI + quad * 8;
    }
    size_t wIdx[4];
    #pragma unroll
    for (int ni = 0; ni < 4; ni++) wIdx[ni] = (size_t)(n_w + ni * 16 + lm) * DI + quad * 8;
    for (int kt = 0; kt < 16; kt++) {
        v8s bfr[4];
        #pragma unroll
        for (int ni = 0; ni < 4; ni++) bfr[ni] = ldW8(W, wIdx[ni] + kt * 32, bf);
        #pragma unroll
        for (int dir = 0; dir < 4; dir++) {
            v8s a0 = ldA8(aP[dir][0] + kt * 32);
            v8s a1 = ldA8(aP[dir][1] + kt * 32);
            #pragma unroll
            for (int ni = 0; ni < 4; ni++) {
                acc[0][ni] = __builtin_amdgcn_mfma_f32_16x16x32_bf16(a0, bfr[ni], acc[0][ni], 0, 0, 0);
                acc[1][ni] = __builtin_amdgcn_mfma_f32_16x16x32_bf16(a1, bfr[ni], acc[1][ni], 0, 0, 0);
            }
        }
    }
    #pragma unroll
    for (int mi = 0; mi < 2; mi++) {
        #pragma unroll
        for (int ni = 0; ni < 4; ni++) {
            int col = n_w + ni * 16 + lm;
            #pragma unroll
            for (int r = 0; r < 4; r++) {
                int row = row0 + mi * 16 + quad * 4 + r;
                size_t off = (size_t)row * Cc + col;
                fg[off] = toF(xrb[off]) + 0.25f * acc[mi][ni][r];
            }
        }
    }
}

// ---------------- LayerNorm ----------------
__global__ __launch_bounds__(256) void k_ln(const bf16* __restrict__ xrb, const void* __restrict__ g,
                                            const void* __restrict__ bvec, bf16* __restrict__ xn,
                                            const int* __restrict__ dflag) {
    bool bf = (*dflag != 0);
    int m = blockIdx.x;
    int c = threadIdx.x;
    float v = toF(xrb[(size_t)m * Cc + c]);
    float s1 = v, s2 = v * v;
    #pragma unroll
    for (int off = 32; off; off >>= 1) {
        s1 += __shfl_down(s1, off);
        s2 += __shfl_down(s2, off);
    }
    __shared__ float a1[4], a2[4];
    int w = c >> 6;
    if ((c & 63) == 0) { a1[w] = s1; a2[w] = s2; }
    __syncthreads();
    float t1 = a1[0] + a1[1] + a1[2] + a1[3];
    float t2 = a2[0] + a2[1] + a2[2] + a2[3];
    float mu = t1 * (1.f / 256.f);
    float var = t2 * (1.f / 256.f) - mu * mu;
    float r = rsqrtf(var + EPSC);
    xn[(size_t)m * Cc + c] = __float2bfloat16((v - mu) * r * ldIn(g, c, bf) + ldIn(bvec, c, bf));
}

// ---------------- fused depthwise convs ----------------
__global__ __launch_bounds__(256) void k_dwconv_hv(const bf16* __restrict__ p, const void* __restrict__ dwh,
                                                   const void* __restrict__ bnhg, const void* __restrict__ bnhb,
                                                   const void* __restrict__ dwv, const void* __restrict__ bnvg,
                                                   const void* __restrict__ bnvb, bf16* __restrict__ hv,
                                                   const int* __restrict__ dflag) {
    bool bf = (*dflag != 0);
    int m = blockIdx.x;
    int c = threadIdx.x;
    int b = m / Ll, l = m % Ll;
    int yy = l / Ww, xx = l % Ww;
    const bf16* base = p + (size_t)b * Ll * Cc;
    float ah = 0.f, av = 0.f;
    #pragma unroll
    for (int j = 0; j < 7; j++) {
        int x2 = xx + j - 3;
        if (0 <= x2 && x2 < Ww) ah += ldIn(dwh, c * 7 + j, bf) * toF(base[(size_t)(yy * Ww + x2) * Cc + c]);
        int y2 = yy + j - 3;
        if (0 <= y2 && y2 < Hh) av += ldIn(dwv, c * 7 + j, bf) * toF(base[(size_t)(y2 * Ww + xx) * Cc + c]);
    }
    float rs = rsqrtf(1.f + EPSC);
    float out = fmaxf(ah * ldIn(bnhg, c, bf) * rs + ldIn(bnhb, c, bf), 0.f) +
                fmaxf(av * ldIn(bnvg, c, bf) * rs + ldIn(bnvb, c, bf), 0.f);
    hv[(size_t)m * Cc + c] = __float2bfloat16(out);
}

// ---------------- causal depthwise conv(k=4) + silu, all 4 dirs in one launch ----------------
__global__ __launch_bounds__(512) void k_conv1d(const bf16* __restrict__ xz, const void* __restrict__ cw,
                                                const void* __restrict__ cb, bf16* __restrict__ xm2,
                                                const int* __restrict__ dflag) {
    bool bf = (*dflag != 0);
    int m = blockIdx.x;
    int dir = blockIdx.y;
    int ch = threadIdx.x;
    int b = m / Ll, t = m % Ll;
    float acc = ldIn(cb, ch, bf);
    #pragma unroll
    for (int j = 0; j < 4; j++) {
        int tt = t + j - 3;
        if (tt >= 0) {
            int l = perm_rt(dir, tt);
            acc += ldIn(cw, ch * 4 + j, bf) * __bfloat162float(xz[((size_t)(b * Ll + l)) * 1024 + ch]);
        }
    }
    xm2[((size_t)dir * MROWS + m) * DI + ch] = __float2bfloat16(acc / (1.f + __expf(-acc)));
}

// ---------------- chunked scan pass A: per-chunk local recurrence -> hfin, sumdt ----------------
// grid = (NCHUNK-1)*1024 blocks x 64 thr
__global__ __launch_bounds__(64) void k_scanA(const bf16* __restrict__ xm2y, const float* __restrict__ proj4,
                                              float* __restrict__ hfin, float* __restrict__ sumdt,
                                              const void* __restrict__ A_log, const void* __restrict__ dt_w,
                                              const void* __restrict__ dt_b, const int* __restrict__ dflag) {
    bool bf = (*dflag != 0);
    int lane = threadIdx.x;
    int g = lane >> 4, s = lane & 15;
    int blk = blockIdx.x;
    int chunk = blk >> 10;           // 0..6
    int rest = blk & 1023;
    int dir = rest >> 8;
    int r2 = rest & 255;
    int b = r2 >> 7;
    int j = r2 & 127;
    int ch0 = (j & 15) * 32 + (j >> 4) * 4;
    int ch = ch0 + g;

    float Acoef = -__expf(ldIn(A_log, ch * 16 + s, bf));
    float dtw = ldIn(dt_w, ch * DTR + s, bf);
    float dtbias = ldIn(dt_b, ch, bf);
    float h = 0.f, sacc = 0.f;

    __shared__ float sP[2 * 32 * 17];   // [comp(dt,B)][t][17]
    __shared__ uint2 sxm[32];

    const bf16* xmS = xm2y + ((size_t)dir * MROWS + (size_t)b * Ll) * DI;
    const float* ppS = proj4 + ((size_t)dir * MROWS + (size_t)b * Ll) * 48;
    int t0c = chunk * CLEN;
    int ttl = lane & 31;
    bool isA = lane < 32;

    float rp[16];
    ushort4 rxm;
    {
        #pragma unroll
        for (int k = 0; k < 16; k++) {
            int e = lane + k * 64;
            int t = e >> 5, r = e & 31;
            rp[k] = ppS[(size_t)(t0c + t) * 48 + r];
        }
        if (isA) rxm = *(const ushort4*)(xmS + (size_t)(t0c + ttl) * DI + ch0);
    }
    for (int tile = 0; tile < CTILES; tile++) {
        // commit current tile to LDS (in-order per wave; no barrier needed, 1 wave/block)
        #pragma unroll
        for (int k = 0; k < 16; k++) {
            int e = lane + k * 64;
            int t = e >> 5, r = e & 31;
            sP[(r >> 4) * 544 + t * 17 + (r & 15)] = rp[k];
        }
        if (isA) sxm[ttl] = *(uint2*)&rxm;
        // prefetch next tile
        if (tile < CTILES - 1) {
            int tb = t0c + (tile + 1) * 32;
            #pragma unroll
            for (int k = 0; k < 16; k++) {
                int e = lane + k * 64;
                int t = e >> 5, r = e & 31;
                rp[k] = ppS[(size_t)(tb + t) * 48 + r];
            }
            if (isA) rxm = *(const ushort4*)(xmS + (size_t)(tb + ttl) * DI + ch0);
        }
        // compute
        const unsigned short* xml = (const unsigned short*)sxm;
        float dtv[32];
        #pragma unroll
        for (int tt = 0; tt < 32; tt++) dtv[tt] = sP[tt * 17 + s] * dtw;
        #pragma unroll
        for (int r = 8; r; r >>= 1) {
            #pragma unroll
            for (int tt = 0; tt < 32; tt++) dtv[tt] += __shfl_xor(dtv[tt], r);
        }
        #pragma unroll
        for (int tt = 0; tt < 32; tt++) {
            float v = dtv[tt] + dtbias;
            dtv[tt] = (v > 20.f) ? v : __logf(1.f + __expf(v));
        }
        #pragma unroll
        for (int tt = 0; tt < 32; tt++) {
            float xv = bfu2f(xml[tt * 4 + g]);
            float Bv = sP[544 + tt * 17 + s];
            float da = __expf(dtv[tt] * Acoef);
            h = fmaf(da, h, dtv[tt] * xv * Bv);
            sacc += dtv[tt];
        }
    }
    int db = (dir * 2 + b);
    hfin[(((size_t)db * NCHUNK + chunk) << 13) + ch * 16 + s] = h;
    if (s == 0) sumdt[(((size_t)db * NCHUNK + chunk) << 9) + ch] = sacc;
}

// ---------------- chunked scan pass B: combine chunk boundaries -> hfin holds h_start ----------------
__global__ __launch_bounds__(256) void k_scanB(float* __restrict__ hfin, const float* __restrict__ sumdt,
                                               const void* __restrict__ A_log, const int* __restrict__ dflag) {
    bool bf = (*dflag != 0);
    int idx = blockIdx.x * 256 + threadIdx.x;   // 65536
    int s = idx & 15, ch = (idx >> 4) & 511;
    int db = idx >> 13;
    float Acoef = -__expf(ldIn(A_log, ch * 16 + s, bf));
    float h = 0.f;
    size_t base = ((size_t)db * NCHUNK << 13) + ch * 16 + s;
    size_t sbase = ((size_t)db * NCHUNK << 9) + ch;
    #pragma unroll
    for (int k = 0; k < NCHUNK; k++) {
        float hf = hfin[base + ((size_t)k << 13)];
        hfin[base + ((size_t)k << 13)] = h;
        if (k < NCHUNK - 1) {
            float a = __expf(Acoef * sumdt[sbase + ((size_t)k << 9)]);
            h = a * h + hf;
        }
    }
}

// ---------------- chunked scan pass C: seeded recurrence + output, y in-place ----------------
// grid = NCHUNK*1024 blocks x 64 thr
__global__ __launch_bounds__(64) void k_scanC(bf16* __restrict__ xm2y, const float* __restrict__ proj4,
                                              const bf16* __restrict__ xz, const float* __restrict__ hfin,
                                              const void* __restrict__ A_log, const void* __restrict__ Dp,
                                              const void* __restrict__ dt_w, const void* __restrict__ dt_b,
                                              const int* __restrict__ dflag) {
    bool bf = (*dflag != 0);
    int lane = threadIdx.x;
    int g = lane >> 4, s = lane & 15;
    int blk = blockIdx.x;
    int chunk = blk >> 10;           // 0..7
    int rest = blk & 1023;
    int dir = rest >> 8;
    int r2 = rest & 255;
    int b = r2 >> 7;
    int j = r2 & 127;
    int ch0 = (j & 15) * 32 + (j >> 4) * 4;
    int ch = ch0 + g;

    float Acoef = -__expf(ldIn(A_log, ch * 16 + s, bf));
    float dp = ldIn(Dp, ch, bf);
    float dtw = ldIn(dt_w, ch * DTR + s, bf);
    float dtbias = ldIn(dt_b, ch, bf);
    int db = (dir * 2 + b);
    float h = hfin[(((size_t)db * NCHUNK + chunk) << 13) + ch * 16 + s];

    __shared__ float sP[3 * 32 * 17];   // [comp(dt,B,C)][t][17]
    __shared__ uint2 sxm[32];
    __shared__ uint2 szz[32];

    bf16* xmS = xm2y + ((size_t)dir * MROWS + (size_t)b * Ll) * DI;
    const float* ppS = proj4 + ((size_t)dir * MROWS + (size_t)b * Ll) * 48;
    const bf16* zp = xz + (size_t)b * Ll * 1024 + 512;
    int t0c = chunk * CLEN;
    int ttl = lane & 31;
    bool isA = lane < 32;

    float rp[24];
    ushort4 rxz;
    {
        #pragma unroll
        for (int k = 0; k < 24; k++) {
            int e = lane + k * 64;
            int t = e / 48, r = e % 48;
            rp[k] = ppS[(size_t)(t0c + t) * 48 + r];
        }
        if (isA) rxz = *(const ushort4*)(xmS + (size_t)(t0c + ttl) * DI + ch0);
        else {
            int l = perm_rt(dir, t0c + ttl);
            rxz = *(const ushort4*)(zp + (size_t)l * 1024 + ch0);
        }
    }
    for (int tile = 0; tile < CTILES; tile++) {
        // commit
        #pragma unroll
        for (int k = 0; k < 24; k++) {
            int e = lane + k * 64;
            int t = e / 48, r = e % 48;
            sP[(r >> 4) * 544 + t * 17 + (r & 15)] = rp[k];
        }
        if (isA) sxm[ttl] = *(uint2*)&rxz; else szz[ttl] = *(uint2*)&rxz;
        // prefetch
        if (tile < CTILES - 1) {
            int tb = t0c + (tile + 1) * 32;
            #pragma unroll
            for (int k = 0; k < 24; k++) {
                int e = lane + k * 64;
                int t = e / 48, r = e % 48;
                rp[k] = ppS[(size_t)(tb + t) * 48 + r];
            }
            if (isA) rxz = *(const ushort4*)(xmS + (size_t)(tb + ttl) * DI + ch0);
            else {
                int l = perm_rt(dir, tb + ttl);
                rxz = *(const ushort4*)(zp + (size_t)l * 1024 + ch0);
            }
        }
        // compute
        const unsigned short* xml = (const unsigned short*)sxm;
        const unsigned short* zl  = (const unsigned short*)szz;
        int tbase = t0c + tile * 32;
        float dtv[32];
        #pragma unroll
        for (int tt = 0; tt < 32; tt++) dtv[tt] = sP[tt * 17 + s] * dtw;
        #pragma unroll
        for (int r = 8; r; r >>= 1) {
            #pragma unroll
            for (int tt = 0; tt < 32; tt++) dtv[tt] += __shfl_xor(dtv[tt], r);
        }
        #pragma unroll
        for (int tt = 0; tt < 32; tt++) {
            float v = dtv[tt] + dtbias;
            dtv[tt] = (v > 20.f) ? v : __logf(1.f + __expf(v));
        }
        float pc[32];
        #pragma unroll
        for (int tt = 0; tt < 32; tt++) {
            float xv = bfu2f(xml[tt * 4 + g]);
            float Bv = sP[544 + tt * 17 + s];
            float da = __expf(dtv[tt] * Acoef);
            h = fmaf(da, h, dtv[tt] * xv * Bv);
            pc[tt] = h * sP[1088 + tt * 17 + s];
        }
        #pragma unroll
        for (int r = 8; r; r >>= 1) {
            #pragma unroll
            for (int tt = 0; tt < 32; tt++) pc[tt] += __shfl_xor(pc[tt], r);
        }
        #pragma unroll
        for (int k = 0; k < 2; k++) {
            int tt = s + 16 * k;
            float xv = bfu2f(xml[tt * 4 + g]);
            float zv = bfu2f(zl[tt * 4 + g]);
            float sig = 1.f / (1.f + __expf(-zv));
            xmS[(size_t)(tbase + tt) * DI + ch] = __float2bfloat16((pc[tt] + dp * xv) * zv * sig);
        }
    }
}

// ---------------- mean over spatial ----------------
__global__ __launch_bounds__(256) void k_meanU(const bf16* __restrict__ fl, const float* __restrict__ fg,
                                               float* __restrict__ ssum) {
    int b = blockIdx.y;
    int chunk = blockIdx.x;
    int c = threadIdx.x;
    float acc = 0.f;
    for (int i = 0; i < 72; i++) {
        int l = chunk * 72 + i;
        size_t off = ((size_t)(b * Ll + l)) * Cc + c;
        acc += toF(fl[off]) + fg[off];
    }
    atomicAdd(&ssum[b * Cc + c], acc);
}

// ---------------- SE head ----------------
__global__ __launch_bounds__(256) void k_se(const float* __restrict__ ssum, const void* __restrict__ fc1,
                                            const void* __restrict__ fc2, float* __restrict__ w01,
                                            const int* __restrict__ dflag) {
    bool bf = (*dflag != 0);
    int b = blockIdx.x;
    int c = threadIdx.x;
    __shared__ float sh[256];
    __shared__ float mid[16];
    sh[c] = ssum[b * 256 + c] * (1.f / (float)Ll);
    __syncthreads();
    if (c < 16) {
        float a = 0.f;
        for (int k = 0; k < 256; k++) a += sh[k] * ldIn(fc1, c * 256 + k, bf);
        mid[c] = fmaxf(a, 0.f);
    }
    __syncthreads();
    float a0 = 0.f, a1 = 0.f;
    #pragma unroll
    for (int j = 0; j < 16; j++) {
        float mj = mid[j];
        a0 += mj * ldIn(fc2, c * 16 + j, bf);
        a1 += mj * ldIn(fc2, (256 + c) * 16 + j, bf);
    }
    float mx = fmaxf(a0, a1);
    float e0 = expf(a0 - mx), e1 = expf(a1 - mx);
    float inv = 1.f / (e0 + e1);
    w01[b * 256 + c] = e0 * inv;
    w01[512 + b * 256 + c] = e1 * inv;
}

// ---------------- final combine + transpose ----------------
__global__ __launch_bounds__(256) void k_final(const bf16* __restrict__ fl, const float* __restrict__ fg,
                                               const float* __restrict__ w01, void* __restrict__ out,
                                               const int* __restrict__ dflag) {
    bool bf = (*dflag != 0);
    __shared__ float tile[32][33];
    int b = blockIdx.z;
    int l0 = blockIdx.x * 32, c0 = blockIdx.y * 32;
    int tx = threadIdx.x, ty = threadIdx.y;
    #pragma unroll
    for (int i = 0; i < 4; i++) {
        int l = l0 + ty + i * 8;
        int c = c0 + tx;
        size_t off = ((size_t)(b * Ll + l)) * Cc + c;
        tile[ty + i * 8][tx] = w01[b * 256 + c] * toF(fl[off]) + w01[512 + b * 256 + c] * fg[off];
    }
    __syncthreads();
    #pragma unroll
    for (int i = 0; i < 4; i++) {
        int c = c0 + ty + i * 8;
        size_t off = ((size_t)(b * Cc + c)) * Ll + l0 + tx;
        float v = tile[tx][ty + i * 8];
        if (bf) ((bf16*)out)[off] = __float2bfloat16(v);
        else    ((float*)out)[off] = v;
    }
}

extern "C" void kernel_launch(void* const* d_in, const int* in_sizes, int n_in,
                              void* d_out, int out_size, void* d_ws, size_t ws_size,
                              hipStream_t stream) {
    const void* x        = d_in[0];
    const void* reduce_w = d_in[1];
    const void* bn0_g    = d_in[2];
    const void* bn0_b    = d_in[3];
    const void* proj_w   = d_in[4];
    const void* bn1_g    = d_in[5];
    const void* bn1_b    = d_in[6];
    const void* dwh_w    = d_in[7];
    const void* bnh_g    = d_in[8];
    const void* bnh_b    = d_in[9];
    const void* dwv_w    = d_in[10];
    const void* bnv_g    = d_in[11];
    const void* bnv_b    = d_in[12];
    const void* fus_w    = d_in[13];
    const void* fus_b    = d_in[14];
    const void* ln_g     = d_in[15];
    const void* ln_b     = d_in[16];
    const void* in_w     = d_in[17];
    const void* conv_w   = d_in[18];
    const void* conv_b   = d_in[19];
    const void* xproj_w  = d_in[20];
    const void* dt_w     = d_in[21];
    const void* dt_b     = d_in[22];
    const void* A_log    = d_in[23];
    const void* Dp       = d_in[24];
    const void* out_w    = d_in[25];
    const void* fc1_w    = d_in[26];
    const void* fc2_w    = d_in[27];

    // ---- workspace layout (f32 slots), total 43.7 MB ----
    float* ws = (float*)d_ws;
    bf16*  fl     = (bf16*)ws;                   // 589824 slots
    float* fg     = ws + 589824;                 // 1179648
    bf16*  xrb    = (bf16*)(ws + 1769472);       // 589824 slots
    bf16*  xz     = (bf16*)(ws + 2359296);       // 2359296 slots
    float* proj4  = ws + 4718592;                // 884736
    bf16*  xm2y   = (bf16*)(ws + 5603328);       // 4718592 slots; hosts xTb/hvb earlier
    float* scrH   = ws + 10321920;               // 589824 slots: pb/xnb early, then hfin+sumdt
    float* ssum   = ws + 10911744;               // 512
    float* w01    = ws + 10912256;               // 1024
    int*   dflag  = (int*)(ws + 10913280);       // 1
    const size_t needed = 10913281ULL * 4ULL;

    if (ws_size < needed) {
        float val = 1000.0f + (float)(ws_size >> 20);
        k_probe<<<(out_size + 255) / 256, 256, 0, stream>>>((bf16*)d_out, out_size, val);
        return;
    }

    bf16* xTb = (bf16*)xm2y;       // transient (steps 1-2)
    bf16* hvb = (bf16*)xm2y;       // transient (steps 4-5)
    bf16* pb  = (bf16*)scrH;       // steps 3-4
    bf16* xnb = (bf16*)scrH;       // steps 6-7
    float* hfin  = scrH;           // 524288 (after step 7)
    float* sumdt = scrH + 524288;  // 32768

    // 0. detect input dtype
    k_detect<<<1, 64, 0, stream>>>((const unsigned int*)x, dflag);
    // 1. transpose x -> xTb
    k_transpose_in<<<dim3(Ll / 32, CIN / 32, Bn), dim3(32, 8), 0, stream>>>(x, xTb, dflag);
    // 2. xrb = relu(bn0(xTb @ reduce_w^T))
    k_mgemm<1, 16, bf16><<<dim3(4, MROWS / 128), 256, 0, stream>>>(xTb, reduce_w, xrb, MROWS, Cc, bn0_g, bn0_b, dflag);
    // 3. pb = relu(bn1(xrb @ proj_w^T))
    k_mgemm<1, 8, bf16><<<dim3(4, MROWS / 128), 256, 0, stream>>>(xrb, proj_w, pb, MROWS, Cc, bn1_g, bn1_b, dflag);
    // 4. hvb = dwconvs
    k_dwconv_hv<<<MROWS, 256, 0, stream>>>(pb, dwh_w, bnh_g, bnh_b, dwv_w, bnv_g, bnv_b, hvb, dflag);
    // 5. fl = hvb @ fus_w^T + fus_b
    k_mgemm<2, 8, bf16><<<dim3(4, MROWS / 128), 256, 0, stream>>>(hvb, fus_w, fl, MROWS, Cc, nullptr, fus_b, dflag);
    // 6. xnb = LN(xrb)
    k_ln<<<MROWS, 256, 0, stream>>>(xrb, ln_g, ln_b, xnb, dflag);
    // 7. xz = xnb @ in_w^T
    k_mgemm<0, 8, bf16><<<dim3(16, MROWS / 128), 256, 0, stream>>>(xnb, in_w, xz, MROWS, 2 * DI, nullptr, nullptr, dflag);
    // 8. conv1d (all 4 dirs, one launch) -> xm2y
    k_conv1d<<<dim3(MROWS, 4), 512, 0, stream>>>(xz, conv_w, conv_b, xm2y, dflag);
    // 9. batched xproj
    k_mgemm<0, 16, float><<<dim3(1, 4 * MROWS / 128), 256, 0, stream>>>(xm2y, xproj_w, proj4, 4 * MROWS, DTR + 2 * DS, nullptr, nullptr, dflag);
    // 10. chunked scan: A (local), B (combine), C (seeded + output)
    k_scanA<<<(NCHUNK - 1) * 1024, 64, 0, stream>>>(xm2y, proj4, hfin, sumdt, A_log, dt_w, dt_b, dflag);
    k_scanB<<<256, 256, 0, stream>>>(hfin, sumdt, A_log, dflag);
    k_scanC<<<NCHUNK * 1024, 64, 0, stream>>>(xm2y, proj4, xz, hfin, A_log, Dp, dt_w, dt_b, dflag);
    // 11. fused out-proj
    k_outgemm<<<dim3(4, MROWS / 128), 256, 0, stream>>>(xm2y, out_w, xrb, fg, dflag);
    // 12. SE head + final
    hipMemsetAsync(ssum, 0, 512 * 4, stream);
    k_meanU<<<dim3(32, Bn), 256, 0, stream>>>(fl, fg, ssum);
    k_se<<<Bn, 256, 0, stream>>>(ssum, fc1_w, fc2_w, w01, dflag);
    k_final<<<dim3(Ll / 32, Cc / 32, Bn), dim3(32, 8), 0, stream>>>(fl, fg, w01, d_out, dflag);
}

// Round 9
// 803.412 us; speedup vs baseline: 11.2114x; 1.0152x over previous
//
#include <hip/hip_runtime.h>
#include <hip/hip_bf16.h>

#define EPSC 1e-5f
#define Bn 2
#define CIN 512
#define Cc 256
#define Hh 48
#define Ww 48
#define Ll 2304
#define DI 512
#define DS 16
#define DTR 16
#define MROWS (Bn * Ll)   // 4608
#define NCHUNK 8
#define CLEN (Ll / NCHUNK)        // 288
#define CTILES (CLEN / 32)        // 9

using bf16 = __hip_bfloat16;
typedef short v8s __attribute__((ext_vector_type(8)));
typedef float v4f __attribute__((ext_vector_type(4)));

__device__ __forceinline__ float ldIn(const void* p, size_t i, bool bf) {
    return bf ? __bfloat162float(((const bf16*)p)[i]) : ((const float*)p)[i];
}
__device__ __forceinline__ float toF(float v) { return v; }
__device__ __forceinline__ float toF(bf16 v) { return __bfloat162float(v); }
__device__ __forceinline__ void stO(float* p, float v) { *p = v; }
__device__ __forceinline__ void stO(bf16* p, float v) { *p = __float2bfloat16(v); }
__device__ __forceinline__ float bfu2f(unsigned short u) {
    return __uint_as_float(((unsigned int)u) << 16);
}
__device__ __forceinline__ short f2bs(float f) {
    bf16 h = __float2bfloat16(f);
    short s;
    __builtin_memcpy(&s, &h, 2);
    return s;
}
union U16B { uint4 u; v8s v; };
__device__ __forceinline__ v8s ldA8(const bf16* p) { U16B t; t.u = *(const uint4*)p; return t.v; }
__device__ __forceinline__ v8s ldW8(const void* W, size_t idx, bool bf) {
    if (bf) return ldA8((const bf16*)W + idx);
    const float* f = (const float*)W + idx;
    float4 a = *(const float4*)f;
    float4 b = *(const float4*)(f + 4);
    v8s r;
    r[0] = f2bs(a.x); r[1] = f2bs(a.y); r[2] = f2bs(a.z); r[3] = f2bs(a.w);
    r[4] = f2bs(b.x); r[5] = f2bs(b.y); r[6] = f2bs(b.z); r[7] = f2bs(b.w);
    return r;
}

__device__ __forceinline__ int perm_rt(int dir, int t) {
    if (dir == 0) return t;
    if (dir == 1) return Ll - 1 - t;
    int tt = (dir == 2) ? t : (Ll - 1 - t);
    int h = tt % Hh, w = tt / Hh;
    return h * Ww + w;
}

// ---------------- dtype detector ----------------
__global__ void k_detect(const unsigned int* __restrict__ xb, int* __restrict__ flag) {
    if (threadIdx.x == 0 && blockIdx.x == 0) {
        int cnt = 0;
        for (int i = 0; i < 64; i++) {
            unsigned int u = xb[i];
            unsigned int lo = u & 0xFFFFu;
            int e = (int)((lo >> 7) & 0xFF);
            if (lo == 0u || (e >= 90 && e <= 160)) cnt++;
        }
        *flag = (cnt >= 60) ? 1 : 0;
    }
}

// ---------------- ws-size probe ----------------
__global__ __launch_bounds__(256) void k_probe(bf16* __restrict__ out, int n, float val) {
    int i = blockIdx.x * 256 + threadIdx.x;
    if (i < n) out[i] = __float2bfloat16(val);
}

// ---------------- transpose ----------------
__global__ __launch_bounds__(256) void k_transpose_in(const void* __restrict__ x, bf16* __restrict__ xT,
                                                      const int* __restrict__ dflag) {
    bool bf = (*dflag != 0);
    __shared__ float tile[32][33];
    int b = blockIdx.z;
    int l0 = blockIdx.x * 32, c0 = blockIdx.y * 32;
    int tx = threadIdx.x, ty = threadIdx.y;
    #pragma unroll
    for (int i = 0; i < 4; i++) {
        int c = c0 + ty + i * 8;
        tile[ty + i * 8][tx] = ldIn(x, ((size_t)(b * CIN + c)) * Ll + l0 + tx, bf);
    }
    __syncthreads();
    #pragma unroll
    for (int i = 0; i < 4; i++) {
        int l = l0 + ty + i * 8;
        xT[((size_t)(b * Ll + l)) * CIN + c0 + tx] = __float2bfloat16(tile[tx][ty + i * 8]);
    }
}

// ---------------- MFMA GEMM ----------------
template <int EP, int KT, typename TO>
__global__ __launch_bounds__(256) void k_mgemm(const bf16* __restrict__ A, const void* __restrict__ W,
                                               TO* __restrict__ Out, int M, int N,
                                               const void* __restrict__ g, const void* __restrict__ bias,
                                               const int* __restrict__ dflag) {
    bool bf = (*dflag != 0);
    constexpr int K = KT * 32;
    int tid = threadIdx.x;
    int w = tid >> 6, lane = tid & 63, quad = lane >> 4, lm = lane & 15;
    int m_w = blockIdx.y * 128 + w * 32;
    int n_w = blockIdx.x * 64;
    v4f acc[2][4] = {};
    const bf16* aP0 = A + (size_t)(m_w + lm) * K + quad * 8;
    const bf16* aP1 = A + (size_t)(m_w + 16 + lm) * K + quad * 8;
    size_t wIdx[4];
    #pragma unroll
    for (int ni = 0; ni < 4; ni++) {
        int n = n_w + ni * 16 + lm;
        wIdx[ni] = (size_t)((n < N) ? n : 0) * K + quad * 8;
    }
    for (int kt = 0; kt < KT; kt++) {
        v8s a0 = ldA8(aP0 + kt * 32);
        v8s a1 = ldA8(aP1 + kt * 32);
        v8s bfr[4];
        #pragma unroll
        for (int ni = 0; ni < 4; ni++) bfr[ni] = ldW8(W, wIdx[ni] + kt * 32, bf);
        #pragma unroll
        for (int ni = 0; ni < 4; ni++) {
            acc[0][ni] = __builtin_amdgcn_mfma_f32_16x16x32_bf16(a0, bfr[ni], acc[0][ni], 0, 0, 0);
            acc[1][ni] = __builtin_amdgcn_mfma_f32_16x16x32_bf16(a1, bfr[ni], acc[1][ni], 0, 0, 0);
        }
    }
    float rs = rsqrtf(1.f + EPSC);
    #pragma unroll
    for (int mi = 0; mi < 2; mi++) {
        #pragma unroll
        for (int ni = 0; ni < 4; ni++) {
            int col = n_w + ni * 16 + lm;
            if (col >= N) continue;
            float gv = 0.f, bv = 0.f;
            if (EP == 1) { gv = ldIn(g, col, bf) * rs; bv = ldIn(bias, col, bf); }
            if (EP == 2) { bv = ldIn(bias, col, bf); }
            #pragma unroll
            for (int r = 0; r < 4; r++) {
                int row = m_w + mi * 16 + quad * 4 + r;
                float v = acc[mi][ni][r];
                if (EP == 1) v = fmaxf(v * gv + bv, 0.f);
                else if (EP == 2) v += bv;
                stO(&Out[(size_t)row * N + col], v);
            }
        }
    }
}

// ---------------- fused out-proj ----------------
__global__ __launch_bounds__(256) void k_outgemm(const bf16* __restrict__ Y, const void* __restrict__ W,
                                                 const bf16* __restrict__ xrb, float* __restrict__ fg,
                                                 const int* __restrict__ dflag) {
    bool bf = (*dflag != 0);
    int tid = threadIdx.x;
    int w = tid >> 6, lane = tid & 63, quad = lane >> 4, lm = lane & 15;
    int row0 = blockIdx.y * 128 + w * 32;
    int n_w = blockIdx.x * 64;
    int b = row0 / Ll;
    v4f acc[2][4] = {};
    const bf16* aP[4][2];
    #pragma unroll
    for (int mi = 0; mi < 2; mi++) {
        int l = (row0 + mi * 16 + lm) - b * Ll;
        int h = l / Ww, w2 = l % Ww;
        int t2 = w2 * Hh + h;
        int tArr[4] = { l, Ll - 1 - l, t2, Ll - 1 - t2 };
        #pragma unroll
        for (int dir = 0; dir < 4; dir++)
            aP[dir][mi] = Y + ((size_t)dir * MROWS + (size_t)b * Ll + tArr[dir]) * DI + quad * 8;
    }
    size_t wIdx[4];
    #pragma unroll
    for (int ni = 0; ni < 4; ni++) wIdx[ni] = (size_t)(n_w + ni * 16 + lm) * DI + quad * 8;
    for (int kt = 0; kt < 16; kt++) {
        v8s bfr[4];
        #pragma unroll
        for (int ni = 0; ni < 4; ni++) bfr[ni] = ldW8(W, wIdx[ni] + kt * 32, bf);
        #pragma unroll
        for (int dir = 0; dir < 4; dir++) {
            v8s a0 = ldA8(aP[dir][0] + kt * 32);
            v8s a1 = ldA8(aP[dir][1] + kt * 32);
            #pragma unroll
            for (int ni = 0; ni < 4; ni++) {
                acc[0][ni] = __builtin_amdgcn_mfma_f32_16x16x32_bf16(a0, bfr[ni], acc[0][ni], 0, 0, 0);
                acc[1][ni] = __builtin_amdgcn_mfma_f32_16x16x32_bf16(a1, bfr[ni], acc[1][ni], 0, 0, 0);
            }
        }
    }
    #pragma unroll
    for (int mi = 0; mi < 2; mi++) {
        #pragma unroll
        for (int ni = 0; ni < 4; ni++) {
            int col = n_w + ni * 16 + lm;
            #pragma unroll
            for (int r = 0; r < 4; r++) {
                int row = row0 + mi * 16 + quad * 4 + r;
                size_t off = (size_t)row * Cc + col;
                fg[off] = toF(xrb[off]) + 0.25f * acc[mi][ni][r];
            }
        }
    }
}

// ---------------- LayerNorm ----------------
__global__ __launch_bounds__(256) void k_ln(const bf16* __restrict__ xrb, const void* __restrict__ g,
                                            const void* __restrict__ bvec, bf16* __restrict__ xn,
                                            const int* __restrict__ dflag) {
    bool bf = (*dflag != 0);
    int m = blockIdx.x;
    int c = threadIdx.x;
    float v = toF(xrb[(size_t)m * Cc + c]);
    float s1 = v, s2 = v * v;
    #pragma unroll
    for (int off = 32; off; off >>= 1) {
        s1 += __shfl_down(s1, off);
        s2 += __shfl_down(s2, off);
    }
    __shared__ float a1[4], a2[4];
    int w = c >> 6;
    if ((c & 63) == 0) { a1[w] = s1; a2[w] = s2; }
    __syncthreads();
    float t1 = a1[0] + a1[1] + a1[2] + a1[3];
    float t2 = a2[0] + a2[1] + a2[2] + a2[3];
    float mu = t1 * (1.f / 256.f);
    float var = t2 * (1.f / 256.f) - mu * mu;
    float r = rsqrtf(var + EPSC);
    xn[(size_t)m * Cc + c] = __float2bfloat16((v - mu) * r * ldIn(g, c, bf) + ldIn(bvec, c, bf));
}

// ---------------- fused depthwise convs ----------------
__global__ __launch_bounds__(256) void k_dwconv_hv(const bf16* __restrict__ p, const void* __restrict__ dwh,
                                                   const void* __restrict__ bnhg, const void* __restrict__ bnhb,
                                                   const void* __restrict__ dwv, const void* __restrict__ bnvg,
                                                   const void* __restrict__ bnvb, bf16* __restrict__ hv,
                                                   const int* __restrict__ dflag) {
    bool bf = (*dflag != 0);
    int m = blockIdx.x;
    int c = threadIdx.x;
    int b = m / Ll, l = m % Ll;
    int yy = l / Ww, xx = l % Ww;
    const bf16* base = p + (size_t)b * Ll * Cc;
    float ah = 0.f, av = 0.f;
    #pragma unroll
    for (int j = 0; j < 7; j++) {
        int x2 = xx + j - 3;
        if (0 <= x2 && x2 < Ww) ah += ldIn(dwh, c * 7 + j, bf) * toF(base[(size_t)(yy * Ww + x2) * Cc + c]);
        int y2 = yy + j - 3;
        if (0 <= y2 && y2 < Hh) av += ldIn(dwv, c * 7 + j, bf) * toF(base[(size_t)(y2 * Ww + xx) * Cc + c]);
    }
    float rs = rsqrtf(1.f + EPSC);
    float out = fmaxf(ah * ldIn(bnhg, c, bf) * rs + ldIn(bnhb, c, bf), 0.f) +
                fmaxf(av * ldIn(bnvg, c, bf) * rs + ldIn(bnvb, c, bf), 0.f);
    hv[(size_t)m * Cc + c] = __float2bfloat16(out);
}

// ---------------- conv1d + silu, all 4 dirs ----------------
__global__ __launch_bounds__(512) void k_conv1d(const bf16* __restrict__ xz, const void* __restrict__ cw,
                                                const void* __restrict__ cb, bf16* __restrict__ xm2,
                                                const int* __restrict__ dflag) {
    bool bf = (*dflag != 0);
    int m = blockIdx.x;
    int dir = blockIdx.y;
    int ch = threadIdx.x;
    int b = m / Ll, t = m % Ll;
    float acc = ldIn(cb, ch, bf);
    #pragma unroll
    for (int j = 0; j < 4; j++) {
        int tt = t + j - 3;
        if (tt >= 0) {
            int l = perm_rt(dir, tt);
            acc += ldIn(cw, ch * 4 + j, bf) * __bfloat162float(xz[((size_t)(b * Ll + l)) * 1024 + ch]);
        }
    }
    xm2[((size_t)dir * MROWS + m) * DI + ch] = __float2bfloat16(acc / (1.f + __expf(-acc)));
}

// ---------------- chunked scan pass A (cooperative 4-wave blocks) ----------------
// grid = (NCHUNK-1)*256 blocks x 256 thr; block handles one (chunk,dir,b) x 16 channels
__global__ __launch_bounds__(256) void k_scanA(const bf16* __restrict__ xm2y, const float* __restrict__ proj4,
                                               float* __restrict__ hfin, float* __restrict__ sumdt,
                                               const void* __restrict__ A_log, const void* __restrict__ dt_w,
                                               const void* __restrict__ dt_b, const int* __restrict__ dflag) {
    bool bf = (*dflag != 0);
    int tid = threadIdx.x;
    int w = tid >> 6, lane = tid & 63;
    int g = lane >> 4, s = lane & 15;
    int blk = blockIdx.x;
    int chunk = blk >> 8;            // 0..6
    int rest = blk & 255;
    int dir = rest >> 6;
    int r2 = rest & 63;
    int b = r2 >> 5;
    int j = (r2 & 31) * 4 + w;       // 0..127
    int ch0 = (j & 15) * 32 + (j >> 4) * 4;
    int ch = ch0 + g;

    float Acoef = -__expf(ldIn(A_log, ch * 16 + s, bf));
    float dtw = ldIn(dt_w, ch * DTR + s, bf);
    float dtbias = ldIn(dt_b, ch, bf);
    float h = 0.f, sacc = 0.f;

    __shared__ float sP[2][32 * 33];   // [tt][33]: dt at col s, B at col 16+s (shared by all 4 waves)
    __shared__ uint2 sxm[4][32];       // per-wave xm (4 channels x 32 t)

    const bf16* xmS = xm2y + ((size_t)dir * MROWS + (size_t)b * Ll) * DI;
    const float* ppS = proj4 + ((size_t)dir * MROWS + (size_t)b * Ll) * 48;
    int t0c = chunk * CLEN;
    int ttl = lane & 31;
    bool isA = lane < 32;

    float rp[4];
    ushort4 rxm;
    // prologue: stage tile 0 into buf 0
    #pragma unroll
    for (int k = 0; k < 4; k++) {
        int idx = tid + k * 256;
        int t = idx >> 5, r = idx & 31;
        sP[0][t * 33 + r] = ppS[(size_t)(t0c + t) * 48 + r];
    }
    if (isA) {
        rxm = *(const ushort4*)(xmS + (size_t)(t0c + ttl) * DI + ch0);
        sxm[w][ttl] = *(uint2*)&rxm;
    }
    __syncthreads();

    int buf = 0;
    for (int tile = 0; tile < CTILES; tile++) {
        // prefetch next tile into regs
        if (tile < CTILES - 1) {
            int tb = t0c + (tile + 1) * 32;
            #pragma unroll
            for (int k = 0; k < 4; k++) {
                int idx = tid + k * 256;
                int t = idx >> 5, r = idx & 31;
                rp[k] = ppS[(size_t)(tb + t) * 48 + r];
            }
            if (isA) rxm = *(const ushort4*)(xmS + (size_t)(tb + ttl) * DI + ch0);
        }
        // compute from LDS
        const float* P = sP[buf];
        const unsigned short* xml = (const unsigned short*)sxm[w];
        float dtv[32];
        #pragma unroll
        for (int tt = 0; tt < 32; tt++) dtv[tt] = P[tt * 33 + s] * dtw;
        #pragma unroll
        for (int r = 8; r; r >>= 1) {
            #pragma unroll
            for (int tt = 0; tt < 32; tt++) dtv[tt] += __shfl_xor(dtv[tt], r);
        }
        #pragma unroll
        for (int tt = 0; tt < 32; tt++) {
            float v = dtv[tt] + dtbias;
            dtv[tt] = (v > 20.f) ? v : __logf(1.f + __expf(v));
        }
        #pragma unroll
        for (int tt = 0; tt < 32; tt++) {
            float xv = bfu2f(xml[tt * 4 + g]);
            float Bv = P[tt * 33 + 16 + s];
            float da = __expf(dtv[tt] * Acoef);
            h = fmaf(da, h, dtv[tt] * xv * Bv);
            sacc += dtv[tt];
        }
        // commit prefetch into other buffer
        if (tile < CTILES - 1) {
            int nb = buf ^ 1;
            #pragma unroll
            for (int k = 0; k < 4; k++) {
                int idx = tid + k * 256;
                int t = idx >> 5, r = idx & 31;
                sP[nb][t * 33 + r] = rp[k];
            }
            if (isA) sxm[w][ttl] = *(uint2*)&rxm;
            __syncthreads();
            buf = nb;
        }
    }
    int db = (dir * 2 + b);
    hfin[(((size_t)db * NCHUNK + chunk) << 13) + ch * 16 + s] = h;
    if (s == 0) sumdt[(((size_t)db * NCHUNK + chunk) << 9) + ch] = sacc;
}

// ---------------- chunked scan pass B ----------------
__global__ __launch_bounds__(256) void k_scanB(float* __restrict__ hfin, const float* __restrict__ sumdt,
                                               const void* __restrict__ A_log, const int* __restrict__ dflag) {
    bool bf = (*dflag != 0);
    int idx = blockIdx.x * 256 + threadIdx.x;   // 65536
    int s = idx & 15, ch = (idx >> 4) & 511;
    int db = idx >> 13;
    float Acoef = -__expf(ldIn(A_log, ch * 16 + s, bf));
    float h = 0.f;
    size_t base = ((size_t)db * NCHUNK << 13) + ch * 16 + s;
    size_t sbase = ((size_t)db * NCHUNK << 9) + ch;
    #pragma unroll
    for (int k = 0; k < NCHUNK; k++) {
        float hf = hfin[base + ((size_t)k << 13)];
        hfin[base + ((size_t)k << 13)] = h;
        if (k < NCHUNK - 1) {
            float a = __expf(Acoef * sumdt[sbase + ((size_t)k << 9)]);
            h = a * h + hf;
        }
    }
}

// ---------------- chunked scan pass C (cooperative 4-wave blocks) ----------------
// grid = NCHUNK*256 blocks x 256 thr
__global__ __launch_bounds__(256) void k_scanC(bf16* __restrict__ xm2y, const float* __restrict__ proj4,
                                               const bf16* __restrict__ xz, const float* __restrict__ hfin,
                                               const void* __restrict__ A_log, const void* __restrict__ Dp,
                                               const void* __restrict__ dt_w, const void* __restrict__ dt_b,
                                               const int* __restrict__ dflag) {
    bool bf = (*dflag != 0);
    int tid = threadIdx.x;
    int w = tid >> 6, lane = tid & 63;
    int g = lane >> 4, s = lane & 15;
    int blk = blockIdx.x;
    int chunk = blk >> 8;            // 0..7
    int rest = blk & 255;
    int dir = rest >> 6;
    int r2 = rest & 63;
    int b = r2 >> 5;
    int j = (r2 & 31) * 4 + w;
    int ch0 = (j & 15) * 32 + (j >> 4) * 4;
    int ch = ch0 + g;

    float Acoef = -__expf(ldIn(A_log, ch * 16 + s, bf));
    float dp = ldIn(Dp, ch, bf);
    float dtw = ldIn(dt_w, ch * DTR + s, bf);
    float dtbias = ldIn(dt_b, ch, bf);
    int db = (dir * 2 + b);
    float h = hfin[(((size_t)db * NCHUNK + chunk) << 13) + ch * 16 + s];

    __shared__ float sP[2][32 * 49];   // [tt][49]: dt=s, B=16+s, C=32+s (shared)
    __shared__ uint2 sxm[4][32];
    __shared__ uint2 szz[4][32];

    bf16* xmS = xm2y + ((size_t)dir * MROWS + (size_t)b * Ll) * DI;
    const float* ppS = proj4 + ((size_t)dir * MROWS + (size_t)b * Ll) * 48;
    const bf16* zp = xz + (size_t)b * Ll * 1024 + 512;
    int t0c = chunk * CLEN;
    int ttl = lane & 31;
    bool isA = lane < 32;

    float rp[6];
    ushort4 rxz;
    // prologue: stage tile 0
    #pragma unroll
    for (int k = 0; k < 6; k++) {
        int idx = tid + k * 256;
        int t = idx / 48, r = idx % 48;
        sP[0][t * 49 + r] = ppS[(size_t)(t0c + t) * 48 + r];
    }
    if (isA) {
        rxz = *(const ushort4*)(xmS + (size_t)(t0c + ttl) * DI + ch0);
        sxm[w][ttl] = *(uint2*)&rxz;
    } else {
        int l = perm_rt(dir, t0c + ttl);
        rxz = *(const ushort4*)(zp + (size_t)l * 1024 + ch0);
        szz[w][ttl] = *(uint2*)&rxz;
    }
    __syncthreads();

    int buf = 0;
    for (int tile = 0; tile < CTILES; tile++) {
        if (tile < CTILES - 1) {
            int tb = t0c + (tile + 1) * 32;
            #pragma unroll
            for (int k = 0; k < 6; k++) {
                int idx = tid + k * 256;
                int t = idx / 48, r = idx % 48;
                rp[k] = ppS[(size_t)(tb + t) * 48 + r];
            }
            if (isA) rxz = *(const ushort4*)(xmS + (size_t)(tb + ttl) * DI + ch0);
            else {
                int l = perm_rt(dir, tb + ttl);
                rxz = *(const ushort4*)(zp + (size_t)l * 1024 + ch0);
            }
        }
        const float* P = sP[buf];
        const unsigned short* xml = (const unsigned short*)sxm[w];
        const unsigned short* zl  = (const unsigned short*)szz[w];
        int tbase = t0c + tile * 32;
        float dtv[32];
        #pragma unroll
        for (int tt = 0; tt < 32; tt++) dtv[tt] = P[tt * 49 + s] * dtw;
        #pragma unroll
        for (int r = 8; r; r >>= 1) {
            #pragma unroll
            for (int tt = 0; tt < 32; tt++) dtv[tt] += __shfl_xor(dtv[tt], r);
        }
        #pragma unroll
        for (int tt = 0; tt < 32; tt++) {
            float v = dtv[tt] + dtbias;
            dtv[tt] = (v > 20.f) ? v : __logf(1.f + __expf(v));
        }
        float pc[32];
        #pragma unroll
        for (int tt = 0; tt < 32; tt++) {
            float xv = bfu2f(xml[tt * 4 + g]);
            float Bv = P[tt * 49 + 16 + s];
            float da = __expf(dtv[tt] * Acoef);
            h = fmaf(da, h, dtv[tt] * xv * Bv);
            pc[tt] = h * P[tt * 49 + 32 + s];
        }
        #pragma unroll
        for (int r = 8; r; r >>= 1) {
            #pragma unroll
            for (int tt = 0; tt < 32; tt++) pc[tt] += __shfl_xor(pc[tt], r);
        }
        #pragma unroll
        for (int k = 0; k < 2; k++) {
            int tt = s + 16 * k;
            float xv = bfu2f(xml[tt * 4 + g]);
            float zv = bfu2f(zl[tt * 4 + g]);
            float sig = 1.f / (1.f + __expf(-zv));
            xmS[(size_t)(tbase + tt) * DI + ch] = __float2bfloat16((pc[tt] + dp * xv) * zv * sig);
        }
        if (tile < CTILES - 1) {
            int nb = buf ^ 1;
            #pragma unroll
            for (int k = 0; k < 6; k++) {
                int idx = tid + k * 256;
                int t = idx / 48, r = idx % 48;
                sP[nb][t * 49 + r] = rp[k];
            }
            if (isA) sxm[w][ttl] = *(uint2*)&rxz;
            else szz[w][ttl] = *(uint2*)&rxz;
            __syncthreads();
            buf = nb;
        }
    }
}

// ---------------- mean over spatial ----------------
__global__ __launch_bounds__(256) void k_meanU(const bf16* __restrict__ fl, const float* __restrict__ fg,
                                               float* __restrict__ ssum) {
    int b = blockIdx.y;
    int chunk = blockIdx.x;
    int c = threadIdx.x;
    float acc = 0.f;
    for (int i = 0; i < 72; i++) {
        int l = chunk * 72 + i;
        size_t off = ((size_t)(b * Ll + l)) * Cc + c;
        acc += toF(fl[off]) + fg[off];
    }
    atomicAdd(&ssum[b * Cc + c], acc);
}

// ---------------- SE head ----------------
__global__ __launch_bounds__(256) void k_se(const float* __restrict__ ssum, const void* __restrict__ fc1,
                                            const void* __restrict__ fc2, float* __restrict__ w01,
                                            const int* __restrict__ dflag) {
    bool bf = (*dflag != 0);
    int b = blockIdx.x;
    int c = threadIdx.x;
    __shared__ float sh[256];
    __shared__ float mid[16];
    sh[c] = ssum[b * 256 + c] * (1.f / (float)Ll);
    __syncthreads();
    if (c < 16) {
        float a = 0.f;
        for (int k = 0; k < 256; k++) a += sh[k] * ldIn(fc1, c * 256 + k, bf);
        mid[c] = fmaxf(a, 0.f);
    }
    __syncthreads();
    float a0 = 0.f, a1 = 0.f;
    #pragma unroll
    for (int j = 0; j < 16; j++) {
        float mj = mid[j];
        a0 += mj * ldIn(fc2, c * 16 + j, bf);
        a1 += mj * ldIn(fc2, (256 + c) * 16 + j, bf);
    }
    float mx = fmaxf(a0, a1);
    float e0 = expf(a0 - mx), e1 = expf(a1 - mx);
    float inv = 1.f / (e0 + e1);
    w01[b * 256 + c] = e0 * inv;
    w01[512 + b * 256 + c] = e1 * inv;
}

// ---------------- final combine + transpose ----------------
__global__ __launch_bounds__(256) void k_final(const bf16* __restrict__ fl, const float* __restrict__ fg,
                                               const float* __restrict__ w01, void* __restrict__ out,
                                               const int* __restrict__ dflag) {
    bool bf = (*dflag != 0);
    __shared__ float tile[32][33];
    int b = blockIdx.z;
    int l0 = blockIdx.x * 32, c0 = blockIdx.y * 32;
    int tx = threadIdx.x, ty = threadIdx.y;
    #pragma unroll
    for (int i = 0; i < 4; i++) {
        int l = l0 + ty + i * 8;
        int c = c0 + tx;
        size_t off = ((size_t)(b * Ll + l)) * Cc + c;
        tile[ty + i * 8][tx] = w01[b * 256 + c] * toF(fl[off]) + w01[512 + b * 256 + c] * fg[off];
    }
    __syncthreads();
    #pragma unroll
    for (int i = 0; i < 4; i++) {
        int c = c0 + ty + i * 8;
        size_t off = ((size_t)(b * Cc + c)) * Ll + l0 + tx;
        float v = tile[tx][ty + i * 8];
        if (bf) ((bf16*)out)[off] = __float2bfloat16(v);
        else    ((float*)out)[off] = v;
    }
}

extern "C" void kernel_launch(void* const* d_in, const int* in_sizes, int n_in,
                              void* d_out, int out_size, void* d_ws, size_t ws_size,
                              hipStream_t stream) {
    const void* x        = d_in[0];
    const void* reduce_w = d_in[1];
    const void* bn0_g    = d_in[2];
    const void* bn0_b    = d_in[3];
    const void* proj_w   = d_in[4];
    const void* bn1_g    = d_in[5];
    const void* bn1_b    = d_in[6];
    const void* dwh_w    = d_in[7];
    const void* bnh_g    = d_in[8];
    const void* bnh_b    = d_in[9];
    const void* dwv_w    = d_in[10];
    const void* bnv_g    = d_in[11];
    const void* bnv_b    = d_in[12];
    const void* fus_w    = d_in[13];
    const void* fus_b    = d_in[14];
    const void* ln_g     = d_in[15];
    const void* ln_b     = d_in[16];
    const void* in_w     = d_in[17];
    const void* conv_w   = d_in[18];
    const void* conv_b   = d_in[19];
    const void* xproj_w  = d_in[20];
    const void* dt_w     = d_in[21];
    const void* dt_b     = d_in[22];
    const void* A_log    = d_in[23];
    const void* Dp       = d_in[24];
    const void* out_w    = d_in[25];
    const void* fc1_w    = d_in[26];
    const void* fc2_w    = d_in[27];

    // ---- workspace layout (f32 slots), total 43.7 MB ----
    float* ws = (float*)d_ws;
    bf16*  fl     = (bf16*)ws;                   // 589824 slots
    float* fg     = ws + 589824;                 // 1179648
    bf16*  xrb    = (bf16*)(ws + 1769472);       // 589824 slots
    bf16*  xz     = (bf16*)(ws + 2359296);       // 2359296 slots
    float* proj4  = ws + 4718592;                // 884736
    bf16*  xm2y   = (bf16*)(ws + 5603328);       // 4718592 slots; hosts xTb/hvb earlier
    float* scrH   = ws + 10321920;               // 589824 slots: pb/xnb early, then hfin+sumdt
    float* ssum   = ws + 10911744;               // 512
    float* w01    = ws + 10912256;               // 1024
    int*   dflag  = (int*)(ws + 10913280);       // 1
    const size_t needed = 10913281ULL * 4ULL;

    if (ws_size < needed) {
        float val = 1000.0f + (float)(ws_size >> 20);
        k_probe<<<(out_size + 255) / 256, 256, 0, stream>>>((bf16*)d_out, out_size, val);
        return;
    }

    bf16* xTb = (bf16*)xm2y;       // transient (steps 1-2)
    bf16* hvb = (bf16*)xm2y;       // transient (steps 4-5)
    bf16* pb  = (bf16*)scrH;       // steps 3-4
    bf16* xnb = (bf16*)scrH;       // steps 6-7
    float* hfin  = scrH;           // 524288 (after step 7)
    float* sumdt = scrH + 524288;  // 32768

    // 0. detect input dtype
    k_detect<<<1, 64, 0, stream>>>((const unsigned int*)x, dflag);
    // 1. transpose x -> xTb
    k_transpose_in<<<dim3(Ll / 32, CIN / 32, Bn), dim3(32, 8), 0, stream>>>(x, xTb, dflag);
    // 2. xrb = relu(bn0(xTb @ reduce_w^T))
    k_mgemm<1, 16, bf16><<<dim3(4, MROWS / 128), 256, 0, stream>>>(xTb, reduce_w, xrb, MROWS, Cc, bn0_g, bn0_b, dflag);
    // 3. pb = relu(bn1(xrb @ proj_w^T))
    k_mgemm<1, 8, bf16><<<dim3(4, MROWS / 128), 256, 0, stream>>>(xrb, proj_w, pb, MROWS, Cc, bn1_g, bn1_b, dflag);
    // 4. hvb = dwconvs
    k_dwconv_hv<<<MROWS, 256, 0, stream>>>(pb, dwh_w, bnh_g, bnh_b, dwv_w, bnv_g, bnv_b, hvb, dflag);
    // 5. fl = hvb @ fus_w^T + fus_b
    k_mgemm<2, 8, bf16><<<dim3(4, MROWS / 128), 256, 0, stream>>>(hvb, fus_w, fl, MROWS, Cc, nullptr, fus_b, dflag);
    // 6. xnb = LN(xrb)
    k_ln<<<MROWS, 256, 0, stream>>>(xrb, ln_g, ln_b, xnb, dflag);
    // 7. xz = xnb @ in_w^T
    k_mgemm<0, 8, bf16><<<dim3(16, MROWS / 128), 256, 0, stream>>>(xnb, in_w, xz, MROWS, 2 * DI, nullptr, nullptr, dflag);
    // 8. conv1d (all 4 dirs) -> xm2y
    k_conv1d<<<dim3(MROWS, 4), 512, 0, stream>>>(xz, conv_w, conv_b, xm2y, dflag);
    // 9. batched xproj
    k_mgemm<0, 16, float><<<dim3(1, 4 * MROWS / 128), 256, 0, stream>>>(xm2y, xproj_w, proj4, 4 * MROWS, DTR + 2 * DS, nullptr, nullptr, dflag);
    // 10. chunked scan: A (local), B (combine), C (seeded + output)
    k_scanA<<<(NCHUNK - 1) * 256, 256, 0, stream>>>(xm2y, proj4, hfin, sumdt, A_log, dt_w, dt_b, dflag);
    k_scanB<<<256, 256, 0, stream>>>(hfin, sumdt, A_log, dflag);
    k_scanC<<<NCHUNK * 256, 256, 0, stream>>>(xm2y, proj4, xz, hfin, A_log, Dp, dt_w, dt_b, dflag);
    // 11. fused out-proj
    k_outgemm<<<dim3(4, MROWS / 128), 256, 0, stream>>>(xm2y, out_w, xrb, fg, dflag);
    // 12. SE head + final
    hipMemsetAsync(ssum, 0, 512 * 4, stream);
    k_meanU<<<dim3(32, Bn), 256, 0, stream>>>(fl, fg, ssum);
    k_se<<<Bn, 256, 0, stream>>>(ssum, fc1_w, fc2_w, w01, dflag);
    k_final<<<dim3(Ll / 32, Cc / 32, Bn), dim3(32, 8), 0, stream>>>(fl, fg, w01, d_out, dflag);
}

// Round 10
// 592.287 us; speedup vs baseline: 15.2077x; 1.3565x over previous
//
#include <hip/hip_runtime.h>
#include <hip/hip_bf16.h>

#define EPSC 1e-5f
#define Bn 2
#define CIN 512
#define Cc 256
#define Hh 48
#define Ww 48
#define Ll 2304
#define DI 512
#define DS 16
#define DTR 16
#define MROWS (Bn * Ll)   // 4608
#define NCHUNK 8
#define CLEN (Ll / NCHUNK)        // 288
#define CTILES (CLEN / 32)        // 9

using bf16 = __hip_bfloat16;
typedef short v8s __attribute__((ext_vector_type(8)));
typedef float v4f __attribute__((ext_vector_type(4)));

__device__ __forceinline__ float ldIn(const void* p, size_t i, bool bf) {
    return bf ? __bfloat162float(((const bf16*)p)[i]) : ((const float*)p)[i];
}
__device__ __forceinline__ float toF(float v) { return v; }
__device__ __forceinline__ float toF(bf16 v) { return __bfloat162float(v); }
__device__ __forceinline__ void stO(float* p, float v) { *p = v; }
__device__ __forceinline__ void stO(bf16* p, float v) { *p = __float2bfloat16(v); }
__device__ __forceinline__ float bfu2f(unsigned short u) {
    return __uint_as_float(((unsigned int)u) << 16);
}
__device__ __forceinline__ short f2bs(float f) {
    bf16 h = __float2bfloat16(f);
    short s;
    __builtin_memcpy(&s, &h, 2);
    return s;
}
union U16B { uint4 u; v8s v; };
__device__ __forceinline__ v8s ldA8(const bf16* p) { U16B t; t.u = *(const uint4*)p; return t.v; }
__device__ __forceinline__ v8s ldW8(const void* W, size_t idx, bool bf) {
    if (bf) return ldA8((const bf16*)W + idx);
    const float* f = (const float*)W + idx;
    float4 a = *(const float4*)f;
    float4 b = *(const float4*)(f + 4);
    v8s r;
    r[0] = f2bs(a.x); r[1] = f2bs(a.y); r[2] = f2bs(a.z); r[3] = f2bs(a.w);
    r[4] = f2bs(b.x); r[5] = f2bs(b.y); r[6] = f2bs(b.z); r[7] = f2bs(b.w);
    return r;
}

__device__ __forceinline__ int perm_rt(int dir, int t) {
    if (dir == 0) return t;
    if (dir == 1) return Ll - 1 - t;
    int tt = (dir == 2) ? t : (Ll - 1 - t);
    int h = tt % Hh, w = tt / Hh;
    return h * Ww + w;
}

// ---------------- dtype detector ----------------
__global__ void k_detect(const unsigned int* __restrict__ xb, int* __restrict__ flag) {
    if (threadIdx.x == 0 && blockIdx.x == 0) {
        int cnt = 0;
        for (int i = 0; i < 64; i++) {
            unsigned int u = xb[i];
            unsigned int lo = u & 0xFFFFu;
            int e = (int)((lo >> 7) & 0xFF);
            if (lo == 0u || (e >= 90 && e <= 160)) cnt++;
        }
        *flag = (cnt >= 60) ? 1 : 0;
    }
}

// ---------------- ws-size probe ----------------
__global__ __launch_bounds__(256) void k_probe(bf16* __restrict__ out, int n, float val) {
    int i = blockIdx.x * 256 + threadIdx.x;
    if (i < n) out[i] = __float2bfloat16(val);
}

// ---------------- transpose ----------------
__global__ __launch_bounds__(256) void k_transpose_in(const void* __restrict__ x, bf16* __restrict__ xT,
                                                      const int* __restrict__ dflag) {
    bool bf = (*dflag != 0);
    __shared__ float tile[32][33];
    int b = blockIdx.z;
    int l0 = blockIdx.x * 32, c0 = blockIdx.y * 32;
    int tx = threadIdx.x, ty = threadIdx.y;
    #pragma unroll
    for (int i = 0; i < 4; i++) {
        int c = c0 + ty + i * 8;
        tile[ty + i * 8][tx] = ldIn(x, ((size_t)(b * CIN + c)) * Ll + l0 + tx, bf);
    }
    __syncthreads();
    #pragma unroll
    for (int i = 0; i < 4; i++) {
        int l = l0 + ty + i * 8;
        xT[((size_t)(b * Ll + l)) * CIN + c0 + tx] = __float2bfloat16(tile[tx][ty + i * 8]);
    }
}

// ---------------- MFMA GEMM ----------------
template <int EP, int KT, typename TO>
__global__ __launch_bounds__(256) void k_mgemm(const bf16* __restrict__ A, const void* __restrict__ W,
                                               TO* __restrict__ Out, int M, int N,
                                               const void* __restrict__ g, const void* __restrict__ bias,
                                               const int* __restrict__ dflag) {
    bool bf = (*dflag != 0);
    constexpr int K = KT * 32;
    int tid = threadIdx.x;
    int w = tid >> 6, lane = tid & 63, quad = lane >> 4, lm = lane & 15;
    int m_w = blockIdx.y * 128 + w * 32;
    int n_w = blockIdx.x * 64;
    v4f acc[2][4] = {};
    const bf16* aP0 = A + (size_t)(m_w + lm) * K + quad * 8;
    const bf16* aP1 = A + (size_t)(m_w + 16 + lm) * K + quad * 8;
    size_t wIdx[4];
    #pragma unroll
    for (int ni = 0; ni < 4; ni++) {
        int n = n_w + ni * 16 + lm;
        wIdx[ni] = (size_t)((n < N) ? n : 0) * K + quad * 8;
    }
    for (int kt = 0; kt < KT; kt++) {
        v8s a0 = ldA8(aP0 + kt * 32);
        v8s a1 = ldA8(aP1 + kt * 32);
        v8s bfr[4];
        #pragma unroll
        for (int ni = 0; ni < 4; ni++) bfr[ni] = ldW8(W, wIdx[ni] + kt * 32, bf);
        #pragma unroll
        for (int ni = 0; ni < 4; ni++) {
            acc[0][ni] = __builtin_amdgcn_mfma_f32_16x16x32_bf16(a0, bfr[ni], acc[0][ni], 0, 0, 0);
            acc[1][ni] = __builtin_amdgcn_mfma_f32_16x16x32_bf16(a1, bfr[ni], acc[1][ni], 0, 0, 0);
        }
    }
    float rs = rsqrtf(1.f + EPSC);
    #pragma unroll
    for (int mi = 0; mi < 2; mi++) {
        #pragma unroll
        for (int ni = 0; ni < 4; ni++) {
            int col = n_w + ni * 16 + lm;
            if (col >= N) continue;
            float gv = 0.f, bv = 0.f;
            if (EP == 1) { gv = ldIn(g, col, bf) * rs; bv = ldIn(bias, col, bf); }
            if (EP == 2) { bv = ldIn(bias, col, bf); }
            #pragma unroll
            for (int r = 0; r < 4; r++) {
                int row = m_w + mi * 16 + quad * 4 + r;
                float v = acc[mi][ni][r];
                if (EP == 1) v = fmaxf(v * gv + bv, 0.f);
                else if (EP == 2) v += bv;
                stO(&Out[(size_t)row * N + col], v);
            }
        }
    }
}

// ---------------- fused out-proj ----------------
__global__ __launch_bounds__(256) void k_outgemm(const bf16* __restrict__ Y, const void* __restrict__ W,
                                                 const bf16* __restrict__ xrb, float* __restrict__ fg,
                                                 const int* __restrict__ dflag) {
    bool bf = (*dflag != 0);
    int tid = threadIdx.x;
    int w = tid >> 6, lane = tid & 63, quad = lane >> 4, lm = lane & 15;
    int row0 = blockIdx.y * 128 + w * 32;
    int n_w = blockIdx.x * 64;
    int b = row0 / Ll;
    v4f acc[2][4] = {};
    const bf16* aP[4][2];
    #pragma unroll
    for (int mi = 0; mi < 2; mi++) {
        int l = (row0 + mi * 16 + lm) - b * Ll;
        int h = l / Ww, w2 = l % Ww;
        int t2 = w2 * Hh + h;
        int tArr[4] = { l, Ll - 1 - l, t2, Ll - 1 - t2 };
        #pragma unroll
        for (int dir = 0; dir < 4; dir++)
            aP[dir][mi] = Y + ((size_t)dir * MROWS + (size_t)b * Ll + tArr[dir]) * DI + quad * 8;
    }
    size_t wIdx[4];
    #pragma unroll
    for (int ni = 0; ni < 4; ni++) wIdx[ni] = (size_t)(n_w + ni * 16 + lm) * DI + quad * 8;
    for (int kt = 0; kt < 16; kt++) {
        v8s bfr[4];
        #pragma unroll
        for (int ni = 0; ni < 4; ni++) bfr[ni] = ldW8(W, wIdx[ni] + kt * 32, bf);
        #pragma unroll
        for (int dir = 0; dir < 4; dir++) {
            v8s a0 = ldA8(aP[dir][0] + kt * 32);
            v8s a1 = ldA8(aP[dir][1] + kt * 32);
            #pragma unroll
            for (int ni = 0; ni < 4; ni++) {
                acc[0][ni] = __builtin_amdgcn_mfma_f32_16x16x32_bf16(a0, bfr[ni], acc[0][ni], 0, 0, 0);
                acc[1][ni] = __builtin_amdgcn_mfma_f32_16x16x32_bf16(a1, bfr[ni], acc[1][ni], 0, 0, 0);
            }
        }
    }
    #pragma unroll
    for (int mi = 0; mi < 2; mi++) {
        #pragma unroll
        for (int ni = 0; ni < 4; ni++) {
            int col = n_w + ni * 16 + lm;
            #pragma unroll
            for (int r = 0; r < 4; r++) {
                int row = row0 + mi * 16 + quad * 4 + r;
                size_t off = (size_t)row * Cc + col;
                fg[off] = toF(xrb[off]) + 0.25f * acc[mi][ni][r];
            }
        }
    }
}

// ---------------- LayerNorm ----------------
__global__ __launch_bounds__(256) void k_ln(const bf16* __restrict__ xrb, const void* __restrict__ g,
                                            const void* __restrict__ bvec, bf16* __restrict__ xn,
                                            const int* __restrict__ dflag) {
    bool bf = (*dflag != 0);
    int m = blockIdx.x;
    int c = threadIdx.x;
    float v = toF(xrb[(size_t)m * Cc + c]);
    float s1 = v, s2 = v * v;
    #pragma unroll
    for (int off = 32; off; off >>= 1) {
        s1 += __shfl_down(s1, off);
        s2 += __shfl_down(s2, off);
    }
    __shared__ float a1[4], a2[4];
    int w = c >> 6;
    if ((c & 63) == 0) { a1[w] = s1; a2[w] = s2; }
    __syncthreads();
    float t1 = a1[0] + a1[1] + a1[2] + a1[3];
    float t2 = a2[0] + a2[1] + a2[2] + a2[3];
    float mu = t1 * (1.f / 256.f);
    float var = t2 * (1.f / 256.f) - mu * mu;
    float r = rsqrtf(var + EPSC);
    xn[(size_t)m * Cc + c] = __float2bfloat16((v - mu) * r * ldIn(g, c, bf) + ldIn(bvec, c, bf));
}

// ---------------- fused depthwise convs ----------------
__global__ __launch_bounds__(256) void k_dwconv_hv(const bf16* __restrict__ p, const void* __restrict__ dwh,
                                                   const void* __restrict__ bnhg, const void* __restrict__ bnhb,
                                                   const void* __restrict__ dwv, const void* __restrict__ bnvg,
                                                   const void* __restrict__ bnvb, bf16* __restrict__ hv,
                                                   const int* __restrict__ dflag) {
    bool bf = (*dflag != 0);
    int m = blockIdx.x;
    int c = threadIdx.x;
    int b = m / Ll, l = m % Ll;
    int yy = l / Ww, xx = l % Ww;
    const bf16* base = p + (size_t)b * Ll * Cc;
    float ah = 0.f, av = 0.f;
    #pragma unroll
    for (int j = 0; j < 7; j++) {
        int x2 = xx + j - 3;
        if (0 <= x2 && x2 < Ww) ah += ldIn(dwh, c * 7 + j, bf) * toF(base[(size_t)(yy * Ww + x2) * Cc + c]);
        int y2 = yy + j - 3;
        if (0 <= y2 && y2 < Hh) av += ldIn(dwv, c * 7 + j, bf) * toF(base[(size_t)(y2 * Ww + xx) * Cc + c]);
    }
    float rs = rsqrtf(1.f + EPSC);
    float out = fmaxf(ah * ldIn(bnhg, c, bf) * rs + ldIn(bnhb, c, bf), 0.f) +
                fmaxf(av * ldIn(bnvg, c, bf) * rs + ldIn(bnvb, c, bf), 0.f);
    hv[(size_t)m * Cc + c] = __float2bfloat16(out);
}

// ---------------- conv1d + silu, all 4 dirs ----------------
__global__ __launch_bounds__(512) void k_conv1d(const bf16* __restrict__ xz, const void* __restrict__ cw,
                                                const void* __restrict__ cb, bf16* __restrict__ xm2,
                                                const int* __restrict__ dflag) {
    bool bf = (*dflag != 0);
    int m = blockIdx.x;
    int dir = blockIdx.y;
    int ch = threadIdx.x;
    int b = m / Ll, t = m % Ll;
    float acc = ldIn(cb, ch, bf);
    #pragma unroll
    for (int j = 0; j < 4; j++) {
        int tt = t + j - 3;
        if (tt >= 0) {
            int l = perm_rt(dir, tt);
            acc += ldIn(cw, ch * 4 + j, bf) * __bfloat162float(xz[((size_t)(b * Ll + l)) * 1024 + ch]);
        }
    }
    xm2[((size_t)dir * MROWS + m) * DI + ch] = __float2bfloat16(acc / (1.f + __expf(-acc)));
}

// ---------------- chunked scan pass A (coop 4-wave, lane-direct dt, XCD-swizzled) ----------------
// grid = 56*32 blocks x 256 thr; combo c = blk % 56 (keeps combo on one XCD), j = blk / 56
__global__ __launch_bounds__(256) void k_scanA(const bf16* __restrict__ xm2y, const float* __restrict__ proj4,
                                               float* __restrict__ hfin, float* __restrict__ sumdt,
                                               const void* __restrict__ A_log, const void* __restrict__ dt_w,
                                               const void* __restrict__ dt_b, const int* __restrict__ dflag) {
    bool bf = (*dflag != 0);
    int tid = threadIdx.x;
    int w = tid >> 6, lane = tid & 63;
    int g = lane >> 4, s = lane & 15;
    int c = blockIdx.x % 56;         // 56 ≡ 0 mod 8 -> same combo -> same XCD
    int j32 = blockIdx.x / 56;       // 0..31
    int chunk = c >> 3;              // 0..6
    int dir = (c & 7) >> 1;
    int b = c & 1;
    int jj = j32 * 4 + w;            // 0..127
    int ch0 = (jj & 15) * 32 + (jj >> 4) * 4;
    int ch = ch0 + g;

    float Acoef = -__expf(ldIn(A_log, ch * 16 + s, bf));
    float dtbias = ldIn(dt_b, ch, bf);
    float dtwv[16];
    #pragma unroll
    for (int r = 0; r < 16; r++) dtwv[r] = ldIn(dt_w, ch * DTR + r, bf);
    float h = 0.f, sacc = 0.f;

    __shared__ float sP[2][32 * 33];   // [tt][33]: dt-cols 0..15, B-cols 16..31 (shared by 4 waves)
    __shared__ uint2 sxm[4][32];
    __shared__ float sdt[4][128];      // per-wave dt [tt*4+g]

    const bf16* xmS = xm2y + ((size_t)dir * MROWS + (size_t)b * Ll) * DI;
    const float* ppS = proj4 + ((size_t)dir * MROWS + (size_t)b * Ll) * 48;
    int t0c = chunk * CLEN;
    int ttl = lane & 31;
    bool isA = lane < 32;

    float rp[4];
    ushort4 rxm;
    #pragma unroll
    for (int k = 0; k < 4; k++) {
        int idx = tid + k * 256;
        int t = idx >> 5, r = idx & 31;
        sP[0][t * 33 + r] = ppS[(size_t)(t0c + t) * 48 + r];
    }
    if (isA) {
        rxm = *(const ushort4*)(xmS + (size_t)(t0c + ttl) * DI + ch0);
        sxm[w][ttl] = *(uint2*)&rxm;
    }
    __syncthreads();

    int buf = 0;
    for (int tile = 0; tile < CTILES; tile++) {
        if (tile < CTILES - 1) {
            int tb = t0c + (tile + 1) * 32;
            #pragma unroll
            for (int k = 0; k < 4; k++) {
                int idx = tid + k * 256;
                int t = idx >> 5, r = idx & 31;
                rp[k] = ppS[(size_t)(tb + t) * 48 + r];
            }
            if (isA) rxm = *(const ushort4*)(xmS + (size_t)(tb + ttl) * DI + ch0);
        }
        const float* P = sP[buf];
        const unsigned short* xml = (const unsigned short*)sxm[w];
        // lane-direct dt: lane (g,s) computes dt at t=s and t=16+s for its channel
        {
            float d0 = dtbias, d1 = dtbias;
            #pragma unroll
            for (int r = 0; r < 16; r++) {
                float wv = dtwv[r];
                d0 = fmaf(P[s * 33 + r], wv, d0);
                d1 = fmaf(P[(16 + s) * 33 + r], wv, d1);
            }
            d0 = (d0 > 20.f) ? d0 : __logf(1.f + __expf(d0));
            d1 = (d1 > 20.f) ? d1 : __logf(1.f + __expf(d1));
            sdt[w][s * 4 + g] = d0;
            sdt[w][(16 + s) * 4 + g] = d1;
        }
        #pragma unroll
        for (int tt = 0; tt < 32; tt++) {
            float dtv = sdt[w][tt * 4 + g];
            float xv = bfu2f(xml[tt * 4 + g]);
            float Bv = P[tt * 33 + 16 + s];
            float da = __expf(dtv * Acoef);
            h = fmaf(da, h, dtv * xv * Bv);
            sacc += dtv;
        }
        if (tile < CTILES - 1) {
            int nb = buf ^ 1;
            #pragma unroll
            for (int k = 0; k < 4; k++) {
                int idx = tid + k * 256;
                int t = idx >> 5, r = idx & 31;
                sP[nb][t * 33 + r] = rp[k];
            }
            if (isA) sxm[w][ttl] = *(uint2*)&rxm;
            __syncthreads();
            buf = nb;
        }
    }
    int db = (dir * 2 + b);
    hfin[(((size_t)db * NCHUNK + chunk) << 13) + ch * 16 + s] = h;
    if (s == 0) sumdt[(((size_t)db * NCHUNK + chunk) << 9) + ch] = sacc;
}

// ---------------- chunked scan pass B ----------------
__global__ __launch_bounds__(256) void k_scanB(float* __restrict__ hfin, const float* __restrict__ sumdt,
                                               const void* __restrict__ A_log, const int* __restrict__ dflag) {
    bool bf = (*dflag != 0);
    int idx = blockIdx.x * 256 + threadIdx.x;   // 65536
    int s = idx & 15, ch = (idx >> 4) & 511;
    int db = idx >> 13;
    float Acoef = -__expf(ldIn(A_log, ch * 16 + s, bf));
    float h = 0.f;
    size_t base = ((size_t)db * NCHUNK << 13) + ch * 16 + s;
    size_t sbase = ((size_t)db * NCHUNK << 9) + ch;
    #pragma unroll
    for (int k = 0; k < NCHUNK; k++) {
        float hf = hfin[base + ((size_t)k << 13)];
        hfin[base + ((size_t)k << 13)] = h;
        if (k < NCHUNK - 1) {
            float a = __expf(Acoef * sumdt[sbase + ((size_t)k << 9)]);
            h = a * h + hf;
        }
    }
}

// ---------------- chunked scan pass C (coop 4-wave, lane-direct dt, XCD-swizzled) ----------------
// grid = 64*32 blocks x 256 thr; combo c = blk & 63, j = blk >> 6
__global__ __launch_bounds__(256) void k_scanC(bf16* __restrict__ xm2y, const float* __restrict__ proj4,
                                               const bf16* __restrict__ xz, const float* __restrict__ hfin,
                                               const void* __restrict__ A_log, const void* __restrict__ Dp,
                                               const void* __restrict__ dt_w, const void* __restrict__ dt_b,
                                               const int* __restrict__ dflag) {
    bool bf = (*dflag != 0);
    int tid = threadIdx.x;
    int w = tid >> 6, lane = tid & 63;
    int g = lane >> 4, s = lane & 15;
    int c = blockIdx.x & 63;         // 64 ≡ 0 mod 8 -> combo pinned to one XCD
    int j32 = blockIdx.x >> 6;       // 0..31
    int chunk = c >> 3;              // 0..7
    int dir = (c & 7) >> 1;
    int b = c & 1;
    int jj = j32 * 4 + w;
    int ch0 = (jj & 15) * 32 + (jj >> 4) * 4;
    int ch = ch0 + g;

    float Acoef = -__expf(ldIn(A_log, ch * 16 + s, bf));
    float dp = ldIn(Dp, ch, bf);
    float dtbias = ldIn(dt_b, ch, bf);
    float dtwv[16];
    #pragma unroll
    for (int r = 0; r < 16; r++) dtwv[r] = ldIn(dt_w, ch * DTR + r, bf);
    int db = (dir * 2 + b);
    float h = hfin[(((size_t)db * NCHUNK + chunk) << 13) + ch * 16 + s];

    __shared__ float sP[2][32 * 49];   // [tt][49]: dt 0..15, B 16..31, C 32..47 (shared)
    __shared__ uint2 sxm[4][32];
    __shared__ uint2 szz[4][32];
    __shared__ float sdt[4][128];

    bf16* xmS = xm2y + ((size_t)dir * MROWS + (size_t)b * Ll) * DI;
    const float* ppS = proj4 + ((size_t)dir * MROWS + (size_t)b * Ll) * 48;
    const bf16* zp = xz + (size_t)b * Ll * 1024 + 512;
    int t0c = chunk * CLEN;
    int ttl = lane & 31;
    bool isA = lane < 32;

    float rp[6];
    ushort4 rxz;
    #pragma unroll
    for (int k = 0; k < 6; k++) {
        int idx = tid + k * 256;
        int t = idx / 48, r = idx % 48;
        sP[0][t * 49 + r] = ppS[(size_t)(t0c + t) * 48 + r];
    }
    if (isA) {
        rxz = *(const ushort4*)(xmS + (size_t)(t0c + ttl) * DI + ch0);
        sxm[w][ttl] = *(uint2*)&rxz;
    } else {
        int l = perm_rt(dir, t0c + ttl);
        rxz = *(const ushort4*)(zp + (size_t)l * 1024 + ch0);
        szz[w][ttl] = *(uint2*)&rxz;
    }
    __syncthreads();

    int buf = 0;
    for (int tile = 0; tile < CTILES; tile++) {
        if (tile < CTILES - 1) {
            int tb = t0c + (tile + 1) * 32;
            #pragma unroll
            for (int k = 0; k < 6; k++) {
                int idx = tid + k * 256;
                int t = idx / 48, r = idx % 48;
                rp[k] = ppS[(size_t)(tb + t) * 48 + r];
            }
            if (isA) rxz = *(const ushort4*)(xmS + (size_t)(tb + ttl) * DI + ch0);
            else {
                int l = perm_rt(dir, tb + ttl);
                rxz = *(const ushort4*)(zp + (size_t)l * 1024 + ch0);
            }
        }
        const float* P = sP[buf];
        const unsigned short* xml = (const unsigned short*)sxm[w];
        const unsigned short* zl  = (const unsigned short*)szz[w];
        int tbase = t0c + tile * 32;
        // lane-direct dt
        {
            float d0 = dtbias, d1 = dtbias;
            #pragma unroll
            for (int r = 0; r < 16; r++) {
                float wv = dtwv[r];
                d0 = fmaf(P[s * 49 + r], wv, d0);
                d1 = fmaf(P[(16 + s) * 49 + r], wv, d1);
            }
            d0 = (d0 > 20.f) ? d0 : __logf(1.f + __expf(d0));
            d1 = (d1 > 20.f) ? d1 : __logf(1.f + __expf(d1));
            sdt[w][s * 4 + g] = d0;
            sdt[w][(16 + s) * 4 + g] = d1;
        }
        float pc[32];
        #pragma unroll
        for (int tt = 0; tt < 32; tt++) {
            float dtv = sdt[w][tt * 4 + g];
            float xv = bfu2f(xml[tt * 4 + g]);
            float Bv = P[tt * 49 + 16 + s];
            float da = __expf(dtv * Acoef);
            h = fmaf(da, h, dtv * xv * Bv);
            pc[tt] = h * P[tt * 49 + 32 + s];
        }
        #pragma unroll
        for (int r = 8; r; r >>= 1) {
            #pragma unroll
            for (int tt = 0; tt < 32; tt++) pc[tt] += __shfl_xor(pc[tt], r);
        }
        #pragma unroll
        for (int k = 0; k < 2; k++) {
            int tt = s + 16 * k;
            float xv = bfu2f(xml[tt * 4 + g]);
            float zv = bfu2f(zl[tt * 4 + g]);
            float sig = 1.f / (1.f + __expf(-zv));
            xmS[(size_t)(tbase + tt) * DI + ch] = __float2bfloat16((pc[tt] + dp * xv) * zv * sig);
        }
        if (tile < CTILES - 1) {
            int nb = buf ^ 1;
            #pragma unroll
            for (int k = 0; k < 6; k++) {
                int idx = tid + k * 256;
                int t = idx / 48, r = idx % 48;
                sP[nb][t * 49 + r] = rp[k];
            }
            if (isA) sxm[w][ttl] = *(uint2*)&rxz;
            else szz[w][ttl] = *(uint2*)&rxz;
            __syncthreads();
            buf = nb;
        }
    }
}

// ---------------- mean over spatial ----------------
__global__ __launch_bounds__(256) void k_meanU(const bf16* __restrict__ fl, const float* __restrict__ fg,
                                               float* __restrict__ ssum) {
    int b = blockIdx.y;
    int chunk = blockIdx.x;
    int c = threadIdx.x;
    float acc = 0.f;
    for (int i = 0; i < 72; i++) {
        int l = chunk * 72 + i;
        size_t off = ((size_t)(b * Ll + l)) * Cc + c;
        acc += toF(fl[off]) + fg[off];
    }
    atomicAdd(&ssum[b * Cc + c], acc);
}

// ---------------- SE head ----------------
__global__ __launch_bounds__(256) void k_se(const float* __restrict__ ssum, const void* __restrict__ fc1,
                                            const void* __restrict__ fc2, float* __restrict__ w01,
                                            const int* __restrict__ dflag) {
    bool bf = (*dflag != 0);
    int b = blockIdx.x;
    int c = threadIdx.x;
    __shared__ float sh[256];
    __shared__ float mid[16];
    sh[c] = ssum[b * 256 + c] * (1.f / (float)Ll);
    __syncthreads();
    if (c < 16) {
        float a = 0.f;
        for (int k = 0; k < 256; k++) a += sh[k] * ldIn(fc1, c * 256 + k, bf);
        mid[c] = fmaxf(a, 0.f);
    }
    __syncthreads();
    float a0 = 0.f, a1 = 0.f;
    #pragma unroll
    for (int j = 0; j < 16; j++) {
        float mj = mid[j];
        a0 += mj * ldIn(fc2, c * 16 + j, bf);
        a1 += mj * ldIn(fc2, (256 + c) * 16 + j, bf);
    }
    float mx = fmaxf(a0, a1);
    float e0 = expf(a0 - mx), e1 = expf(a1 - mx);
    float inv = 1.f / (e0 + e1);
    w01[b * 256 + c] = e0 * inv;
    w01[512 + b * 256 + c] = e1 * inv;
}

// ---------------- final combine + transpose ----------------
__global__ __launch_bounds__(256) void k_final(const bf16* __restrict__ fl, const float* __restrict__ fg,
                                               const float* __restrict__ w01, void* __restrict__ out,
                                               const int* __restrict__ dflag) {
    bool bf = (*dflag != 0);
    __shared__ float tile[32][33];
    int b = blockIdx.z;
    int l0 = blockIdx.x * 32, c0 = blockIdx.y * 32;
    int tx = threadIdx.x, ty = threadIdx.y;
    #pragma unroll
    for (int i = 0; i < 4; i++) {
        int l = l0 + ty + i * 8;
        int c = c0 + tx;
        size_t off = ((size_t)(b * Ll + l)) * Cc + c;
        tile[ty + i * 8][tx] = w01[b * 256 + c] * toF(fl[off]) + w01[512 + b * 256 + c] * fg[off];
    }
    __syncthreads();
    #pragma unroll
    for (int i = 0; i < 4; i++) {
        int c = c0 + ty + i * 8;
        size_t off = ((size_t)(b * Cc + c)) * Ll + l0 + tx;
        float v = tile[tx][ty + i * 8];
        if (bf) ((bf16*)out)[off] = __float2bfloat16(v);
        else    ((float*)out)[off] = v;
    }
}

extern "C" void kernel_launch(void* const* d_in, const int* in_sizes, int n_in,
                              void* d_out, int out_size, void* d_ws, size_t ws_size,
                              hipStream_t stream) {
    const void* x        = d_in[0];
    const void* reduce_w = d_in[1];
    const void* bn0_g    = d_in[2];
    const void* bn0_b    = d_in[3];
    const void* proj_w   = d_in[4];
    const void* bn1_g    = d_in[5];
    const void* bn1_b    = d_in[6];
    const void* dwh_w    = d_in[7];
    const void* bnh_g    = d_in[8];
    const void* bnh_b    = d_in[9];
    const void* dwv_w    = d_in[10];
    const void* bnv_g    = d_in[11];
    const void* bnv_b    = d_in[12];
    const void* fus_w    = d_in[13];
    const void* fus_b    = d_in[14];
    const void* ln_g     = d_in[15];
    const void* ln_b     = d_in[16];
    const void* in_w     = d_in[17];
    const void* conv_w   = d_in[18];
    const void* conv_b   = d_in[19];
    const void* xproj_w  = d_in[20];
    const void* dt_w     = d_in[21];
    const void* dt_b     = d_in[22];
    const void* A_log    = d_in[23];
    const void* Dp       = d_in[24];
    const void* out_w    = d_in[25];
    const void* fc1_w    = d_in[26];
    const void* fc2_w    = d_in[27];

    // ---- workspace layout (f32 slots), total 43.7 MB ----
    float* ws = (float*)d_ws;
    bf16*  fl     = (bf16*)ws;                   // 589824 slots
    float* fg     = ws + 589824;                 // 1179648
    bf16*  xrb    = (bf16*)(ws + 1769472);       // 589824 slots
    bf16*  xz     = (bf16*)(ws + 2359296);       // 2359296 slots
    float* proj4  = ws + 4718592;                // 884736
    bf16*  xm2y   = (bf16*)(ws + 5603328);       // 4718592 slots; hosts xTb/hvb earlier
    float* scrH   = ws + 10321920;               // 589824 slots: pb/xnb early, then hfin+sumdt
    float* ssum   = ws + 10911744;               // 512
    float* w01    = ws + 10912256;               // 1024
    int*   dflag  = (int*)(ws + 10913280);       // 1
    const size_t needed = 10913281ULL * 4ULL;

    if (ws_size < needed) {
        float val = 1000.0f + (float)(ws_size >> 20);
        k_probe<<<(out_size + 255) / 256, 256, 0, stream>>>((bf16*)d_out, out_size, val);
        return;
    }

    bf16* xTb = (bf16*)xm2y;       // transient (steps 1-2)
    bf16* hvb = (bf16*)xm2y;       // transient (steps 4-5)
    bf16* pb  = (bf16*)scrH;       // steps 3-4
    bf16* xnb = (bf16*)scrH;       // steps 6-7
    float* hfin  = scrH;           // 524288 (after step 7)
    float* sumdt = scrH + 524288;  // 32768

    // 0. detect input dtype
    k_detect<<<1, 64, 0, stream>>>((const unsigned int*)x, dflag);
    // 1. transpose x -> xTb
    k_transpose_in<<<dim3(Ll / 32, CIN / 32, Bn), dim3(32, 8), 0, stream>>>(x, xTb, dflag);
    // 2. xrb = relu(bn0(xTb @ reduce_w^T))
    k_mgemm<1, 16, bf16><<<dim3(4, MROWS / 128), 256, 0, stream>>>(xTb, reduce_w, xrb, MROWS, Cc, bn0_g, bn0_b, dflag);
    // 3. pb = relu(bn1(xrb @ proj_w^T))
    k_mgemm<1, 8, bf16><<<dim3(4, MROWS / 128), 256, 0, stream>>>(xrb, proj_w, pb, MROWS, Cc, bn1_g, bn1_b, dflag);
    // 4. hvb = dwconvs
    k_dwconv_hv<<<MROWS, 256, 0, stream>>>(pb, dwh_w, bnh_g, bnh_b, dwv_w, bnv_g, bnv_b, hvb, dflag);
    // 5. fl = hvb @ fus_w^T + fus_b
    k_mgemm<2, 8, bf16><<<dim3(4, MROWS / 128), 256, 0, stream>>>(hvb, fus_w, fl, MROWS, Cc, nullptr, fus_b, dflag);
    // 6. xnb = LN(xrb)
    k_ln<<<MROWS, 256, 0, stream>>>(xrb, ln_g, ln_b, xnb, dflag);
    // 7. xz = xnb @ in_w^T
    k_mgemm<0, 8, bf16><<<dim3(16, MROWS / 128), 256, 0, stream>>>(xnb, in_w, xz, MROWS, 2 * DI, nullptr, nullptr, dflag);
    // 8. conv1d (all 4 dirs) -> xm2y
    k_conv1d<<<dim3(MROWS, 4), 512, 0, stream>>>(xz, conv_w, conv_b, xm2y, dflag);
    // 9. batched xproj
    k_mgemm<0, 16, float><<<dim3(1, 4 * MROWS / 128), 256, 0, stream>>>(xm2y, xproj_w, proj4, 4 * MROWS, DTR + 2 * DS, nullptr, nullptr, dflag);
    // 10. chunked scan: A (local), B (combine), C (seeded + output)
    k_scanA<<<(NCHUNK - 1) * 256, 256, 0, stream>>>(xm2y, proj4, hfin, sumdt, A_log, dt_w, dt_b, dflag);
    k_scanB<<<256, 256, 0, stream>>>(hfin, sumdt, A_log, dflag);
    k_scanC<<<NCHUNK * 256, 256, 0, stream>>>(xm2y, proj4, xz, hfin, A_log, Dp, dt_w, dt_b, dflag);
    // 11. fused out-proj
    k_outgemm<<<dim3(4, MROWS / 128), 256, 0, stream>>>(xm2y, out_w, xrb, fg, dflag);
    // 12. SE head + final
    hipMemsetAsync(ssum, 0, 512 * 4, stream);
    k_meanU<<<dim3(32, Bn), 256, 0, stream>>>(fl, fg, ssum);
    k_se<<<Bn, 256, 0, stream>>>(ssum, fc1_w, fc2_w, w01, dflag);
    k_final<<<dim3(Ll / 32, Cc / 32, Bn), dim3(32, 8), 0, stream>>>(fl, fg, w01, d_out, dflag);
}